// Round 1
// baseline (708.224 us; speedup 1.0000x reference)
//
#include <hip/hip_runtime.h>
#include <cstdint>

#define WPOS 251
#define NBB  30
#define NCH  512
#define RELP 501
#define NEPS 1e-5f

// ---------------- workspace layout (in floats) ----------------
static constexpr size_t SZ_Z    = (size_t)NBB * NCH * WPOS;        // 3,855,360
static constexpr size_t OFF_Z   = 0;
static constexpr size_t OFF_QT  = OFF_Z + SZ_Z;                    // [bbh][x][16]
static constexpr size_t SZ_QT   = (size_t)NBB * 8 * WPOS * 16;
static constexpr size_t OFF_VT  = OFF_QT + SZ_QT;                  // [bbh][y][32]
static constexpr size_t SZ_VT   = (size_t)NBB * 8 * WPOS * 32;
static constexpr size_t OFF_QET = OFF_VT + SZ_VT;                  // [501][16]
static constexpr size_t OFF_KET = OFF_QET + (size_t)RELP * 16;     // [501][16]
static constexpr size_t OFF_VET = OFF_KET + (size_t)RELP * 16;     // [501][32]
static constexpr size_t OFF_P1Q = OFF_VET + (size_t)RELP * 32;     // [16][502]
static constexpr size_t OFF_P1K = OFF_P1Q + (size_t)16 * 502;
static constexpr size_t OFF_P2Q = OFF_P1K + (size_t)16 * 502;      // [256][502]
static constexpr size_t OFF_P2K = OFF_P2Q + (size_t)256 * 502;
static constexpr size_t OFF_CA  = OFF_P2K + (size_t)256 * 502;     // [512]
static constexpr size_t OFF_CB  = OFF_CA + 512;                    // [512]
static constexpr size_t OFF_LP  = OFF_CB + 512;                    // [240][6]
static constexpr size_t OFF_LAB = OFF_LP + (size_t)240 * 6;        // [24][2]

// ---------------- K1: kqv GEMM: Z[bb][o][l] ----------------
__global__ __launch_bounds__(256) void k_gemm(
    const float* __restrict__ x, const float* __restrict__ y,
    const float* __restrict__ wk, const float* __restrict__ wq,
    const float* __restrict__ wv, float* __restrict__ z) {
  int l0 = blockIdx.x * 64;
  int o0 = blockIdx.y * 64;
  int bb = blockIdx.z;
  int b = bb / 15, hi = bb % 15;
  const float* src;
  const float* wmat;
  int orow0;
  if (o0 < 128)      { wmat = wk; orow0 = o0;       src = x; }
  else if (o0 < 256) { wmat = wq; orow0 = o0 - 128; src = y; }
  else               { wmat = wv; orow0 = o0 - 256; src = x; }

  __shared__ float Ws[32][65];   // [c][o]
  __shared__ float Xs[32][65];   // [c][l]
  int tid = threadIdx.x;
  int tx = tid & 15, ty = tid >> 4;
  float acc[4][4] = {};

  for (int c0 = 0; c0 < 256; c0 += 32) {
#pragma unroll
    for (int r = 0; r < 8; ++r) {
      int idx = tid + r * 256;           // 64 o x 32 c
      int oo = idx >> 5, cc = idx & 31;
      Ws[cc][oo] = wmat[(size_t)(orow0 + oo) * 256 + c0 + cc];
    }
#pragma unroll
    for (int r = 0; r < 8; ++r) {
      int idx = tid + r * 256;           // 32 c x 64 l
      int cc = idx >> 6, ll = idx & 63;
      int l = l0 + ll;
      float v = 0.f;
      if (l < WPOS)
        v = src[(((size_t)b * 256 + c0 + cc) * 15 + hi) * WPOS + l];
      Xs[cc][ll] = v;
    }
    __syncthreads();
#pragma unroll
    for (int cc = 0; cc < 32; ++cc) {
      float rw[4], rx[4];
#pragma unroll
      for (int i = 0; i < 4; ++i) rw[i] = Ws[cc][ty * 4 + i];
#pragma unroll
      for (int j = 0; j < 4; ++j) rx[j] = Xs[cc][tx * 4 + j];
#pragma unroll
      for (int i = 0; i < 4; ++i)
#pragma unroll
        for (int j = 0; j < 4; ++j) acc[i][j] += rw[i] * rx[j];
    }
    __syncthreads();
  }
#pragma unroll
  for (int i = 0; i < 4; ++i) {
    int o = o0 + ty * 4 + i;
#pragma unroll
    for (int j = 0; j < 4; ++j) {
      int l = l0 + tx * 4 + j;
      if (l < WPOS) z[((size_t)bb * NCH + o) * WPOS + l] = acc[i][j];
    }
  }
}

// ---------------- K2: per-channel BN stats -> affine a,b ----------------
__global__ __launch_bounds__(256) void k_chan_stats(
    const float* __restrict__ z,
    const float* __restrict__ gk, const float* __restrict__ bk,
    const float* __restrict__ gq, const float* __restrict__ bq,
    const float* __restrict__ gkq, const float* __restrict__ bkq,
    float* __restrict__ ca, float* __restrict__ cb) {
  int o = blockIdx.x;
  int tid = threadIdx.x;
  float s = 0.f, s2 = 0.f;
  for (int idx = tid; idx < NBB * WPOS; idx += 256) {
    int bb = idx / WPOS, l = idx - bb * WPOS;
    float v = z[((size_t)bb * NCH + o) * WPOS + l];
    s += v; s2 += v * v;
  }
  __shared__ float r1[256], r2[256];
  r1[tid] = s; r2[tid] = s2; __syncthreads();
  for (int st = 128; st > 0; st >>= 1) {
    if (tid < st) { r1[tid] += r1[tid + st]; r2[tid] += r2[tid + st]; }
    __syncthreads();
  }
  if (tid == 0) {
    float n = (float)(NBB * WPOS);
    float mean = r1[0] / n;
    float var = r2[0] / n - mean * mean;
    float g, bi;
    if (o < 128)      { g = gk[o];        bi = bk[o]; }
    else if (o < 256) { g = gq[o - 128];  bi = bq[o - 128]; }
    else              { g = gkq[o - 256]; bi = bkq[o - 256]; }
    float a = g / sqrtf(var + NEPS);
    ca[o] = a;
    cb[o] = bi - mean * a;
  }
}

// ---------------- K3: normalize in place + scatter qt/vt ----------------
__global__ __launch_bounds__(256) void k_norm_scatter(
    float* __restrict__ z, const float* __restrict__ ca, const float* __restrict__ cb,
    float* __restrict__ qt, float* __restrict__ vt) {
  size_t idx = (size_t)blockIdx.x * 256 + threadIdx.x;
  if (idx >= SZ_Z) return;
  int l = (int)(idx % WPOS);
  size_t t = idx / WPOS;
  int o = (int)(t % NCH);
  int bb = (int)(t / NCH);
  float v = ca[o] * z[idx] + cb[o];
  z[idx] = v;
  int h = o >> 6, j = o & 63;
  int bbh = bb * 8 + h;
  if (j >= 16 && j < 32)
    qt[((size_t)bbh * WPOS + l) * 16 + (j - 16)] = v;
  else if (j >= 32)
    vt[((size_t)bbh * WPOS + l) * 32 + (j - 32)] = v;
}

// ---------------- K4: transpose rel slices ----------------
__global__ void k_rel_t(const float* __restrict__ rel, float* __restrict__ qet,
                        float* __restrict__ ket, float* __restrict__ vet) {
  int idx = blockIdx.x * 256 + threadIdx.x;
  if (idx >= 64 * RELP) return;
  int d = idx / RELP, p = idx - d * RELP;
  float v = rel[idx];
  if (d < 16)      qet[(size_t)p * 16 + d] = v;
  else if (d < 32) ket[(size_t)p * 16 + (d - 16)] = v;
  else             vet[(size_t)p * 32 + (d - 32)] = v;
}

// ---------------- K5: prefix sums of rel rows / pair products ----------------
__global__ __launch_bounds__(256) void k_prefix(const float* __restrict__ rel,
                                                float* __restrict__ p1q, float* __restrict__ p1k,
                                                float* __restrict__ p2q, float* __restrict__ p2k) {
  int task = blockIdx.x;   // 0..543
  const float* ra;
  const float* rb = nullptr;
  float* outp;
  if (task < 16)        { ra = rel + (size_t)task * RELP; outp = p1q + (size_t)task * 502; }
  else if (task < 32)   { ra = rel + (size_t)task * RELP; outp = p1k + (size_t)(task - 16) * 502; }
  else if (task < 288)  { int pr = task - 32;
                          ra = rel + (size_t)(pr >> 4) * RELP;
                          rb = rel + (size_t)(pr & 15) * RELP;
                          outp = p2q + (size_t)pr * 502; }
  else                  { int pr = task - 288;
                          ra = rel + (size_t)(16 + (pr >> 4)) * RELP;
                          rb = rel + (size_t)(16 + (pr & 15)) * RELP;
                          outp = p2k + (size_t)pr * 502; }
  __shared__ float buf[502];
  int tid = threadIdx.x;
  for (int p = tid; p < RELP; p += 256)
    buf[p + 1] = rb ? ra[p] * rb[p] : ra[p];
  if (tid == 0) buf[0] = 0.f;
  __syncthreads();
  if (tid == 0) {
    float s = 0.f;
    for (int p = 1; p <= RELP; ++p) { s += buf[p]; buf[p] = s; }
  }
  __syncthreads();
  for (int p = tid; p <= RELP; p += 256) outp[p] = buf[p];
}

// ---------------- block reduce helper ----------------
__device__ __forceinline__ float block_reduce(float v, float* red, int tid) {
  red[tid] = v; __syncthreads();
  for (int s = 128; s > 0; s >>= 1) {
    if (tid < s) red[tid] += red[tid + s];
    __syncthreads();
  }
  float r = red[0]; __syncthreads();
  return r;
}

// ---------------- K6: logit BN stats per (bb,h) via Gram + prefix ----------------
__global__ __launch_bounds__(256) void k_logit_stats(
    const float* __restrict__ z,
    const float* __restrict__ p1q, const float* __restrict__ p1k,
    const float* __restrict__ p2q, const float* __restrict__ p2k,
    float* __restrict__ lp) {
  int bbh = blockIdx.x;
  int bb = bbh >> 3, h = bbh & 7;
  int tid = threadIdx.x;
  __shared__ float qs[16][257], ks[16][257];
  __shared__ float Qg[256], Kg[256];
  __shared__ float red[256];
  __shared__ float qsum[16], ksum[16];

  const float* zb = z + ((size_t)bb * NCH + h * 64) * WPOS;
  for (int idx = tid; idx < 16 * WPOS; idx += 256) {
    int d = idx / WPOS, xx = idx - d * WPOS;
    ks[d][xx] = zb[(size_t)d * WPOS + xx];
    qs[d][xx] = zb[(size_t)(16 + d) * WPOS + xx];
  }
  __syncthreads();
  if (tid < 16) {
    float s = 0.f;
    for (int xx = 0; xx < WPOS; ++xx) s += qs[tid][xx];
    qsum[tid] = s;
  } else if (tid < 32) {
    float s = 0.f;
    for (int xx = 0; xx < WPOS; ++xx) s += ks[tid - 16][xx];
    ksum[tid - 16] = s;
  }
  {
    int d = tid >> 4, d2 = tid & 15;
    float g1 = 0.f, g2 = 0.f;
    for (int xx = 0; xx < WPOS; ++xx) {
      g1 += qs[d][xx] * qs[d2][xx];
      g2 += ks[d][xx] * ks[d2][xx];
    }
    Qg[tid] = g1; Kg[tid] = g2;
  }
  __syncthreads();

  float v_sqqk = Qg[tid] * Kg[tid];
  float v_sumqr = 0.f, v_sqqr = 0.f, v_sumkr = 0.f, v_sqkr = 0.f;
  for (int idx = tid; idx < 16 * WPOS; idx += 256) {
    int d = idx / WPOS, xx = idx - d * WPOS;
    int ihi = 501 - xx, ilo = 250 - xx;
    float qv = qs[d][xx];
    v_sumqr += qv * (p1q[d * 502 + ihi] - p1q[d * 502 + ilo]);
    float t = 0.f;
    for (int d2 = 0; d2 < 16; ++d2) {
      const float* pp = p2q + (size_t)(d * 16 + d2) * 502;
      t += qs[d2][xx] * (pp[ihi] - pp[ilo]);
    }
    v_sqqr += qv * t;
    float kv = ks[d][xx];
    v_sumkr += kv * (p1k[d * 502 + ihi] - p1k[d * 502 + ilo]);
    float t2 = 0.f;
    for (int d2 = 0; d2 < 16; ++d2) {
      const float* pp = p2k + (size_t)(d * 16 + d2) * 502;
      t2 += ks[d2][xx] * (pp[ihi] - pp[ilo]);
    }
    v_sqkr += kv * t2;
  }
  float r_sqqk  = block_reduce(v_sqqk, red, tid);
  float r_sumqr = block_reduce(v_sumqr, red, tid);
  float r_sqqr  = block_reduce(v_sqqr, red, tid);
  float r_sumkr = block_reduce(v_sumkr, red, tid);
  float r_sqkr  = block_reduce(v_sqkr, red, tid);
  if (tid == 0) {
    float sum_qk = 0.f;
    for (int d = 0; d < 16; ++d) sum_qk += qsum[d] * ksum[d];
    float* o = lp + (size_t)bbh * 6;
    o[0] = sum_qk; o[1] = r_sqqk;
    o[2] = r_sumqr; o[3] = r_sqqr;
    o[4] = r_sumkr; o[5] = r_sqkr;
  }
}

// ---------------- K7: finalize logit BN affine ----------------
__global__ void k_logit_final(const float* __restrict__ lp,
                              const float* __restrict__ glog, const float* __restrict__ blog,
                              float* __restrict__ lab) {
  int c = threadIdx.x;
  if (c >= 24) return;
  int grp = c >> 3, h = c & 7;
  float s = 0.f, s2 = 0.f;
  for (int bb = 0; bb < NBB; ++bb) {
    const float* o = lp + (size_t)(bb * 8 + h) * 6 + grp * 2;
    s += o[0]; s2 += o[1];
  }
  float n = (float)NBB * (float)WPOS * (float)WPOS;
  float mean = s / n;
  float var = s2 / n - mean * mean;
  float la = glog[c] / sqrtf(var + NEPS);
  lab[c * 2] = la;
  lab[c * 2 + 1] = blog[c] - mean * la;
}

// ---------------- K8: fused logits + softmax + attention ----------------
__global__ __launch_bounds__(256) void k_attn(
    const float* __restrict__ z, const float* __restrict__ qt, const float* __restrict__ vt,
    const float* __restrict__ qet, const float* __restrict__ ket, const float* __restrict__ vet,
    const float* __restrict__ lab, float* __restrict__ out) {
  int bbh = blockIdx.x;
  int bb = bbh >> 3, h = bbh & 7;
  int b = bb / 15, hi = bb % 15;
  int tid = threadIdx.x;
  int lane = tid & 63, wvid = tid >> 6;

  float la_qk = lab[h * 2],        /* lb folded into lbsum */ lb0 = lab[h * 2 + 1];
  float la_qr = lab[(8 + h) * 2],  lb1 = lab[(8 + h) * 2 + 1];
  float la_kr = lab[(16 + h) * 2], lb2 = lab[(16 + h) * 2 + 1];
  float lbsum = lb0 + lb1 + lb2;

  __shared__ float S[64][253];
  __shared__ float smax[4][64], ssum[4][64];

  const float* zb = z + ((size_t)bb * NCH + h * 64) * WPOS;

  for (int x0 = 0; x0 < WPOS; x0 += 64) {
    int nr = min(64, WPOS - x0);

    // ---- phase 1: qk (write) + kr (RMW); wave wvid owns y-group ----
    int yy = wvid * 64 + lane;
    int yc = min(yy, WPOS - 1);
    bool yok = (yy < WPOS);
    float kreg[16];
#pragma unroll
    for (int d = 0; d < 16; ++d) kreg[d] = zb[(size_t)d * WPOS + yc];

    for (int xx = 0; xx < nr; ++xx) {
      const float* __restrict__ qrow = qt + ((size_t)bbh * WPOS + x0 + xx) * 16;
      float dot = 0.f;
#pragma unroll
      for (int d = 0; d < 16; ++d) dot += kreg[d] * qrow[d];
      if (yok) S[xx][yy] = la_qk * dot + lbsum;
    }
    {
      int ymin = wvid * 64, ymax = min(wvid * 64 + 63, WPOS - 1);
      int pmin = max(0, 250 + x0 - ymax);
      int pmax = min(500, 250 + x0 + nr - 1 - ymin);
      for (int p = pmin; p <= pmax; ++p) {
        const float* __restrict__ krow = ket + (size_t)p * 16;
        float dot = 0.f;
#pragma unroll
        for (int d = 0; d < 16; ++d) dot += kreg[d] * krow[d];
        int xx = yy + p - 250 - x0;
        if (yok && xx >= 0 && xx < nr) S[xx][yy] += la_kr * dot;
      }
    }
    __syncthreads();

    // ---- phase 2: qr (RMW), lanes on x, waves split p ----
    {
      int xg = x0 + lane;
      int xc = min(xg, WPOS - 1);
      bool xok = (lane < nr);
      float qreg[16];
#pragma unroll
      for (int d = 0; d < 16; ++d) qreg[d] = zb[(size_t)(16 + d) * WPOS + xc];
      int pmin = max(0, 250 - (x0 + nr - 1));
      int pmax = min(500, 500 - x0);
      for (int p = pmin + wvid; p <= pmax; p += 4) {
        const float* __restrict__ qrow = qet + (size_t)p * 16;
        float dot = 0.f;
#pragma unroll
        for (int d = 0; d < 16; ++d) dot += qreg[d] * qrow[d];
        int yv = xg + p - 250;
        if (xok && yv >= 0 && yv < WPOS) S[lane][yv] += la_qr * dot;
      }
    }
    __syncthreads();

    // ---- phase 3: softmax over y, lanes on x, waves split y-range ----
    int ylo = wvid * 63;
    int yhi = (wvid == 3) ? WPOS : ylo + 63;
    {
      float m = -1e30f;
      for (int y2 = ylo; y2 < yhi; ++y2) m = fmaxf(m, S[lane][y2]);
      smax[wvid][lane] = m;
    }
    __syncthreads();
    float rowm = fmaxf(fmaxf(smax[0][lane], smax[1][lane]),
                       fmaxf(smax[2][lane], smax[3][lane]));
    {
      float s = 0.f;
      for (int y2 = ylo; y2 < yhi; ++y2) {
        float e = __expf(S[lane][y2] - rowm);
        S[lane][y2] = e;
        s += e;
      }
      ssum[wvid][lane] = s;
    }
    __syncthreads();
    float denom = ssum[0][lane] + ssum[1][lane] + ssum[2][lane] + ssum[3][lane];

    // ---- phase 4: attention; wave wvid owns d-slice [8w,8w+8) ----
    float acc[8] = {0, 0, 0, 0, 0, 0, 0, 0};
    {
      const float* __restrict__ vbase = vt + (size_t)bbh * WPOS * 32 + 8 * wvid;
      for (int y2 = 0; y2 < WPOS; ++y2) {
        float wgt = S[lane][y2];
        const float* __restrict__ vrow = vbase + (size_t)y2 * 32;
#pragma unroll
        for (int dd = 0; dd < 8; ++dd) acc[dd] += wgt * vrow[dd];
      }
      int pmin = max(0, 250 - (x0 + nr - 1));
      int pmax = min(500, 500 - x0);
      int xg = x0 + lane;
      for (int p = pmin; p <= pmax; ++p) {
        int y2 = xg + p - 250;
        float wgt = (lane < nr && y2 >= 0 && y2 < WPOS) ? S[lane][y2] : 0.f;
        const float* __restrict__ vrow = vet + (size_t)p * 32 + 8 * wvid;
#pragma unroll
        for (int dd = 0; dd < 8; ++dd) acc[dd] += wgt * vrow[dd];
      }
    }
    if (lane < nr) {
      float rinv = 1.0f / denom;
      int xg = x0 + lane;
#pragma unroll
      for (int dd = 0; dd < 8; ++dd) {
        int d = 8 * wvid + dd;
        out[(((size_t)b * 256 + h * 32 + d) * 15 + hi) * WPOS + xg] = acc[dd] * rinv;
      }
    }
    __syncthreads();   // S reused next tile
  }
}

// ---------------- launch ----------------
extern "C" void kernel_launch(void* const* d_in, const int* in_sizes, int n_in,
                              void* d_out, int out_size, void* d_ws, size_t ws_size,
                              hipStream_t stream) {
  const float* x    = (const float*)d_in[0];
  const float* y    = (const float*)d_in[1];
  const float* wk   = (const float*)d_in[2];
  const float* wq   = (const float*)d_in[3];
  const float* wv   = (const float*)d_in[4];
  const float* gk   = (const float*)d_in[5];
  const float* bk   = (const float*)d_in[6];
  const float* gq   = (const float*)d_in[7];
  const float* bq   = (const float*)d_in[8];
  const float* gkq  = (const float*)d_in[9];
  const float* bkq  = (const float*)d_in[10];
  const float* glog = (const float*)d_in[11];
  const float* blog = (const float*)d_in[12];
  const float* rel  = (const float*)d_in[13];
  float* out = (float*)d_out;
  float* ws  = (float*)d_ws;

  float* z   = ws + OFF_Z;
  float* qt  = ws + OFF_QT;
  float* vt  = ws + OFF_VT;
  float* qet = ws + OFF_QET;
  float* ket = ws + OFF_KET;
  float* vet = ws + OFF_VET;
  float* p1q = ws + OFF_P1Q;
  float* p1k = ws + OFF_P1K;
  float* p2q = ws + OFF_P2Q;
  float* p2k = ws + OFF_P2K;
  float* ca  = ws + OFF_CA;
  float* cb  = ws + OFF_CB;
  float* lp  = ws + OFF_LP;
  float* lab = ws + OFF_LAB;

  dim3 g1(4, 8, NBB);
  k_gemm<<<g1, 256, 0, stream>>>(x, y, wk, wq, wv, z);
  k_chan_stats<<<512, 256, 0, stream>>>(z, gk, bk, gq, bq, gkq, bkq, ca, cb);
  k_norm_scatter<<<(int)((SZ_Z + 255) / 256), 256, 0, stream>>>(z, ca, cb, qt, vt);
  k_rel_t<<<(64 * RELP + 255) / 256, 256, 0, stream>>>(rel, qet, ket, vet);
  k_prefix<<<544, 256, 0, stream>>>(rel, p1q, p1k, p2q, p2k);
  k_logit_stats<<<240, 256, 0, stream>>>(z, p1q, p1k, p2q, p2k, lp);
  k_logit_final<<<1, 32, 0, stream>>>(lp, glog, blog, lab);
  k_attn<<<240, 256, 0, stream>>>(z, qt, vt, qet, ket, vet, lab, out);
}

// Round 2
// 462.778 us; speedup vs baseline: 1.5304x; 1.5304x over previous
//
#include <hip/hip_runtime.h>
#include <cstdint>

#define WPOS 251
#define NBB  30
#define NCH  512
#define RELP 501
#define NEPS 1e-5f

// ---------------- workspace layout (in floats) ----------------
static constexpr size_t SZ_Z    = (size_t)NBB * NCH * WPOS;        // 3,855,360
static constexpr size_t OFF_Z   = 0;
static constexpr size_t OFF_QT  = OFF_Z + SZ_Z;                    // [bbh][x][16]
static constexpr size_t SZ_QT   = (size_t)NBB * 8 * WPOS * 16;
static constexpr size_t OFF_VT  = OFF_QT + SZ_QT;                  // [bbh][y][32]
static constexpr size_t SZ_VT   = (size_t)NBB * 8 * WPOS * 32;
static constexpr size_t OFF_QET = OFF_VT + SZ_VT;                  // [501][16]
static constexpr size_t OFF_KET = OFF_QET + (size_t)RELP * 16;     // [501][16]
static constexpr size_t OFF_VET = OFF_KET + (size_t)RELP * 16;     // [501][32]
static constexpr size_t OFF_P1Q = OFF_VET + (size_t)RELP * 32;     // [16][502]
static constexpr size_t OFF_P1K = OFF_P1Q + (size_t)16 * 502;
static constexpr size_t OFF_P2Q = OFF_P1K + (size_t)16 * 502;      // [256][502]
static constexpr size_t OFF_P2K = OFF_P2Q + (size_t)256 * 502;
static constexpr size_t OFF_CA  = OFF_P2K + (size_t)256 * 502;     // [512]
static constexpr size_t OFF_CB  = OFF_CA + 512;                    // [512]
static constexpr size_t OFF_LP  = OFF_CB + 512;                    // [240][6]
static constexpr size_t OFF_LAB = OFF_LP + (size_t)240 * 6;        // [24][2]

// ---------------- K1: kqv GEMM: Z[bb][o][l] ----------------
__global__ __launch_bounds__(256) void k_gemm(
    const float* __restrict__ x, const float* __restrict__ y,
    const float* __restrict__ wk, const float* __restrict__ wq,
    const float* __restrict__ wv, float* __restrict__ z) {
  int l0 = blockIdx.x * 64;
  int o0 = blockIdx.y * 64;
  int bb = blockIdx.z;
  int b = bb / 15, hi = bb % 15;
  const float* src;
  const float* wmat;
  int orow0;
  if (o0 < 128)      { wmat = wk; orow0 = o0;       src = x; }
  else if (o0 < 256) { wmat = wq; orow0 = o0 - 128; src = y; }
  else               { wmat = wv; orow0 = o0 - 256; src = x; }

  __shared__ float Ws[32][65];   // [c][o]
  __shared__ float Xs[32][65];   // [c][l]
  int tid = threadIdx.x;
  int tx = tid & 15, ty = tid >> 4;
  float acc[4][4] = {};

  for (int c0 = 0; c0 < 256; c0 += 32) {
#pragma unroll
    for (int r = 0; r < 8; ++r) {
      int idx = tid + r * 256;           // 64 o x 32 c
      int oo = idx >> 5, cc = idx & 31;
      Ws[cc][oo] = wmat[(size_t)(orow0 + oo) * 256 + c0 + cc];
    }
#pragma unroll
    for (int r = 0; r < 8; ++r) {
      int idx = tid + r * 256;           // 32 c x 64 l
      int cc = idx >> 6, ll = idx & 63;
      int l = l0 + ll;
      float v = 0.f;
      if (l < WPOS)
        v = src[(((size_t)b * 256 + c0 + cc) * 15 + hi) * WPOS + l];
      Xs[cc][ll] = v;
    }
    __syncthreads();
#pragma unroll
    for (int cc = 0; cc < 32; ++cc) {
      float rw[4], rx[4];
#pragma unroll
      for (int i = 0; i < 4; ++i) rw[i] = Ws[cc][ty * 4 + i];
#pragma unroll
      for (int j = 0; j < 4; ++j) rx[j] = Xs[cc][tx * 4 + j];
#pragma unroll
      for (int i = 0; i < 4; ++i)
#pragma unroll
        for (int j = 0; j < 4; ++j) acc[i][j] += rw[i] * rx[j];
    }
    __syncthreads();
  }
#pragma unroll
  for (int i = 0; i < 4; ++i) {
    int o = o0 + ty * 4 + i;
#pragma unroll
    for (int j = 0; j < 4; ++j) {
      int l = l0 + tx * 4 + j;
      if (l < WPOS) z[((size_t)bb * NCH + o) * WPOS + l] = acc[i][j];
    }
  }
}

// ---------------- K2: per-channel BN stats -> affine a,b ----------------
__global__ __launch_bounds__(256) void k_chan_stats(
    const float* __restrict__ z,
    const float* __restrict__ gk, const float* __restrict__ bk,
    const float* __restrict__ gq, const float* __restrict__ bq,
    const float* __restrict__ gkq, const float* __restrict__ bkq,
    float* __restrict__ ca, float* __restrict__ cb) {
  int o = blockIdx.x;
  int tid = threadIdx.x;
  float s = 0.f, s2 = 0.f;
  for (int idx = tid; idx < NBB * WPOS; idx += 256) {
    int bb = idx / WPOS, l = idx - bb * WPOS;
    float v = z[((size_t)bb * NCH + o) * WPOS + l];
    s += v; s2 += v * v;
  }
  __shared__ float r1[256], r2[256];
  r1[tid] = s; r2[tid] = s2; __syncthreads();
  for (int st = 128; st > 0; st >>= 1) {
    if (tid < st) { r1[tid] += r1[tid + st]; r2[tid] += r2[tid + st]; }
    __syncthreads();
  }
  if (tid == 0) {
    float n = (float)(NBB * WPOS);
    float mean = r1[0] / n;
    float var = r2[0] / n - mean * mean;
    float g, bi;
    if (o < 128)      { g = gk[o];        bi = bk[o]; }
    else if (o < 256) { g = gq[o - 128];  bi = bq[o - 128]; }
    else              { g = gkq[o - 256]; bi = bkq[o - 256]; }
    float a = g / sqrtf(var + NEPS);
    ca[o] = a;
    cb[o] = bi - mean * a;
  }
}

// ---------------- K3: normalize in place + scatter qt/vt ----------------
__global__ __launch_bounds__(256) void k_norm_scatter(
    float* __restrict__ z, const float* __restrict__ ca, const float* __restrict__ cb,
    float* __restrict__ qt, float* __restrict__ vt) {
  size_t idx = (size_t)blockIdx.x * 256 + threadIdx.x;
  if (idx >= SZ_Z) return;
  int l = (int)(idx % WPOS);
  size_t t = idx / WPOS;
  int o = (int)(t % NCH);
  int bb = (int)(t / NCH);
  float v = ca[o] * z[idx] + cb[o];
  z[idx] = v;
  int h = o >> 6, j = o & 63;
  int bbh = bb * 8 + h;
  if (j >= 16 && j < 32)
    qt[((size_t)bbh * WPOS + l) * 16 + (j - 16)] = v;
  else if (j >= 32)
    vt[((size_t)bbh * WPOS + l) * 32 + (j - 32)] = v;
}

// ---------------- K4: transpose rel slices ----------------
__global__ void k_rel_t(const float* __restrict__ rel, float* __restrict__ qet,
                        float* __restrict__ ket, float* __restrict__ vet) {
  int idx = blockIdx.x * 256 + threadIdx.x;
  if (idx >= 64 * RELP) return;
  int d = idx / RELP, p = idx - d * RELP;
  float v = rel[idx];
  if (d < 16)      qet[(size_t)p * 16 + d] = v;
  else if (d < 32) ket[(size_t)p * 16 + (d - 16)] = v;
  else             vet[(size_t)p * 32 + (d - 32)] = v;
}

// ---------------- K5: prefix sums of rel rows / pair products ----------------
__global__ __launch_bounds__(256) void k_prefix(const float* __restrict__ rel,
                                                float* __restrict__ p1q, float* __restrict__ p1k,
                                                float* __restrict__ p2q, float* __restrict__ p2k) {
  int task = blockIdx.x;   // 0..543
  const float* ra;
  const float* rb = nullptr;
  float* outp;
  if (task < 16)        { ra = rel + (size_t)task * RELP; outp = p1q + (size_t)task * 502; }
  else if (task < 32)   { ra = rel + (size_t)task * RELP; outp = p1k + (size_t)(task - 16) * 502; }
  else if (task < 288)  { int pr = task - 32;
                          ra = rel + (size_t)(pr >> 4) * RELP;
                          rb = rel + (size_t)(pr & 15) * RELP;
                          outp = p2q + (size_t)pr * 502; }
  else                  { int pr = task - 288;
                          ra = rel + (size_t)(16 + (pr >> 4)) * RELP;
                          rb = rel + (size_t)(16 + (pr & 15)) * RELP;
                          outp = p2k + (size_t)pr * 502; }
  __shared__ float buf[502];
  int tid = threadIdx.x;
  for (int p = tid; p < RELP; p += 256)
    buf[p + 1] = rb ? ra[p] * rb[p] : ra[p];
  if (tid == 0) buf[0] = 0.f;
  __syncthreads();
  if (tid == 0) {
    float s = 0.f;
    for (int p = 1; p <= RELP; ++p) { s += buf[p]; buf[p] = s; }
  }
  __syncthreads();
  for (int p = tid; p <= RELP; p += 256) outp[p] = buf[p];
}

// ---------------- block reduce helper ----------------
__device__ __forceinline__ float block_reduce(float v, float* red, int tid) {
  red[tid] = v; __syncthreads();
  for (int s = 128; s > 0; s >>= 1) {
    if (tid < s) red[tid] += red[tid + s];
    __syncthreads();
  }
  float r = red[0]; __syncthreads();
  return r;
}

// ---------------- K6: logit BN stats per (bb,h) via Gram + prefix ----------------
__global__ __launch_bounds__(256) void k_logit_stats(
    const float* __restrict__ z,
    const float* __restrict__ p1q, const float* __restrict__ p1k,
    const float* __restrict__ p2q, const float* __restrict__ p2k,
    float* __restrict__ lp) {
  int bbh = blockIdx.x;
  int bb = bbh >> 3, h = bbh & 7;
  int tid = threadIdx.x;
  __shared__ float qs[16][257], ks[16][257];
  __shared__ float Qg[256], Kg[256];
  __shared__ float red[256];
  __shared__ float qsum[16], ksum[16];

  const float* zb = z + ((size_t)bb * NCH + h * 64) * WPOS;
  for (int idx = tid; idx < 16 * WPOS; idx += 256) {
    int d = idx / WPOS, xx = idx - d * WPOS;
    ks[d][xx] = zb[(size_t)d * WPOS + xx];
    qs[d][xx] = zb[(size_t)(16 + d) * WPOS + xx];
  }
  __syncthreads();
  if (tid < 16) {
    float s = 0.f;
    for (int xx = 0; xx < WPOS; ++xx) s += qs[tid][xx];
    qsum[tid] = s;
  } else if (tid < 32) {
    float s = 0.f;
    for (int xx = 0; xx < WPOS; ++xx) s += ks[tid - 16][xx];
    ksum[tid - 16] = s;
  }
  {
    int d = tid >> 4, d2 = tid & 15;
    float g1 = 0.f, g2 = 0.f;
    for (int xx = 0; xx < WPOS; ++xx) {
      g1 += qs[d][xx] * qs[d2][xx];
      g2 += ks[d][xx] * ks[d2][xx];
    }
    Qg[tid] = g1; Kg[tid] = g2;
  }
  __syncthreads();

  float v_sqqk = Qg[tid] * Kg[tid];
  float v_sumqr = 0.f, v_sqqr = 0.f, v_sumkr = 0.f, v_sqkr = 0.f;
  for (int idx = tid; idx < 16 * WPOS; idx += 256) {
    int d = idx / WPOS, xx = idx - d * WPOS;
    int ihi = 501 - xx, ilo = 250 - xx;
    float qv = qs[d][xx];
    v_sumqr += qv * (p1q[d * 502 + ihi] - p1q[d * 502 + ilo]);
    float t = 0.f;
    for (int d2 = 0; d2 < 16; ++d2) {
      const float* pp = p2q + (size_t)(d * 16 + d2) * 502;
      t += qs[d2][xx] * (pp[ihi] - pp[ilo]);
    }
    v_sqqr += qv * t;
    float kv = ks[d][xx];
    v_sumkr += kv * (p1k[d * 502 + ihi] - p1k[d * 502 + ilo]);
    float t2 = 0.f;
    for (int d2 = 0; d2 < 16; ++d2) {
      const float* pp = p2k + (size_t)(d * 16 + d2) * 502;
      t2 += ks[d2][xx] * (pp[ihi] - pp[ilo]);
    }
    v_sqkr += kv * t2;
  }
  float r_sqqk  = block_reduce(v_sqqk, red, tid);
  float r_sumqr = block_reduce(v_sumqr, red, tid);
  float r_sqqr  = block_reduce(v_sqqr, red, tid);
  float r_sumkr = block_reduce(v_sumkr, red, tid);
  float r_sqkr  = block_reduce(v_sqkr, red, tid);
  if (tid == 0) {
    float sum_qk = 0.f;
    for (int d = 0; d < 16; ++d) sum_qk += qsum[d] * ksum[d];
    float* o = lp + (size_t)bbh * 6;
    o[0] = sum_qk; o[1] = r_sqqk;
    o[2] = r_sumqr; o[3] = r_sqqr;
    o[4] = r_sumkr; o[5] = r_sqkr;
  }
}

// ---------------- K7: finalize logit BN affine ----------------
__global__ void k_logit_final(const float* __restrict__ lp,
                              const float* __restrict__ glog, const float* __restrict__ blog,
                              float* __restrict__ lab) {
  int c = threadIdx.x;
  if (c >= 24) return;
  int grp = c >> 3, h = c & 7;
  float s = 0.f, s2 = 0.f;
  for (int bb = 0; bb < NBB; ++bb) {
    const float* o = lp + (size_t)(bb * 8 + h) * 6 + grp * 2;
    s += o[0]; s2 += o[1];
  }
  float n = (float)NBB * (float)WPOS * (float)WPOS;
  float mean = s / n;
  float var = s2 / n - mean * mean;
  float la = glog[c] / sqrtf(var + NEPS);
  lab[c * 2] = la;
  lab[c * 2 + 1] = blog[c] - mean * la;
}

// ---------------- K8: fused logits + softmax + attention ----------------
// One block per (bbh, 32-row x-tile). 1920 blocks, 256 threads.
__global__ __launch_bounds__(256) void k_attn(
    const float* __restrict__ z, const float* __restrict__ qt, const float* __restrict__ vt,
    const float* __restrict__ qet, const float* __restrict__ ket, const float* __restrict__ vet,
    const float* __restrict__ lab, float* __restrict__ out) {
  int blk = blockIdx.x;
  int bbh = blk >> 3, tile = blk & 7;
  int bb = bbh >> 3, h = bbh & 7;
  int b = bb / 15, hi = bb % 15;
  int x0 = tile * 32;
  int nr = min(32, WPOS - x0);            // 32 (tiles 0-6) or 27 (tile 7)
  int tid = threadIdx.x;
  int lane = tid & 63, wvid = tid >> 6;

  float la_qk = lab[h * 2],        lb0 = lab[h * 2 + 1];
  float la_qr = lab[(8 + h) * 2],  lb1 = lab[(8 + h) * 2 + 1];
  float la_kr = lab[(16 + h) * 2], lb2 = lab[(16 + h) * 2 + 1];
  float lbsum = lb0 + lb1 + lb2;

  __shared__ float S[32][253];            // stride 253: odd -> conflict-free column reads
  __shared__ float qs[32][20];            // stride 20 floats = 80B, 16B-aligned rows
  __shared__ float smax[8][33], ssum[8][33];

  // ---- stage q tile into LDS ----
  for (int i = tid; i < nr * 16; i += 256) {
    int xx = i >> 4, d = i & 15;
    qs[xx][d] = qt[((size_t)bbh * WPOS + x0 + xx) * 16 + d];
  }

  // ---- k row per lane (y = wvid*64 + lane) ----
  int yy = wvid * 64 + lane;
  int yc = min(yy, WPOS - 1);
  bool yok = (yy < WPOS);
  const float* zb = z + ((size_t)bb * NCH + h * 64) * WPOS;
  float kreg[16];
#pragma unroll
  for (int d = 0; d < 16; ++d) kreg[d] = zb[(size_t)d * WPOS + yc];
  __syncthreads();

  // ---- fused S = la_qk*qk + la_qr*qr + la_kr*kr + lbsum, single write ----
  for (int xx = 0; xx < nr; ++xx) {
    int x = x0 + xx;
    int pq = yc - x + 250;                // index for qet (q_enc[d][x][y])
    int pk = 500 - pq;                    // index for ket (k_enc[d][y][x])
    float qxv[16], qev[16], kev[16];
    const float4* qe = (const float4*)(qet + (size_t)pq * 16);
    const float4* ke = (const float4*)(ket + (size_t)pk * 16);
    const float4* qx = (const float4*)(&qs[xx][0]);
#pragma unroll
    for (int t = 0; t < 4; ++t) {
      *(float4*)&qev[t * 4] = qe[t];
      *(float4*)&kev[t * 4] = ke[t];
      *(float4*)&qxv[t * 4] = qx[t];
    }
    float dqk = 0.f, dqr = 0.f, dkr = 0.f;
#pragma unroll
    for (int d = 0; d < 16; ++d) {
      dqk += kreg[d] * qxv[d];
      dqr += qxv[d] * qev[d];
      dkr += kreg[d] * kev[d];
    }
    if (yok) S[xx][yy] = la_qk * dqk + la_qr * dqr + la_kr * dkr + lbsum;
  }
  __syncthreads();

  // ---- softmax over y; 8 slices of 32 y each, lanes on x ----
  int xx = lane & 31;
  int sl = wvid * 2 + (lane >> 5);        // 0..7
  int ylo = sl * 32;
  int yhi = min(ylo + 32, WPOS);
  {
    float m = -1e30f;
    for (int y2 = ylo; y2 < yhi; ++y2) m = fmaxf(m, S[xx][y2]);
    smax[sl][xx] = m;
  }
  __syncthreads();
  float rowm = smax[0][xx];
#pragma unroll
  for (int s = 1; s < 8; ++s) rowm = fmaxf(rowm, smax[s][xx]);
  {
    float sacc = 0.f;
    for (int y2 = ylo; y2 < yhi; ++y2) {
      float e = __expf(S[xx][y2] - rowm);
      S[xx][y2] = e;
      sacc += e;
    }
    ssum[sl][xx] = sacc;
  }
  __syncthreads();
  float denom = 0.f;
#pragma unroll
  for (int s = 0; s < 8; ++s) denom += ssum[s][xx];

  // ---- attention: 8 groups (wvid,half) x 4 d-channels, lanes on x ----
  int g = sl;                              // same decomposition: group 0..7
  int d0 = g * 4;
  float4 acc = {0.f, 0.f, 0.f, 0.f};
  {
    const float* vb = vt + (size_t)bbh * WPOS * 32 + d0;
    for (int y2 = 0; y2 < WPOS; ++y2) {
      float wgt = S[xx][y2];
      float4 vr = *(const float4*)(vb + (size_t)y2 * 32);
      acc.x += wgt * vr.x; acc.y += wgt * vr.y;
      acc.z += wgt * vr.z; acc.w += wgt * vr.w;
    }
  }
  {
    int xg = x0 + xx;
    int pmin = max(0, 250 - (x0 + nr - 1));
    int pmax = min(500, 500 - x0);
    for (int p = pmin; p <= pmax; ++p) {
      int y2 = xg + p - 250;
      float wgt = (y2 >= 0 && y2 < WPOS) ? S[xx][y2] : 0.f;
      float4 vr = *(const float4*)(vet + (size_t)p * 32 + d0);
      acc.x += wgt * vr.x; acc.y += wgt * vr.y;
      acc.z += wgt * vr.z; acc.w += wgt * vr.w;
    }
  }
  if (xx < nr) {
    float rinv = 1.0f / denom;
    int xg = x0 + xx;
    float av[4] = {acc.x, acc.y, acc.z, acc.w};
#pragma unroll
    for (int dd = 0; dd < 4; ++dd) {
      int d = d0 + dd;
      out[(((size_t)b * 256 + h * 32 + d) * 15 + hi) * WPOS + xg] = av[dd] * rinv;
    }
  }
}

// ---------------- launch ----------------
extern "C" void kernel_launch(void* const* d_in, const int* in_sizes, int n_in,
                              void* d_out, int out_size, void* d_ws, size_t ws_size,
                              hipStream_t stream) {
  const float* x    = (const float*)d_in[0];
  const float* y    = (const float*)d_in[1];
  const float* wk   = (const float*)d_in[2];
  const float* wq   = (const float*)d_in[3];
  const float* wv   = (const float*)d_in[4];
  const float* gk   = (const float*)d_in[5];
  const float* bk   = (const float*)d_in[6];
  const float* gq   = (const float*)d_in[7];
  const float* bq   = (const float*)d_in[8];
  const float* gkq  = (const float*)d_in[9];
  const float* bkq  = (const float*)d_in[10];
  const float* glog = (const float*)d_in[11];
  const float* blog = (const float*)d_in[12];
  const float* rel  = (const float*)d_in[13];
  float* out = (float*)d_out;
  float* ws  = (float*)d_ws;

  float* z   = ws + OFF_Z;
  float* qt  = ws + OFF_QT;
  float* vt  = ws + OFF_VT;
  float* qet = ws + OFF_QET;
  float* ket = ws + OFF_KET;
  float* vet = ws + OFF_VET;
  float* p1q = ws + OFF_P1Q;
  float* p1k = ws + OFF_P1K;
  float* p2q = ws + OFF_P2Q;
  float* p2k = ws + OFF_P2K;
  float* ca  = ws + OFF_CA;
  float* cb  = ws + OFF_CB;
  float* lp  = ws + OFF_LP;
  float* lab = ws + OFF_LAB;

  dim3 g1(4, 8, NBB);
  k_gemm<<<g1, 256, 0, stream>>>(x, y, wk, wq, wv, z);
  k_chan_stats<<<512, 256, 0, stream>>>(z, gk, bk, gq, bq, gkq, bkq, ca, cb);
  k_norm_scatter<<<(int)((SZ_Z + 255) / 256), 256, 0, stream>>>(z, ca, cb, qt, vt);
  k_rel_t<<<(64 * RELP + 255) / 256, 256, 0, stream>>>(rel, qet, ket, vet);
  k_prefix<<<544, 256, 0, stream>>>(rel, p1q, p1k, p2q, p2k);
  k_logit_stats<<<240, 256, 0, stream>>>(z, p1q, p1k, p2q, p2k, lp);
  k_logit_final<<<1, 32, 0, stream>>>(lp, glog, blog, lab);
  k_attn<<<240 * 8, 256, 0, stream>>>(z, qt, vt, qet, ket, vet, lab, out);
}

// Round 3
// 347.310 us; speedup vs baseline: 2.0392x; 1.3325x over previous
//
#include <hip/hip_runtime.h>
#include <hip/hip_bf16.h>
#include <cstdint>

#define WPOS 251
#define NBB  30
#define NCH  512
#define RELP 501
#define NEPS 1e-5f

// ---------------- workspace layout (in float slots) ----------------
static constexpr size_t SZ_Z     = (size_t)NBB * NCH * WPOS;
static constexpr size_t OFF_Z    = 0;
static constexpr size_t OFF_QT   = OFF_Z + SZ_Z;                   // [bbh][x][16]
static constexpr size_t SZ_QT    = (size_t)NBB * 8 * WPOS * 16;
static constexpr size_t OFF_VT   = OFF_QT + SZ_QT;                 // [bbh][y][32]
static constexpr size_t SZ_VT    = (size_t)NBB * 8 * WPOS * 32;
static constexpr size_t OFF_RETC = OFF_VT + SZ_VT;                 // uint[501][16]: qe|keR bf16 pairs
static constexpr size_t OFF_VET  = OFF_RETC + (size_t)RELP * 16;   // f32 [501][32]
static constexpr size_t OFF_P1Q  = OFF_VET + (size_t)RELP * 32;    // [16][502]
static constexpr size_t OFF_P1K  = OFF_P1Q + (size_t)16 * 502;
static constexpr size_t OFF_P2Q  = OFF_P1K + (size_t)16 * 502;     // [256][502]
static constexpr size_t OFF_P2K  = OFF_P2Q + (size_t)256 * 502;
static constexpr size_t OFF_CA   = OFF_P2K + (size_t)256 * 502;    // [512]
static constexpr size_t OFF_CB   = OFF_CA + 512;
static constexpr size_t OFF_LP   = OFF_CB + 512;                   // [240][6]
static constexpr size_t OFF_LAB  = OFF_LP + (size_t)240 * 6;       // [24][2]

static __device__ __forceinline__ unsigned short f2bf(float f) {
  __hip_bfloat16 h = __float2bfloat16(f);
  return *reinterpret_cast<unsigned short*>(&h);
}

// ---------------- K1: kqv GEMM: Z[bb][o][l] ----------------
__global__ __launch_bounds__(256) void k_gemm(
    const float* __restrict__ x, const float* __restrict__ y,
    const float* __restrict__ wk, const float* __restrict__ wq,
    const float* __restrict__ wv, float* __restrict__ z) {
  int l0 = blockIdx.x * 64;
  int o0 = blockIdx.y * 64;
  int bb = blockIdx.z;
  int b = bb / 15, hi = bb % 15;
  const float* src;
  const float* wmat;
  int orow0;
  if (o0 < 128)      { wmat = wk; orow0 = o0;       src = x; }
  else if (o0 < 256) { wmat = wq; orow0 = o0 - 128; src = y; }
  else               { wmat = wv; orow0 = o0 - 256; src = x; }

  __shared__ float Ws[32][65];
  __shared__ float Xs[32][65];
  int tid = threadIdx.x;
  int tx = tid & 15, ty = tid >> 4;
  float acc[4][4] = {};

  for (int c0 = 0; c0 < 256; c0 += 32) {
#pragma unroll
    for (int r = 0; r < 8; ++r) {
      int idx = tid + r * 256;
      int oo = idx >> 5, cc = idx & 31;
      Ws[cc][oo] = wmat[(size_t)(orow0 + oo) * 256 + c0 + cc];
    }
#pragma unroll
    for (int r = 0; r < 8; ++r) {
      int idx = tid + r * 256;
      int cc = idx >> 6, ll = idx & 63;
      int l = l0 + ll;
      float v = 0.f;
      if (l < WPOS)
        v = src[(((size_t)b * 256 + c0 + cc) * 15 + hi) * WPOS + l];
      Xs[cc][ll] = v;
    }
    __syncthreads();
#pragma unroll
    for (int cc = 0; cc < 32; ++cc) {
      float rw[4], rx[4];
#pragma unroll
      for (int i = 0; i < 4; ++i) rw[i] = Ws[cc][ty * 4 + i];
#pragma unroll
      for (int j = 0; j < 4; ++j) rx[j] = Xs[cc][tx * 4 + j];
#pragma unroll
      for (int i = 0; i < 4; ++i)
#pragma unroll
        for (int j = 0; j < 4; ++j) acc[i][j] += rw[i] * rx[j];
    }
    __syncthreads();
  }
#pragma unroll
  for (int i = 0; i < 4; ++i) {
    int o = o0 + ty * 4 + i;
#pragma unroll
    for (int j = 0; j < 4; ++j) {
      int l = l0 + tx * 4 + j;
      if (l < WPOS) z[((size_t)bb * NCH + o) * WPOS + l] = acc[i][j];
    }
  }
}

// ---------------- K2: per-channel BN stats -> affine a,b ----------------
__global__ __launch_bounds__(256) void k_chan_stats(
    const float* __restrict__ z,
    const float* __restrict__ gk, const float* __restrict__ bk,
    const float* __restrict__ gq, const float* __restrict__ bq,
    const float* __restrict__ gkq, const float* __restrict__ bkq,
    float* __restrict__ ca, float* __restrict__ cb) {
  int o = blockIdx.x;
  int tid = threadIdx.x;
  float s = 0.f, s2 = 0.f;
  for (int idx = tid; idx < NBB * WPOS; idx += 256) {
    int bb = idx / WPOS, l = idx - bb * WPOS;
    float v = z[((size_t)bb * NCH + o) * WPOS + l];
    s += v; s2 += v * v;
  }
  __shared__ float r1[256], r2[256];
  r1[tid] = s; r2[tid] = s2; __syncthreads();
  for (int st = 128; st > 0; st >>= 1) {
    if (tid < st) { r1[tid] += r1[tid + st]; r2[tid] += r2[tid + st]; }
    __syncthreads();
  }
  if (tid == 0) {
    float n = (float)(NBB * WPOS);
    float mean = r1[0] / n;
    float var = r2[0] / n - mean * mean;
    float g, bi;
    if (o < 128)      { g = gk[o];        bi = bk[o]; }
    else if (o < 256) { g = gq[o - 128];  bi = bq[o - 128]; }
    else              { g = gkq[o - 256]; bi = bkq[o - 256]; }
    float a = g / sqrtf(var + NEPS);
    ca[o] = a;
    cb[o] = bi - mean * a;
  }
}

// ---------------- K3: normalize in place + scatter qt/vt ----------------
__global__ __launch_bounds__(256) void k_norm_scatter(
    float* __restrict__ z, const float* __restrict__ ca, const float* __restrict__ cb,
    float* __restrict__ qt, float* __restrict__ vt) {
  size_t idx = (size_t)blockIdx.x * 256 + threadIdx.x;
  if (idx >= SZ_Z) return;
  int l = (int)(idx % WPOS);
  size_t t = idx / WPOS;
  int o = (int)(t % NCH);
  int bb = (int)(t / NCH);
  float v = ca[o] * z[idx] + cb[o];
  z[idx] = v;
  int h = o >> 6, j = o & 63;
  int bbh = bb * 8 + h;
  if (j >= 16 && j < 32)
    qt[((size_t)bbh * WPOS + l) * 16 + (j - 16)] = v;
  else if (j >= 32)
    vt[((size_t)bbh * WPOS + l) * 32 + (j - 32)] = v;
}

// ---------------- K4: rel prep: combined bf16 qe|keR table + vet ----------------
__global__ void k_rel_prep(const float* __restrict__ rel, unsigned* __restrict__ retc,
                           float* __restrict__ vet) {
  int idx = blockIdx.x * 256 + threadIdx.x;
  if (idx >= RELP * 48) return;
  int p = idx / 48, j = idx - p * 48;
  if (j < 16) {
    float lo, hi;
    if (j < 8) {                       // qe pairs: d = 2j, 2j+1 at position p
      lo = rel[(size_t)(2 * j) * RELP + p];
      hi = rel[(size_t)(2 * j + 1) * RELP + p];
    } else {                           // keR pairs: d = 2(j-8), at position 500-p
      int jj = j - 8;
      lo = rel[(size_t)(16 + 2 * jj) * RELP + (500 - p)];
      hi = rel[(size_t)(17 + 2 * jj) * RELP + (500 - p)];
    }
    retc[(size_t)p * 16 + j] = ((unsigned)f2bf(hi) << 16) | (unsigned)f2bf(lo);
  } else {
    int dd = j - 16;
    vet[(size_t)p * 32 + dd] = rel[(size_t)(32 + dd) * RELP + p];
  }
}

// ---------------- K5: prefix sums of rel rows / pair products ----------------
__global__ __launch_bounds__(256) void k_prefix(const float* __restrict__ rel,
                                                float* __restrict__ p1q, float* __restrict__ p1k,
                                                float* __restrict__ p2q, float* __restrict__ p2k) {
  int task = blockIdx.x;   // 0..543
  const float* ra;
  const float* rb = nullptr;
  float* outp;
  if (task < 16)        { ra = rel + (size_t)task * RELP; outp = p1q + (size_t)task * 502; }
  else if (task < 32)   { ra = rel + (size_t)task * RELP; outp = p1k + (size_t)(task - 16) * 502; }
  else if (task < 288)  { int pr = task - 32;
                          ra = rel + (size_t)(pr >> 4) * RELP;
                          rb = rel + (size_t)(pr & 15) * RELP;
                          outp = p2q + (size_t)pr * 502; }
  else                  { int pr = task - 288;
                          ra = rel + (size_t)(16 + (pr >> 4)) * RELP;
                          rb = rel + (size_t)(16 + (pr & 15)) * RELP;
                          outp = p2k + (size_t)pr * 502; }
  __shared__ float buf[502];
  int tid = threadIdx.x;
  for (int p = tid; p < RELP; p += 256)
    buf[p + 1] = rb ? ra[p] * rb[p] : ra[p];
  if (tid == 0) buf[0] = 0.f;
  __syncthreads();
  if (tid == 0) {
    float s = 0.f;
    for (int p = 1; p <= RELP; ++p) { s += buf[p]; buf[p] = s; }
  }
  __syncthreads();
  for (int p = tid; p <= RELP; p += 256) outp[p] = buf[p];
}

// ---------------- block reduce helper ----------------
__device__ __forceinline__ float block_reduce(float v, float* red, int tid) {
  red[tid] = v; __syncthreads();
  for (int s = 128; s > 0; s >>= 1) {
    if (tid < s) red[tid] += red[tid + s];
    __syncthreads();
  }
  float r = red[0]; __syncthreads();
  return r;
}

// ---------------- K6: logit BN stats per (bb,h) ----------------
__global__ __launch_bounds__(256) void k_logit_stats(
    const float* __restrict__ z,
    const float* __restrict__ p1q, const float* __restrict__ p1k,
    const float* __restrict__ p2q, const float* __restrict__ p2k,
    float* __restrict__ lp) {
  int bbh = blockIdx.x;
  int bb = bbh >> 3, h = bbh & 7;
  int tid = threadIdx.x;
  __shared__ float qs[16][257], ks[16][257];
  __shared__ float Qg[256], Kg[256];
  __shared__ float red[256];
  __shared__ float qsum[16], ksum[16];

  const float* zb = z + ((size_t)bb * NCH + h * 64) * WPOS;
  for (int idx = tid; idx < 16 * WPOS; idx += 256) {
    int d = idx / WPOS, xx = idx - d * WPOS;
    ks[d][xx] = zb[(size_t)d * WPOS + xx];
    qs[d][xx] = zb[(size_t)(16 + d) * WPOS + xx];
  }
  __syncthreads();
  if (tid < 16) {
    float s = 0.f;
    for (int xx = 0; xx < WPOS; ++xx) s += qs[tid][xx];
    qsum[tid] = s;
  } else if (tid < 32) {
    float s = 0.f;
    for (int xx = 0; xx < WPOS; ++xx) s += ks[tid - 16][xx];
    ksum[tid - 16] = s;
  }
  {
    int d = tid >> 4, d2 = tid & 15;
    float g1 = 0.f, g2 = 0.f;
    for (int xx = 0; xx < WPOS; ++xx) {
      g1 += qs[d][xx] * qs[d2][xx];
      g2 += ks[d][xx] * ks[d2][xx];
    }
    Qg[tid] = g1; Kg[tid] = g2;
  }
  __syncthreads();

  float v_sqqk = Qg[tid] * Kg[tid];
  float v_sumqr = 0.f, v_sqqr = 0.f, v_sumkr = 0.f, v_sqkr = 0.f;
  for (int idx = tid; idx < 16 * WPOS; idx += 256) {
    int d = idx / WPOS, xx = idx - d * WPOS;
    int ihi = 501 - xx, ilo = 250 - xx;
    float qv = qs[d][xx];
    v_sumqr += qv * (p1q[d * 502 + ihi] - p1q[d * 502 + ilo]);
    float t = 0.f;
    for (int d2 = 0; d2 < 16; ++d2) {
      const float* pp = p2q + (size_t)(d * 16 + d2) * 502;
      t += qs[d2][xx] * (pp[ihi] - pp[ilo]);
    }
    v_sqqr += qv * t;
    float kv = ks[d][xx];
    v_sumkr += kv * (p1k[d * 502 + ihi] - p1k[d * 502 + ilo]);
    float t2 = 0.f;
    for (int d2 = 0; d2 < 16; ++d2) {
      const float* pp = p2k + (size_t)(d * 16 + d2) * 502;
      t2 += ks[d2][xx] * (pp[ihi] - pp[ilo]);
    }
    v_sqkr += kv * t2;
  }
  float r_sqqk  = block_reduce(v_sqqk, red, tid);
  float r_sumqr = block_reduce(v_sumqr, red, tid);
  float r_sqqr  = block_reduce(v_sqqr, red, tid);
  float r_sumkr = block_reduce(v_sumkr, red, tid);
  float r_sqkr  = block_reduce(v_sqkr, red, tid);
  if (tid == 0) {
    float sum_qk = 0.f;
    for (int d = 0; d < 16; ++d) sum_qk += qsum[d] * ksum[d];
    float* o = lp + (size_t)bbh * 6;
    o[0] = sum_qk; o[1] = r_sqqk;
    o[2] = r_sumqr; o[3] = r_sqqr;
    o[4] = r_sumkr; o[5] = r_sqkr;
  }
}

// ---------------- K7: finalize logit BN affine ----------------
__global__ void k_logit_final(const float* __restrict__ lp,
                              const float* __restrict__ glog, const float* __restrict__ blog,
                              float* __restrict__ lab) {
  int c = threadIdx.x;
  if (c >= 24) return;
  int grp = c >> 3, h = c & 7;
  float s = 0.f, s2 = 0.f;
  for (int bb = 0; bb < NBB; ++bb) {
    const float* o = lp + (size_t)(bb * 8 + h) * 6 + grp * 2;
    s += o[0]; s2 += o[1];
  }
  float n = (float)NBB * (float)WPOS * (float)WPOS;
  float mean = s / n;
  float var = s2 / n - mean * mean;
  float la = glog[c] / sqrtf(var + NEPS);
  lab[c * 2] = la;
  lab[c * 2 + 1] = blog[c] - mean * la;
}

// ---------------- K8: fused logits + softmax + attention ----------------
// One block per (bbh, 32-row x-tile). 1920 blocks, 256 threads, ~52KB LDS.
__global__ __launch_bounds__(256) void k_attn(
    const float* __restrict__ z, const float* __restrict__ qt, const float* __restrict__ vt,
    const unsigned* __restrict__ retc, const float* __restrict__ vet,
    const float* __restrict__ lab, float* __restrict__ out) {
  int blk = blockIdx.x;
  int bbh = blk >> 3, tile = blk & 7;
  int bb = bbh >> 3, h = bbh & 7;
  int b = bb / 15, hi = bb % 15;
  int x0 = tile * 32;
  int nr = min(32, WPOS - x0);
  int tid = threadIdx.x;
  int lane = tid & 63, wvid = tid >> 6;

  float la_qk = lab[h * 2],        lb0 = lab[h * 2 + 1];
  float la_qr = lab[(8 + h) * 2],  lb1 = lab[(8 + h) * 2 + 1];
  float la_kr = lab[(16 + h) * 2], lb2 = lab[(16 + h) * 2 + 1];
  float lbsum = lb0 + lb1 + lb2;

  __shared__ float S[32][251];          // 32,128 B; odd stride -> conflict-free columns
  __shared__ unsigned winU[282 * 17];   // 19,176 B; rel window, stride-17 rows
  __shared__ float smax[8][32];         // 1,024 B (reused for sums)

  int pwin0 = 251 - x0 - nr;            // first window row
  int nwin = 250 + nr;                  // rows staged

  // ---- stage rel window into LDS (coalesced) ----
  for (int i = tid; i < nwin * 16; i += 256) {
    int r = i >> 4, j = i & 15;
    winU[r * 17 + j] = retc[(size_t)(pwin0 + r) * 16 + j];
  }

  // ---- k row per lane (y = wvid*64 + lane) ----
  int yy = wvid * 64 + lane;
  int yc = min(yy, WPOS - 1);
  bool yok = (yy < WPOS);
  const float* zb = z + ((size_t)bb * NCH + h * 64) * WPOS;
  float kreg[16];
#pragma unroll
  for (int d = 0; d < 16; ++d) kreg[d] = zb[(size_t)d * WPOS + yc];
  __syncthreads();

  // ---- fused S: qk + qr + kr in one pass; lanes on y, loop over x ----
  for (int xx = 0; xx < nr; ++xx) {
    int x = x0 + xx;
    const float4* q4 = (const float4*)(qt + ((size_t)bbh * WPOS + x) * 16);  // uniform row
    float qv[16];
    *(float4*)&qv[0]  = q4[0];
    *(float4*)&qv[4]  = q4[1];
    *(float4*)&qv[8]  = q4[2];
    *(float4*)&qv[12] = q4[3];
    const unsigned* wr = &winU[(size_t)(yc - x + 250 - pwin0) * 17];
    float dqk0 = 0.f, dqk1 = 0.f, dqr0 = 0.f, dqr1 = 0.f, dkr0 = 0.f, dkr1 = 0.f;
#pragma unroll
    for (int j = 0; j < 8; ++j) {
      unsigned uq = wr[j], uk = wr[j + 8];
      float qe0 = __uint_as_float(uq << 16);
      float qe1 = __uint_as_float(uq & 0xffff0000u);
      float ke0 = __uint_as_float(uk << 16);
      float ke1 = __uint_as_float(uk & 0xffff0000u);
      float q0 = qv[2 * j], q1 = qv[2 * j + 1];
      float k0 = kreg[2 * j], k1 = kreg[2 * j + 1];
      dqk0 += q0 * k0;  dqk1 += q1 * k1;
      dqr0 += q0 * qe0; dqr1 += q1 * qe1;
      dkr0 += k0 * ke0; dkr1 += k1 * ke1;
    }
    if (yok)
      S[xx][yy] = la_qk * (dqk0 + dqk1) + la_qr * (dqr0 + dqr1)
                + la_kr * (dkr0 + dkr1) + lbsum;
  }
  __syncthreads();

  // ---- softmax over y; lanes on x, 8 slices of ~32 y ----
  int xx = lane & 31;
  int sl = wvid * 2 + (lane >> 5);
  int ylo = sl * 32;
  int yhi = min(ylo + 32, WPOS);
  {
    float m = -1e30f;
    for (int y2 = ylo; y2 < yhi; ++y2) m = fmaxf(m, S[xx][y2]);
    smax[sl][xx] = m;
  }
  __syncthreads();
  float rowm = smax[0][xx];
#pragma unroll
  for (int s = 1; s < 8; ++s) rowm = fmaxf(rowm, smax[s][xx]);
  __syncthreads();                      // protect smax reuse
  {
    float sacc = 0.f;
    for (int y2 = ylo; y2 < yhi; ++y2) {
      float e = __expf(S[xx][y2] - rowm);
      S[xx][y2] = e;
      sacc += e;
    }
    smax[sl][xx] = sacc;
  }
  __syncthreads();
  float denom = 0.f;
#pragma unroll
  for (int s = 0; s < 8; ++s) denom += smax[s][xx];

  // ---- attention: group g = 4 d-channels, lanes on x ----
  int d0 = sl * 4;
  const float* Srow = &S[xx][0];
  float4 acc = {0.f, 0.f, 0.f, 0.f};
  {
    const float* vb = vt + (size_t)bbh * WPOS * 32 + d0;
    int y2 = 0;
    for (; y2 + 3 < WPOS; y2 += 4) {
      float w0 = Srow[y2], w1 = Srow[y2 + 1], w2 = Srow[y2 + 2], w3 = Srow[y2 + 3];
      float4 v0 = *(const float4*)(vb + (size_t)(y2 + 0) * 32);
      float4 v1 = *(const float4*)(vb + (size_t)(y2 + 1) * 32);
      float4 v2 = *(const float4*)(vb + (size_t)(y2 + 2) * 32);
      float4 v3 = *(const float4*)(vb + (size_t)(y2 + 3) * 32);
      acc.x += w0 * v0.x + w1 * v1.x + w2 * v2.x + w3 * v3.x;
      acc.y += w0 * v0.y + w1 * v1.y + w2 * v2.y + w3 * v3.y;
      acc.z += w0 * v0.z + w1 * v1.z + w2 * v2.z + w3 * v3.z;
      acc.w += w0 * v0.w + w1 * v1.w + w2 * v2.w + w3 * v3.w;
    }
    for (; y2 < WPOS; ++y2) {
      float w0 = Srow[y2];
      float4 v0 = *(const float4*)(vb + (size_t)y2 * 32);
      acc.x += w0 * v0.x; acc.y += w0 * v0.y;
      acc.z += w0 * v0.z; acc.w += w0 * v0.w;
    }
  }
  {
    int xg = x0 + xx;
    int pmin = max(0, 250 - (x0 + nr - 1));
    int pmax = 500 - x0;
    int pi0 = max(pmin, 250 - x0);       // all-lane y2 >= 0
    int pi1 = min(pmax, 466 - x0);       // all-lane y2+3 <= 250
    const float* veb = vet + d0;
    int p = pmin;
    for (; p < pi0; ++p) {
      int y2 = xg + p - 250;
      float w0 = ((unsigned)y2 < (unsigned)WPOS) ? Srow[y2] : 0.f;
      float4 v0 = *(const float4*)(veb + (size_t)p * 32);
      acc.x += w0 * v0.x; acc.y += w0 * v0.y;
      acc.z += w0 * v0.z; acc.w += w0 * v0.w;
    }
    for (; p + 3 <= pi1; p += 4) {
      int y2 = xg + p - 250;
      float w0 = Srow[y2], w1 = Srow[y2 + 1], w2 = Srow[y2 + 2], w3 = Srow[y2 + 3];
      float4 v0 = *(const float4*)(veb + (size_t)(p + 0) * 32);
      float4 v1 = *(const float4*)(veb + (size_t)(p + 1) * 32);
      float4 v2 = *(const float4*)(veb + (size_t)(p + 2) * 32);
      float4 v3 = *(const float4*)(veb + (size_t)(p + 3) * 32);
      acc.x += w0 * v0.x + w1 * v1.x + w2 * v2.x + w3 * v3.x;
      acc.y += w0 * v0.y + w1 * v1.y + w2 * v2.y + w3 * v3.y;
      acc.z += w0 * v0.z + w1 * v1.z + w2 * v2.z + w3 * v3.z;
      acc.w += w0 * v0.w + w1 * v1.w + w2 * v2.w + w3 * v3.w;
    }
    for (; p <= pmax; ++p) {
      int y2 = xg + p - 250;
      float w0 = ((unsigned)y2 < (unsigned)WPOS) ? Srow[y2] : 0.f;
      float4 v0 = *(const float4*)(veb + (size_t)p * 32);
      acc.x += w0 * v0.x; acc.y += w0 * v0.y;
      acc.z += w0 * v0.z; acc.w += w0 * v0.w;
    }
  }
  if (xx < nr) {
    float rinv = 1.0f / denom;
    int xg = x0 + xx;
    float av[4] = {acc.x, acc.y, acc.z, acc.w};
#pragma unroll
    for (int dd = 0; dd < 4; ++dd) {
      int d = d0 + dd;
      out[(((size_t)b * 256 + h * 32 + d) * 15 + hi) * WPOS + xg] = av[dd] * rinv;
    }
  }
}

// ---------------- launch ----------------
extern "C" void kernel_launch(void* const* d_in, const int* in_sizes, int n_in,
                              void* d_out, int out_size, void* d_ws, size_t ws_size,
                              hipStream_t stream) {
  const float* x    = (const float*)d_in[0];
  const float* y    = (const float*)d_in[1];
  const float* wk   = (const float*)d_in[2];
  const float* wq   = (const float*)d_in[3];
  const float* wv   = (const float*)d_in[4];
  const float* gk   = (const float*)d_in[5];
  const float* bk   = (const float*)d_in[6];
  const float* gq   = (const float*)d_in[7];
  const float* bq   = (const float*)d_in[8];
  const float* gkq  = (const float*)d_in[9];
  const float* bkq  = (const float*)d_in[10];
  const float* glog = (const float*)d_in[11];
  const float* blog = (const float*)d_in[12];
  const float* rel  = (const float*)d_in[13];
  float* out = (float*)d_out;
  float* ws  = (float*)d_ws;

  float* z      = ws + OFF_Z;
  float* qt     = ws + OFF_QT;
  float* vt     = ws + OFF_VT;
  unsigned* retc= (unsigned*)(ws + OFF_RETC);
  float* vet    = ws + OFF_VET;
  float* p1q    = ws + OFF_P1Q;
  float* p1k    = ws + OFF_P1K;
  float* p2q    = ws + OFF_P2Q;
  float* p2k    = ws + OFF_P2K;
  float* ca     = ws + OFF_CA;
  float* cb     = ws + OFF_CB;
  float* lp     = ws + OFF_LP;
  float* lab    = ws + OFF_LAB;

  dim3 g1(4, 8, NBB);
  k_gemm<<<g1, 256, 0, stream>>>(x, y, wk, wq, wv, z);
  k_chan_stats<<<512, 256, 0, stream>>>(z, gk, bk, gq, bq, gkq, bkq, ca, cb);
  k_norm_scatter<<<(int)((SZ_Z + 255) / 256), 256, 0, stream>>>(z, ca, cb, qt, vt);
  k_rel_prep<<<(RELP * 48 + 255) / 256, 256, 0, stream>>>(rel, retc, vet);
  k_prefix<<<544, 256, 0, stream>>>(rel, p1q, p1k, p2q, p2k);
  k_logit_stats<<<240, 256, 0, stream>>>(z, p1q, p1k, p2q, p2k, lp);
  k_logit_final<<<1, 32, 0, stream>>>(lp, glog, blog, lab);
  k_attn<<<240 * 8, 256, 0, stream>>>(z, qt, vt, retc, vet, lab, out);
}

// Round 4
// 297.307 us; speedup vs baseline: 2.3821x; 1.1682x over previous
//
#include <hip/hip_runtime.h>
#include <hip/hip_bf16.h>
#include <cstdint>

#define WPOS 251
#define NBB  30
#define NCH  512
#define RELP 501
#define NEPS 1e-5f

// ---------------- workspace layout (in float slots) ----------------
static constexpr size_t SZ_Z     = (size_t)NBB * NCH * WPOS;
static constexpr size_t OFF_Z    = 0;
static constexpr size_t OFF_VT   = OFF_Z + SZ_Z;                   // [bbh][y][32] normalized v
static constexpr size_t SZ_VT    = (size_t)NBB * 8 * WPOS * 32;
static constexpr size_t OFF_RETC = OFF_VT + SZ_VT;                 // uint[501][16]: qe|keR bf16 pairs
static constexpr size_t OFF_VET  = OFF_RETC + (size_t)RELP * 16;   // f32 [501][32]
static constexpr size_t OFF_P1Q  = OFF_VET + (size_t)RELP * 32;    // [16][502]
static constexpr size_t OFF_P1K  = OFF_P1Q + (size_t)16 * 502;
static constexpr size_t OFF_P2Q  = OFF_P1K + (size_t)16 * 502;     // [256][502]
static constexpr size_t OFF_P2K  = OFF_P2Q + (size_t)256 * 502;
static constexpr size_t OFF_CA   = OFF_P2K + (size_t)256 * 502;    // [512]
static constexpr size_t OFF_CB   = OFF_CA + 512;
static constexpr size_t OFF_LP   = OFF_CB + 512;                   // [240][6]
static constexpr size_t OFF_LAB  = OFF_LP + (size_t)240 * 6;       // [24][2]

static __device__ __forceinline__ unsigned short f2bf(float f) {
  __hip_bfloat16 h = __float2bfloat16(f);
  return *reinterpret_cast<unsigned short*>(&h);
}

// ---------------- K1: kqv GEMM: Z[bb][o][l] (raw, pre-BN) ----------------
__global__ __launch_bounds__(256) void k_gemm(
    const float* __restrict__ x, const float* __restrict__ y,
    const float* __restrict__ wk, const float* __restrict__ wq,
    const float* __restrict__ wv, float* __restrict__ z) {
  int l0 = blockIdx.x * 64;
  int o0 = blockIdx.y * 64;
  int bb = blockIdx.z;
  int b = bb / 15, hi = bb % 15;
  const float* src;
  const float* wmat;
  int orow0;
  if (o0 < 128)      { wmat = wk; orow0 = o0;       src = x; }
  else if (o0 < 256) { wmat = wq; orow0 = o0 - 128; src = y; }
  else               { wmat = wv; orow0 = o0 - 256; src = x; }

  __shared__ float Ws[32][65];
  __shared__ float Xs[32][65];
  int tid = threadIdx.x;
  int tx = tid & 15, ty = tid >> 4;
  float acc[4][4] = {};

  for (int c0 = 0; c0 < 256; c0 += 32) {
#pragma unroll
    for (int r = 0; r < 8; ++r) {
      int idx = tid + r * 256;
      int oo = idx >> 5, cc = idx & 31;
      Ws[cc][oo] = wmat[(size_t)(orow0 + oo) * 256 + c0 + cc];
    }
#pragma unroll
    for (int r = 0; r < 8; ++r) {
      int idx = tid + r * 256;
      int cc = idx >> 6, ll = idx & 63;
      int l = l0 + ll;
      float v = 0.f;
      if (l < WPOS)
        v = src[(((size_t)b * 256 + c0 + cc) * 15 + hi) * WPOS + l];
      Xs[cc][ll] = v;
    }
    __syncthreads();
#pragma unroll
    for (int cc = 0; cc < 32; ++cc) {
      float rw[4], rx[4];
#pragma unroll
      for (int i = 0; i < 4; ++i) rw[i] = Ws[cc][ty * 4 + i];
#pragma unroll
      for (int j = 0; j < 4; ++j) rx[j] = Xs[cc][tx * 4 + j];
#pragma unroll
      for (int i = 0; i < 4; ++i)
#pragma unroll
        for (int j = 0; j < 4; ++j) acc[i][j] += rw[i] * rx[j];
    }
    __syncthreads();
  }
#pragma unroll
  for (int i = 0; i < 4; ++i) {
    int o = o0 + ty * 4 + i;
#pragma unroll
    for (int j = 0; j < 4; ++j) {
      int l = l0 + tx * 4 + j;
      if (l < WPOS) z[((size_t)bb * NCH + o) * WPOS + l] = acc[i][j];
    }
  }
}

// ---------------- K2: per-channel BN stats -> affine a,b ----------------
__global__ __launch_bounds__(256) void k_chan_stats(
    const float* __restrict__ z,
    const float* __restrict__ gk, const float* __restrict__ bk,
    const float* __restrict__ gq, const float* __restrict__ bq,
    const float* __restrict__ gkq, const float* __restrict__ bkq,
    float* __restrict__ ca, float* __restrict__ cb) {
  int o = blockIdx.x;
  int tid = threadIdx.x;
  float s = 0.f, s2 = 0.f;
  for (int idx = tid; idx < NBB * WPOS; idx += 256) {
    int bb = idx / WPOS, l = idx - bb * WPOS;
    float v = z[((size_t)bb * NCH + o) * WPOS + l];
    s += v; s2 += v * v;
  }
  __shared__ float r1[256], r2[256];
  r1[tid] = s; r2[tid] = s2; __syncthreads();
  for (int st = 128; st > 0; st >>= 1) {
    if (tid < st) { r1[tid] += r1[tid + st]; r2[tid] += r2[tid + st]; }
    __syncthreads();
  }
  if (tid == 0) {
    float n = (float)(NBB * WPOS);
    float mean = r1[0] / n;
    float var = r2[0] / n - mean * mean;
    float g, bi;
    if (o < 128)      { g = gk[o];        bi = bk[o]; }
    else if (o < 256) { g = gq[o - 128];  bi = bq[o - 128]; }
    else              { g = gkq[o - 256]; bi = bkq[o - 256]; }
    float a = g / sqrtf(var + NEPS);
    ca[o] = a;
    cb[o] = bi - mean * a;
  }
}

// ---------------- K3: normalized v -> vt[bbh][y][32] (tiled transpose) ----------------
__global__ __launch_bounds__(256) void k_norm_v(
    const float* __restrict__ z, const float* __restrict__ ca, const float* __restrict__ cb,
    float* __restrict__ vt) {
  int blk = blockIdx.x;            // 960 = 4 ltile * 240 bbh, bbh fastest (XCD locality)
  int bbh = blk % 240, lt = blk / 240;
  int bb = bbh >> 3, h = bbh & 7;
  int l0 = lt * 64;
  int nl = min(64, WPOS - l0);
  __shared__ float T[32][65];
  int tid = threadIdx.x;
  const float* zv = z + ((size_t)bb * NCH + h * 64 + 32) * WPOS;
  for (int i = tid; i < 32 * 64; i += 256) {
    int ch = i >> 6, l = i & 63;
    int ll = min(l0 + l, WPOS - 1);
    int cch = h * 64 + 32 + ch;
    T[ch][l] = ca[cch] * zv[(size_t)ch * WPOS + ll] + cb[cch];
  }
  __syncthreads();
  for (int i = tid; i < 64 * 32; i += 256) {
    int l = i >> 5, ch = i & 31;
    if (l < nl) vt[((size_t)bbh * WPOS + l0 + l) * 32 + ch] = T[ch][l];
  }
}

// ---------------- K4: rel prep: combined bf16 qe|keR table + vet ----------------
__global__ void k_rel_prep(const float* __restrict__ rel, unsigned* __restrict__ retc,
                           float* __restrict__ vet) {
  int idx = blockIdx.x * 256 + threadIdx.x;
  if (idx >= RELP * 48) return;
  int p = idx / 48, j = idx - p * 48;
  if (j < 16) {
    float lo, hi;
    if (j < 8) {
      lo = rel[(size_t)(2 * j) * RELP + p];
      hi = rel[(size_t)(2 * j + 1) * RELP + p];
    } else {
      int jj = j - 8;
      lo = rel[(size_t)(16 + 2 * jj) * RELP + (500 - p)];
      hi = rel[(size_t)(17 + 2 * jj) * RELP + (500 - p)];
    }
    retc[(size_t)p * 16 + j] = ((unsigned)f2bf(hi) << 16) | (unsigned)f2bf(lo);
  } else {
    int dd = j - 16;
    vet[(size_t)p * 32 + dd] = rel[(size_t)(32 + dd) * RELP + p];
  }
}

// ---------------- K5: prefix sums (parallel pair + Hillis-Steele scan) ----------------
__global__ __launch_bounds__(256) void k_prefix(const float* __restrict__ rel,
                                                float* __restrict__ p1q, float* __restrict__ p1k,
                                                float* __restrict__ p2q, float* __restrict__ p2k) {
  int task = blockIdx.x;   // 0..543
  const float* ra;
  const float* rb = nullptr;
  float* outp;
  if (task < 16)        { ra = rel + (size_t)task * RELP; outp = p1q + (size_t)task * 502; }
  else if (task < 32)   { ra = rel + (size_t)task * RELP; outp = p1k + (size_t)(task - 16) * 502; }
  else if (task < 288)  { int pr = task - 32;
                          ra = rel + (size_t)(pr >> 4) * RELP;
                          rb = rel + (size_t)(pr & 15) * RELP;
                          outp = p2q + (size_t)pr * 502; }
  else                  { int pr = task - 288;
                          ra = rel + (size_t)(16 + (pr >> 4)) * RELP;
                          rb = rel + (size_t)(16 + (pr & 15)) * RELP;
                          outp = p2k + (size_t)pr * 502; }
  __shared__ float buf[256];
  int t = threadIdx.x;
  int i0 = 2 * t, i1 = 2 * t + 1;
  float a0 = (i0 < RELP) ? (rb ? ra[i0] * rb[i0] : ra[i0]) : 0.f;
  float a1 = (i1 < RELP) ? (rb ? ra[i1] * rb[i1] : ra[i1]) : 0.f;
  buf[t] = a0 + a1;
  __syncthreads();
#pragma unroll
  for (int off = 1; off < 256; off <<= 1) {
    float v = buf[t];
    float add = (t >= off) ? buf[t - off] : 0.f;
    __syncthreads();
    buf[t] = v + add;
    __syncthreads();
  }
  float ex = buf[t] - (a0 + a1);          // exclusive scan over pairs
  if (i0 <= RELP) outp[i0] = ex;
  if (i1 <= RELP) outp[i1] = ex + a0;
}

// ---------------- block reduce helper ----------------
__device__ __forceinline__ float block_reduce(float v, float* red, int tid) {
  red[tid] = v; __syncthreads();
  for (int s = 128; s > 0; s >>= 1) {
    if (tid < s) red[tid] += red[tid + s];
    __syncthreads();
  }
  float r = red[0]; __syncthreads();
  return r;
}

// ---------------- K6: logit BN stats per (bb,h) (affine at staging) ----------------
__global__ __launch_bounds__(256) void k_logit_stats(
    const float* __restrict__ z, const float* __restrict__ ca, const float* __restrict__ cb,
    const float* __restrict__ p1q, const float* __restrict__ p1k,
    const float* __restrict__ p2q, const float* __restrict__ p2k,
    float* __restrict__ lp) {
  int bbh = blockIdx.x;
  int bb = bbh >> 3, h = bbh & 7;
  int tid = threadIdx.x;
  __shared__ float qs[16][257], ks[16][257];
  __shared__ float Qg[256], Kg[256];
  __shared__ float red[256];
  __shared__ float qsum[16], ksum[16];

  const float* zb = z + ((size_t)bb * NCH + h * 64) * WPOS;
  for (int idx = tid; idx < 16 * WPOS; idx += 256) {
    int d = idx / WPOS, xx = idx - d * WPOS;
    int chk = h * 64 + d, chq = h * 64 + 16 + d;
    ks[d][xx] = ca[chk] * zb[(size_t)d * WPOS + xx] + cb[chk];
    qs[d][xx] = ca[chq] * zb[(size_t)(16 + d) * WPOS + xx] + cb[chq];
  }
  __syncthreads();
  if (tid < 16) {
    float s = 0.f;
    for (int xx = 0; xx < WPOS; ++xx) s += qs[tid][xx];
    qsum[tid] = s;
  } else if (tid < 32) {
    float s = 0.f;
    for (int xx = 0; xx < WPOS; ++xx) s += ks[tid - 16][xx];
    ksum[tid - 16] = s;
  }
  {
    int d = tid >> 4, d2 = tid & 15;
    float g1 = 0.f, g2 = 0.f;
    for (int xx = 0; xx < WPOS; ++xx) {
      g1 += qs[d][xx] * qs[d2][xx];
      g2 += ks[d][xx] * ks[d2][xx];
    }
    Qg[tid] = g1; Kg[tid] = g2;
  }
  __syncthreads();

  float v_sqqk = Qg[tid] * Kg[tid];
  float v_sumqr = 0.f, v_sqqr = 0.f, v_sumkr = 0.f, v_sqkr = 0.f;
  for (int idx = tid; idx < 16 * WPOS; idx += 256) {
    int d = idx / WPOS, xx = idx - d * WPOS;
    int ihi = 501 - xx, ilo = 250 - xx;
    float qv = qs[d][xx];
    v_sumqr += qv * (p1q[d * 502 + ihi] - p1q[d * 502 + ilo]);
    float t = 0.f;
    for (int d2 = 0; d2 < 16; ++d2) {
      const float* pp = p2q + (size_t)(d * 16 + d2) * 502;
      t += qs[d2][xx] * (pp[ihi] - pp[ilo]);
    }
    v_sqqr += qv * t;
    float kv = ks[d][xx];
    v_sumkr += kv * (p1k[d * 502 + ihi] - p1k[d * 502 + ilo]);
    float t2 = 0.f;
    for (int d2 = 0; d2 < 16; ++d2) {
      const float* pp = p2k + (size_t)(d * 16 + d2) * 502;
      t2 += ks[d2][xx] * (pp[ihi] - pp[ilo]);
    }
    v_sqkr += kv * t2;
  }
  float r_sqqk  = block_reduce(v_sqqk, red, tid);
  float r_sumqr = block_reduce(v_sumqr, red, tid);
  float r_sqqr  = block_reduce(v_sqqr, red, tid);
  float r_sumkr = block_reduce(v_sumkr, red, tid);
  float r_sqkr  = block_reduce(v_sqkr, red, tid);
  if (tid == 0) {
    float sum_qk = 0.f;
    for (int d = 0; d < 16; ++d) sum_qk += qsum[d] * ksum[d];
    float* o = lp + (size_t)bbh * 6;
    o[0] = sum_qk; o[1] = r_sqqk;
    o[2] = r_sumqr; o[3] = r_sqqr;
    o[4] = r_sumkr; o[5] = r_sqkr;
  }
}

// ---------------- K7: finalize logit BN affine ----------------
__global__ void k_logit_final(const float* __restrict__ lp,
                              const float* __restrict__ glog, const float* __restrict__ blog,
                              float* __restrict__ lab) {
  int c = threadIdx.x;
  if (c >= 24) return;
  int grp = c >> 3, h = c & 7;
  float s = 0.f, s2 = 0.f;
  for (int bb = 0; bb < NBB; ++bb) {
    const float* o = lp + (size_t)(bb * 8 + h) * 6 + grp * 2;
    s += o[0]; s2 += o[1];
  }
  float n = (float)NBB * (float)WPOS * (float)WPOS;
  float mean = s / n;
  float var = s2 / n - mean * mean;
  float la = glog[c] / sqrtf(var + NEPS);
  lab[c * 2] = la;
  lab[c * 2 + 1] = blog[c] - mean * la;
}

// ---------------- K8: fused logits + softmax + attention ----------------
// 1920 blocks = 8 tiles x 240 bbh, bbh fastest -> blk%8 == bbh%8 (XCD locality).
__global__ __launch_bounds__(256) void k_attn(
    const float* __restrict__ z, const float* __restrict__ ca, const float* __restrict__ cb,
    const float* __restrict__ vt,
    const unsigned* __restrict__ retc, const float* __restrict__ vet,
    const float* __restrict__ lab, float* __restrict__ out) {
  int blk = blockIdx.x;
  int bbh = blk % 240, tile = blk / 240;
  int bb = bbh >> 3, h = bbh & 7;
  int b = bb / 15, hi = bb % 15;
  int x0 = tile * 32;
  int nr = min(32, WPOS - x0);
  int tid = threadIdx.x;
  int lane = tid & 63, wvid = tid >> 6;

  float la_qk = lab[h * 2],        lb0 = lab[h * 2 + 1];
  float la_qr = lab[(8 + h) * 2],  lb1 = lab[(8 + h) * 2 + 1];
  float la_kr = lab[(16 + h) * 2], lb2 = lab[(16 + h) * 2 + 1];
  float lbsum = lb0 + lb1 + lb2;

  __shared__ float S[32][251];          // 32,128 B
  __shared__ unsigned winU[282 * 17];   // 19,176 B
  __shared__ unsigned qsP[32][9];       // 1,152 B  bf16-pair q rows
  __shared__ float smax[8][32];         // 1,024 B  (reused for sums)

  int pwin0 = 251 - x0 - nr;
  int nwin = 250 + nr;

  const float* zb = z + ((size_t)bb * NCH + h * 64) * WPOS;

  // ---- stage rel window into LDS (coalesced, L2-resident) ----
  for (int i = tid; i < nwin * 16; i += 256) {
    int r = i >> 4, j = i & 15;
    winU[r * 17 + j] = retc[(size_t)(pwin0 + r) * 16 + j];
  }

  // ---- stage q tile (affine from raw z, bf16-packed) ----
  {
    int xx = tid & 31, j = tid >> 5;          // j 0..7
    int xcl = min(x0 + xx, WPOS - 1);
    int ch0 = h * 64 + 16 + 2 * j;
    float q0 = ca[ch0]     * zb[(size_t)(16 + 2 * j) * WPOS + xcl] + cb[ch0];
    float q1 = ca[ch0 + 1] * zb[(size_t)(17 + 2 * j) * WPOS + xcl] + cb[ch0 + 1];
    qsP[xx][j] = ((unsigned)f2bf(q1) << 16) | (unsigned)f2bf(q0);
  }

  // ---- k row per lane (affine from raw z) ----
  int yy = wvid * 64 + lane;
  int yc = min(yy, WPOS - 1);
  bool yok = (yy < WPOS);
  float kreg[16];
#pragma unroll
  for (int d = 0; d < 16; ++d) {
    int ch = h * 64 + d;
    kreg[d] = ca[ch] * zb[(size_t)d * WPOS + yc] + cb[ch];
  }
  __syncthreads();

  // ---- fused S: qk + qr + kr; lanes on y, loop over x ----
  for (int xx = 0; xx < nr; ++xx) {
    int x = x0 + xx;
    const unsigned* wr = &winU[(size_t)(yc - x + 250 - pwin0) * 17];
    float dqk0 = 0.f, dqk1 = 0.f, dqr0 = 0.f, dqr1 = 0.f, dkr0 = 0.f, dkr1 = 0.f;
#pragma unroll
    for (int j = 0; j < 8; ++j) {
      unsigned uq = wr[j], uk = wr[j + 8], uu = qsP[xx][j];
      float qe0 = __uint_as_float(uq << 16);
      float qe1 = __uint_as_float(uq & 0xffff0000u);
      float ke0 = __uint_as_float(uk << 16);
      float ke1 = __uint_as_float(uk & 0xffff0000u);
      float q0  = __uint_as_float(uu << 16);
      float q1  = __uint_as_float(uu & 0xffff0000u);
      float k0 = kreg[2 * j], k1 = kreg[2 * j + 1];
      dqk0 += q0 * k0;  dqk1 += q1 * k1;
      dqr0 += q0 * qe0; dqr1 += q1 * qe1;
      dkr0 += k0 * ke0; dkr1 += k1 * ke1;
    }
    if (yok)
      S[xx][yy] = la_qk * (dqk0 + dqk1) + la_qr * (dqr0 + dqr1)
                + la_kr * (dkr0 + dkr1) + lbsum;
  }
  __syncthreads();

  // ---- softmax over y; lanes on x, 8 slices of ~32 y ----
  int xx = lane & 31;
  int sl = wvid * 2 + (lane >> 5);
  int ylo = sl * 32;
  int yhi = min(ylo + 32, WPOS);
  {
    float m = -1e30f;
    for (int y2 = ylo; y2 < yhi; ++y2) m = fmaxf(m, S[xx][y2]);
    smax[sl][xx] = m;
  }
  __syncthreads();
  float rowm = smax[0][xx];
#pragma unroll
  for (int s = 1; s < 8; ++s) rowm = fmaxf(rowm, smax[s][xx]);
  __syncthreads();
  {
    float sacc = 0.f;
    for (int y2 = ylo; y2 < yhi; ++y2) {
      float e = __expf(S[xx][y2] - rowm);
      S[xx][y2] = e;
      sacc += e;
    }
    smax[sl][xx] = sacc;
  }
  __syncthreads();
  float denom = 0.f;
#pragma unroll
  for (int s = 0; s < 8; ++s) denom += smax[s][xx];

  // ---- attention: group sl = 4 d-channels, lanes on x ----
  int d0 = sl * 4;
  const float* Srow = &S[xx][0];
  float4 acc = {0.f, 0.f, 0.f, 0.f};
  {
    const float* vb = vt + (size_t)bbh * WPOS * 32 + d0;
    int y2 = 0;
    for (; y2 + 3 < WPOS; y2 += 4) {
      float w0 = Srow[y2], w1 = Srow[y2 + 1], w2 = Srow[y2 + 2], w3 = Srow[y2 + 3];
      float4 v0 = *(const float4*)(vb + (size_t)(y2 + 0) * 32);
      float4 v1 = *(const float4*)(vb + (size_t)(y2 + 1) * 32);
      float4 v2 = *(const float4*)(vb + (size_t)(y2 + 2) * 32);
      float4 v3 = *(const float4*)(vb + (size_t)(y2 + 3) * 32);
      acc.x += w0 * v0.x + w1 * v1.x + w2 * v2.x + w3 * v3.x;
      acc.y += w0 * v0.y + w1 * v1.y + w2 * v2.y + w3 * v3.y;
      acc.z += w0 * v0.z + w1 * v1.z + w2 * v2.z + w3 * v3.z;
      acc.w += w0 * v0.w + w1 * v1.w + w2 * v2.w + w3 * v3.w;
    }
    for (; y2 < WPOS; ++y2) {
      float w0 = Srow[y2];
      float4 v0 = *(const float4*)(vb + (size_t)y2 * 32);
      acc.x += w0 * v0.x; acc.y += w0 * v0.y;
      acc.z += w0 * v0.z; acc.w += w0 * v0.w;
    }
  }
  {
    int xg = x0 + xx;
    int pmin = max(0, 250 - (x0 + nr - 1));
    int pmax = 500 - x0;
    int pi0 = max(pmin, 250 - x0);
    int pi1 = min(pmax, 466 - x0);
    const float* veb = vet + d0;
    int p = pmin;
    for (; p < pi0; ++p) {
      int y2 = xg + p - 250;
      float w0 = ((unsigned)y2 < (unsigned)WPOS) ? Srow[y2] : 0.f;
      float4 v0 = *(const float4*)(veb + (size_t)p * 32);
      acc.x += w0 * v0.x; acc.y += w0 * v0.y;
      acc.z += w0 * v0.z; acc.w += w0 * v0.w;
    }
    for (; p + 3 <= pi1; p += 4) {
      int y2 = xg + p - 250;
      float w0 = Srow[y2], w1 = Srow[y2 + 1], w2 = Srow[y2 + 2], w3 = Srow[y2 + 3];
      float4 v0 = *(const float4*)(veb + (size_t)(p + 0) * 32);
      float4 v1 = *(const float4*)(veb + (size_t)(p + 1) * 32);
      float4 v2 = *(const float4*)(veb + (size_t)(p + 2) * 32);
      float4 v3 = *(const float4*)(veb + (size_t)(p + 3) * 32);
      acc.x += w0 * v0.x + w1 * v1.x + w2 * v2.x + w3 * v3.x;
      acc.y += w0 * v0.y + w1 * v1.y + w2 * v2.y + w3 * v3.y;
      acc.z += w0 * v0.z + w1 * v1.z + w2 * v2.z + w3 * v3.z;
      acc.w += w0 * v0.w + w1 * v1.w + w2 * v2.w + w3 * v3.w;
    }
    for (; p <= pmax; ++p) {
      int y2 = xg + p - 250;
      float w0 = ((unsigned)y2 < (unsigned)WPOS) ? Srow[y2] : 0.f;
      float4 v0 = *(const float4*)(veb + (size_t)p * 32);
      acc.x += w0 * v0.x; acc.y += w0 * v0.y;
      acc.z += w0 * v0.z; acc.w += w0 * v0.w;
    }
  }
  if (xx < nr) {
    float rinv = 1.0f / denom;
    int xg = x0 + xx;
    float av[4] = {acc.x, acc.y, acc.z, acc.w};
#pragma unroll
    for (int dd = 0; dd < 4; ++dd) {
      int d = d0 + dd;
      out[(((size_t)b * 256 + h * 32 + d) * 15 + hi) * WPOS + xg] = av[dd] * rinv;
    }
  }
}

// ---------------- launch ----------------
extern "C" void kernel_launch(void* const* d_in, const int* in_sizes, int n_in,
                              void* d_out, int out_size, void* d_ws, size_t ws_size,
                              hipStream_t stream) {
  const float* x    = (const float*)d_in[0];
  const float* y    = (const float*)d_in[1];
  const float* wk   = (const float*)d_in[2];
  const float* wq   = (const float*)d_in[3];
  const float* wv   = (const float*)d_in[4];
  const float* gk   = (const float*)d_in[5];
  const float* bk   = (const float*)d_in[6];
  const float* gq   = (const float*)d_in[7];
  const float* bq   = (const float*)d_in[8];
  const float* gkq  = (const float*)d_in[9];
  const float* bkq  = (const float*)d_in[10];
  const float* glog = (const float*)d_in[11];
  const float* blog = (const float*)d_in[12];
  const float* rel  = (const float*)d_in[13];
  float* out = (float*)d_out;
  float* ws  = (float*)d_ws;

  float* z      = ws + OFF_Z;
  float* vt     = ws + OFF_VT;
  unsigned* retc= (unsigned*)(ws + OFF_RETC);
  float* vet    = ws + OFF_VET;
  float* p1q    = ws + OFF_P1Q;
  float* p1k    = ws + OFF_P1K;
  float* p2q    = ws + OFF_P2Q;
  float* p2k    = ws + OFF_P2K;
  float* ca     = ws + OFF_CA;
  float* cb     = ws + OFF_CB;
  float* lp     = ws + OFF_LP;
  float* lab    = ws + OFF_LAB;

  dim3 g1(4, 8, NBB);
  k_gemm<<<g1, 256, 0, stream>>>(x, y, wk, wq, wv, z);
  k_chan_stats<<<512, 256, 0, stream>>>(z, gk, bk, gq, bq, gkq, bkq, ca, cb);
  k_norm_v<<<960, 256, 0, stream>>>(z, ca, cb, vt);
  k_rel_prep<<<(RELP * 48 + 255) / 256, 256, 0, stream>>>(rel, retc, vet);
  k_prefix<<<544, 256, 0, stream>>>(rel, p1q, p1k, p2q, p2k);
  k_logit_stats<<<240, 256, 0, stream>>>(z, ca, cb, p1q, p1k, p2q, p2k, lp);
  k_logit_final<<<1, 32, 0, stream>>>(lp, glog, blog, lab);
  k_attn<<<240 * 8, 256, 0, stream>>>(z, ca, cb, vt, retc, vet, lab, out);
}

// Round 5
// 284.575 us; speedup vs baseline: 2.4887x; 1.0447x over previous
//
#include <hip/hip_runtime.h>
#include <hip/hip_bf16.h>
#include <cstdint>

#define WPOS 251
#define NBB  30
#define NCH  512
#define RELP 501
#define NEPS 1e-5f

typedef _Float16 half2_t __attribute__((ext_vector_type(2)));

#if defined(__has_builtin)
#if __has_builtin(__builtin_amdgcn_fdot2)
#define FDOT2(a, b, c) __builtin_amdgcn_fdot2((a), (b), (c), false)
#endif
#endif
#ifndef FDOT2
#define FDOT2(a, b, c) ((float)(a)[0] * (float)(b)[0] + (float)(a)[1] * (float)(b)[1] + (c))
#endif

// ---------------- workspace layout (in float slots) ----------------
static constexpr size_t SZ_Z     = (size_t)NBB * NCH * WPOS;
static constexpr size_t OFF_Z    = 0;
static constexpr size_t OFF_VT   = OFF_Z + SZ_Z;                   // [bbh][y][32] normalized v
static constexpr size_t SZ_VT    = (size_t)NBB * 8 * WPOS * 32;
static constexpr size_t OFF_RETC = OFF_VT + SZ_VT;                 // uint[501][16]: qe|keR fp16 pairs
static constexpr size_t OFF_VET  = OFF_RETC + (size_t)RELP * 16;   // f32 [501][32]
static constexpr size_t OFF_P1Q  = OFF_VET + (size_t)RELP * 32;    // [16][502]
static constexpr size_t OFF_P1K  = OFF_P1Q + (size_t)16 * 502;
static constexpr size_t OFF_P2Q  = OFF_P1K + (size_t)16 * 502;     // [256][502]
static constexpr size_t OFF_P2K  = OFF_P2Q + (size_t)256 * 502;
static constexpr size_t OFF_CA   = OFF_P2K + (size_t)256 * 502;    // [512]
static constexpr size_t OFF_CB   = OFF_CA + 512;
static constexpr size_t OFF_LP   = OFF_CB + 512;                   // [240][6]
static constexpr size_t OFF_LAB  = OFF_LP + (size_t)240 * 6;       // [24][2]

static __device__ __forceinline__ unsigned packh2(float a, float b) {
  half2_t t;
  t[0] = (_Float16)a;
  t[1] = (_Float16)b;
  return __builtin_bit_cast(unsigned, t);
}
static __device__ __forceinline__ half2_t ash2(unsigned u) {
  return __builtin_bit_cast(half2_t, u);
}

// ---------------- K1: kqv GEMM: Z[bb][o][l] (raw, pre-BN) ----------------
__global__ __launch_bounds__(256) void k_gemm(
    const float* __restrict__ x, const float* __restrict__ y,
    const float* __restrict__ wk, const float* __restrict__ wq,
    const float* __restrict__ wv, float* __restrict__ z) {
  int l0 = blockIdx.x * 64;
  int o0 = blockIdx.y * 64;
  int bb = blockIdx.z;
  int b = bb / 15, hi = bb % 15;
  const float* src;
  const float* wmat;
  int orow0;
  if (o0 < 128)      { wmat = wk; orow0 = o0;       src = x; }
  else if (o0 < 256) { wmat = wq; orow0 = o0 - 128; src = y; }
  else               { wmat = wv; orow0 = o0 - 256; src = x; }

  __shared__ float Ws[32][65];
  __shared__ float Xs[32][65];
  int tid = threadIdx.x;
  int tx = tid & 15, ty = tid >> 4;
  float acc[4][4] = {};

  for (int c0 = 0; c0 < 256; c0 += 32) {
#pragma unroll
    for (int r = 0; r < 8; ++r) {
      int idx = tid + r * 256;
      int oo = idx >> 5, cc = idx & 31;
      Ws[cc][oo] = wmat[(size_t)(orow0 + oo) * 256 + c0 + cc];
    }
#pragma unroll
    for (int r = 0; r < 8; ++r) {
      int idx = tid + r * 256;
      int cc = idx >> 6, ll = idx & 63;
      int l = l0 + ll;
      float v = 0.f;
      if (l < WPOS)
        v = src[(((size_t)b * 256 + c0 + cc) * 15 + hi) * WPOS + l];
      Xs[cc][ll] = v;
    }
    __syncthreads();
#pragma unroll
    for (int cc = 0; cc < 32; ++cc) {
      float rw[4], rx[4];
#pragma unroll
      for (int i = 0; i < 4; ++i) rw[i] = Ws[cc][ty * 4 + i];
#pragma unroll
      for (int j = 0; j < 4; ++j) rx[j] = Xs[cc][tx * 4 + j];
#pragma unroll
      for (int i = 0; i < 4; ++i)
#pragma unroll
        for (int j = 0; j < 4; ++j) acc[i][j] += rw[i] * rx[j];
    }
    __syncthreads();
  }
#pragma unroll
  for (int i = 0; i < 4; ++i) {
    int o = o0 + ty * 4 + i;
#pragma unroll
    for (int j = 0; j < 4; ++j) {
      int l = l0 + tx * 4 + j;
      if (l < WPOS) z[((size_t)bb * NCH + o) * WPOS + l] = acc[i][j];
    }
  }
}

// ---------------- K2: per-channel BN stats -> affine a,b ----------------
__global__ __launch_bounds__(256) void k_chan_stats(
    const float* __restrict__ z,
    const float* __restrict__ gk, const float* __restrict__ bk,
    const float* __restrict__ gq, const float* __restrict__ bq,
    const float* __restrict__ gkq, const float* __restrict__ bkq,
    float* __restrict__ ca, float* __restrict__ cb) {
  int o = blockIdx.x;
  int tid = threadIdx.x;
  float s = 0.f, s2 = 0.f;
  for (int idx = tid; idx < NBB * WPOS; idx += 256) {
    int bb = idx / WPOS, l = idx - bb * WPOS;
    float v = z[((size_t)bb * NCH + o) * WPOS + l];
    s += v; s2 += v * v;
  }
  __shared__ float r1[256], r2[256];
  r1[tid] = s; r2[tid] = s2; __syncthreads();
  for (int st = 128; st > 0; st >>= 1) {
    if (tid < st) { r1[tid] += r1[tid + st]; r2[tid] += r2[tid + st]; }
    __syncthreads();
  }
  if (tid == 0) {
    float n = (float)(NBB * WPOS);
    float mean = r1[0] / n;
    float var = r2[0] / n - mean * mean;
    float g, bi;
    if (o < 128)      { g = gk[o];        bi = bk[o]; }
    else if (o < 256) { g = gq[o - 128];  bi = bq[o - 128]; }
    else              { g = gkq[o - 256]; bi = bkq[o - 256]; }
    float a = g / sqrtf(var + NEPS);
    ca[o] = a;
    cb[o] = bi - mean * a;
  }
}

// ---------------- K3: normalized v -> vt[bbh][y][32] (tiled transpose) ----------------
__global__ __launch_bounds__(256) void k_norm_v(
    const float* __restrict__ z, const float* __restrict__ ca, const float* __restrict__ cb,
    float* __restrict__ vt) {
  int blk = blockIdx.x;            // 960 = 4 ltile * 240 bbh, bbh fastest (XCD locality)
  int bbh = blk % 240, lt = blk / 240;
  int bb = bbh >> 3, h = bbh & 7;
  int l0 = lt * 64;
  int nl = min(64, WPOS - l0);
  __shared__ float T[32][65];
  int tid = threadIdx.x;
  const float* zv = z + ((size_t)bb * NCH + h * 64 + 32) * WPOS;
  for (int i = tid; i < 32 * 64; i += 256) {
    int ch = i >> 6, l = i & 63;
    int ll = min(l0 + l, WPOS - 1);
    int cch = h * 64 + 32 + ch;
    T[ch][l] = ca[cch] * zv[(size_t)ch * WPOS + ll] + cb[cch];
  }
  __syncthreads();
  for (int i = tid; i < 64 * 32; i += 256) {
    int l = i >> 5, ch = i & 31;
    if (l < nl) vt[((size_t)bbh * WPOS + l0 + l) * 32 + ch] = T[ch][l];
  }
}

// ---------------- K4: rel prep: combined fp16 qe|keR table + vet ----------------
__global__ void k_rel_prep(const float* __restrict__ rel, unsigned* __restrict__ retc,
                           float* __restrict__ vet) {
  int idx = blockIdx.x * 256 + threadIdx.x;
  if (idx >= RELP * 48) return;
  int p = idx / 48, j = idx - p * 48;
  if (j < 16) {
    float lo, hi;
    if (j < 8) {                       // qe pairs: d = 2j, 2j+1 at position p
      lo = rel[(size_t)(2 * j) * RELP + p];
      hi = rel[(size_t)(2 * j + 1) * RELP + p];
    } else {                           // keR pairs: d = 2(j-8), at position 500-p
      int jj = j - 8;
      lo = rel[(size_t)(16 + 2 * jj) * RELP + (500 - p)];
      hi = rel[(size_t)(17 + 2 * jj) * RELP + (500 - p)];
    }
    retc[(size_t)p * 16 + j] = packh2(lo, hi);
  } else {
    int dd = j - 16;
    vet[(size_t)p * 32 + dd] = rel[(size_t)(32 + dd) * RELP + p];
  }
}

// ---------------- K5: prefix sums (parallel pair + Hillis-Steele scan) ----------------
__global__ __launch_bounds__(256) void k_prefix(const float* __restrict__ rel,
                                                float* __restrict__ p1q, float* __restrict__ p1k,
                                                float* __restrict__ p2q, float* __restrict__ p2k) {
  int task = blockIdx.x;   // 0..543
  const float* ra;
  const float* rb = nullptr;
  float* outp;
  if (task < 16)        { ra = rel + (size_t)task * RELP; outp = p1q + (size_t)task * 502; }
  else if (task < 32)   { ra = rel + (size_t)task * RELP; outp = p1k + (size_t)(task - 16) * 502; }
  else if (task < 288)  { int pr = task - 32;
                          ra = rel + (size_t)(pr >> 4) * RELP;
                          rb = rel + (size_t)(pr & 15) * RELP;
                          outp = p2q + (size_t)pr * 502; }
  else                  { int pr = task - 288;
                          ra = rel + (size_t)(16 + (pr >> 4)) * RELP;
                          rb = rel + (size_t)(16 + (pr & 15)) * RELP;
                          outp = p2k + (size_t)pr * 502; }
  __shared__ float buf[256];
  int t = threadIdx.x;
  int i0 = 2 * t, i1 = 2 * t + 1;
  float a0 = (i0 < RELP) ? (rb ? ra[i0] * rb[i0] : ra[i0]) : 0.f;
  float a1 = (i1 < RELP) ? (rb ? ra[i1] * rb[i1] : ra[i1]) : 0.f;
  buf[t] = a0 + a1;
  __syncthreads();
#pragma unroll
  for (int off = 1; off < 256; off <<= 1) {
    float v = buf[t];
    float add = (t >= off) ? buf[t - off] : 0.f;
    __syncthreads();
    buf[t] = v + add;
    __syncthreads();
  }
  float ex = buf[t] - (a0 + a1);          // exclusive scan over pairs
  if (i0 <= RELP) outp[i0] = ex;
  if (i1 <= RELP) outp[i1] = ex + a0;
}

// ---------------- block reduce helper ----------------
__device__ __forceinline__ float block_reduce(float v, float* red, int tid) {
  red[tid] = v; __syncthreads();
  for (int s = 128; s > 0; s >>= 1) {
    if (tid < s) red[tid] += red[tid + s];
    __syncthreads();
  }
  float r = red[0]; __syncthreads();
  return r;
}

// ---------------- K6: logit BN stats per (bb,h) (affine at staging) ----------------
__global__ __launch_bounds__(256) void k_logit_stats(
    const float* __restrict__ z, const float* __restrict__ ca, const float* __restrict__ cb,
    const float* __restrict__ p1q, const float* __restrict__ p1k,
    const float* __restrict__ p2q, const float* __restrict__ p2k,
    float* __restrict__ lp) {
  int bbh = blockIdx.x;
  int bb = bbh >> 3, h = bbh & 7;
  int tid = threadIdx.x;
  __shared__ float qs[16][257], ks[16][257];
  __shared__ float Qg[256], Kg[256];
  __shared__ float red[256];
  __shared__ float qsum[16], ksum[16];

  const float* zb = z + ((size_t)bb * NCH + h * 64) * WPOS;
  for (int idx = tid; idx < 16 * WPOS; idx += 256) {
    int d = idx / WPOS, xx = idx - d * WPOS;
    int chk = h * 64 + d, chq = h * 64 + 16 + d;
    ks[d][xx] = ca[chk] * zb[(size_t)d * WPOS + xx] + cb[chk];
    qs[d][xx] = ca[chq] * zb[(size_t)(16 + d) * WPOS + xx] + cb[chq];
  }
  __syncthreads();
  if (tid < 16) {
    float s = 0.f;
    for (int xx = 0; xx < WPOS; ++xx) s += qs[tid][xx];
    qsum[tid] = s;
  } else if (tid < 32) {
    float s = 0.f;
    for (int xx = 0; xx < WPOS; ++xx) s += ks[tid - 16][xx];
    ksum[tid - 16] = s;
  }
  {
    int d = tid >> 4, d2 = tid & 15;
    float g1 = 0.f, g2 = 0.f;
    for (int xx = 0; xx < WPOS; ++xx) {
      g1 += qs[d][xx] * qs[d2][xx];
      g2 += ks[d][xx] * ks[d2][xx];
    }
    Qg[tid] = g1; Kg[tid] = g2;
  }
  __syncthreads();

  float v_sqqk = Qg[tid] * Kg[tid];
  float v_sumqr = 0.f, v_sqqr = 0.f, v_sumkr = 0.f, v_sqkr = 0.f;
  for (int idx = tid; idx < 16 * WPOS; idx += 256) {
    int d = idx / WPOS, xx = idx - d * WPOS;
    int ihi = 501 - xx, ilo = 250 - xx;
    float qv = qs[d][xx];
    v_sumqr += qv * (p1q[d * 502 + ihi] - p1q[d * 502 + ilo]);
    float t = 0.f;
    for (int d2 = 0; d2 < 16; ++d2) {
      const float* pp = p2q + (size_t)(d * 16 + d2) * 502;
      t += qs[d2][xx] * (pp[ihi] - pp[ilo]);
    }
    v_sqqr += qv * t;
    float kv = ks[d][xx];
    v_sumkr += kv * (p1k[d * 502 + ihi] - p1k[d * 502 + ilo]);
    float t2 = 0.f;
    for (int d2 = 0; d2 < 16; ++d2) {
      const float* pp = p2k + (size_t)(d * 16 + d2) * 502;
      t2 += ks[d2][xx] * (pp[ihi] - pp[ilo]);
    }
    v_sqkr += kv * t2;
  }
  float r_sqqk  = block_reduce(v_sqqk, red, tid);
  float r_sumqr = block_reduce(v_sumqr, red, tid);
  float r_sqqr  = block_reduce(v_sqqr, red, tid);
  float r_sumkr = block_reduce(v_sumkr, red, tid);
  float r_sqkr  = block_reduce(v_sqkr, red, tid);
  if (tid == 0) {
    float sum_qk = 0.f;
    for (int d = 0; d < 16; ++d) sum_qk += qsum[d] * ksum[d];
    float* o = lp + (size_t)bbh * 6;
    o[0] = sum_qk; o[1] = r_sqqk;
    o[2] = r_sumqr; o[3] = r_sqqr;
    o[4] = r_sumkr; o[5] = r_sqkr;
  }
}

// ---------------- K7: finalize logit BN affine ----------------
__global__ void k_logit_final(const float* __restrict__ lp,
                              const float* __restrict__ glog, const float* __restrict__ blog,
                              float* __restrict__ lab) {
  int c = threadIdx.x;
  if (c >= 24) return;
  int grp = c >> 3, h = c & 7;
  float s = 0.f, s2 = 0.f;
  for (int bb = 0; bb < NBB; ++bb) {
    const float* o = lp + (size_t)(bb * 8 + h) * 6 + grp * 2;
    s += o[0]; s2 += o[1];
  }
  float n = (float)NBB * (float)WPOS * (float)WPOS;
  float mean = s / n;
  float var = s2 / n - mean * mean;
  float la = glog[c] / sqrtf(var + NEPS);
  lab[c * 2] = la;
  lab[c * 2 + 1] = blog[c] - mean * la;
}

// ---------------- K8: fused logits + softmax + attention ----------------
// 1920 blocks = 8 tiles x 240 bbh, bbh fastest -> blk%8 == bbh%8 (XCD locality).
__global__ __launch_bounds__(256) void k_attn(
    const float* __restrict__ z, const float* __restrict__ ca, const float* __restrict__ cb,
    const float* __restrict__ vt,
    const unsigned* __restrict__ retc, const float* __restrict__ vet,
    const float* __restrict__ lab, float* __restrict__ out) {
  int blk = blockIdx.x;
  int bbh = blk % 240, tile = blk / 240;
  int bb = bbh >> 3, h = bbh & 7;
  int b = bb / 15, hi = bb % 15;
  int x0 = tile * 32;
  int nr = min(32, WPOS - x0);
  int tid = threadIdx.x;
  int lane = tid & 63, wvid = tid >> 6;

  float la_qk = lab[h * 2],        lb0 = lab[h * 2 + 1];
  float la_qr = lab[(8 + h) * 2],  lb1 = lab[(8 + h) * 2 + 1];
  float la_kr = lab[(16 + h) * 2], lb2 = lab[(16 + h) * 2 + 1];
  float lbsum = lb0 + lb1 + lb2;

  __shared__ float S[32][253];                 // 32,384 B; diag stride 254 (2-way, free)
  __shared__ __align__(16) unsigned winU[282 * 18];  // 20,304 B; fp16-pair rows, 8B-aligned
  __shared__ __align__(16) unsigned uSh[256];  // 1,024 B; qsP early, smax/ssum later

  unsigned* qsP = uSh;                         // [32][8] fp16-pair q rows
  float* sred = (float*)uSh;                   // [8][32] softmax reduce

  int pwin0 = 251 - x0 - nr;
  int nwin = 250 + nr;

  const float* zb = z + ((size_t)bb * NCH + h * 64) * WPOS;

  // ---- stage rel window into LDS (coalesced, L2-resident) ----
  for (int i = tid; i < nwin * 16; i += 256) {
    int r = i >> 4, j = i & 15;
    winU[r * 18 + j] = retc[(size_t)(pwin0 + r) * 16 + j];
  }

  // ---- stage q tile (affine from raw z, fp16-packed) ----
  {
    int xx = tid & 31, j = tid >> 5;          // j 0..7
    int xcl = min(x0 + xx, WPOS - 1);
    int ch0 = h * 64 + 16 + 2 * j;
    float q0 = ca[ch0]     * zb[(size_t)(16 + 2 * j) * WPOS + xcl] + cb[ch0];
    float q1 = ca[ch0 + 1] * zb[(size_t)(17 + 2 * j) * WPOS + xcl] + cb[ch0 + 1];
    qsP[xx * 8 + j] = packh2(q0, q1);
  }

  // ---- k row per lane (affine from raw z), fp16-packed ----
  int yy = wvid * 64 + lane;
  int yc = min(yy, WPOS - 1);
  bool yok = (yy < WPOS);
  half2_t kh[8];
#pragma unroll
  for (int d = 0; d < 8; ++d) {
    int ch = h * 64 + 2 * d;
    float k0 = ca[ch]     * zb[(size_t)(2 * d) * WPOS + yc] + cb[ch];
    float k1 = ca[ch + 1] * zb[(size_t)(2 * d + 1) * WPOS + yc] + cb[ch + 1];
    kh[d] = __builtin_bit_cast(half2_t, packh2(k0, k1));
  }
  __syncthreads();

  // ---- fused S: qk + qr + kr via v_dot2_f32_f16; lanes on y, loop over x ----
  {
    int rowbase = yc + nr - 1;                // yc - x + 250 - pwin0 at xx=0
    for (int xx = 0; xx < nr; ++xx) {
      const unsigned* wr = &winU[(size_t)(rowbase - xx) * 18];
      const unsigned* qp = &qsP[xx * 8];
      float dqk = 0.f, dqr = 0.f, dkr = 0.f;
#pragma unroll
      for (int j2 = 0; j2 < 4; ++j2) {
        uint2 ue = *(const uint2*)(wr + 2 * j2);
        uint2 uk = *(const uint2*)(wr + 8 + 2 * j2);
        uint2 uq = *(const uint2*)(qp + 2 * j2);
        half2_t qe0 = ash2(ue.x), qe1 = ash2(ue.y);
        half2_t ke0 = ash2(uk.x), ke1 = ash2(uk.y);
        half2_t q0  = ash2(uq.x), q1  = ash2(uq.y);
        half2_t k0 = kh[2 * j2], k1 = kh[2 * j2 + 1];
        dqk = FDOT2(q0, k0, dqk);  dqk = FDOT2(q1, k1, dqk);
        dqr = FDOT2(q0, qe0, dqr); dqr = FDOT2(q1, qe1, dqr);
        dkr = FDOT2(k0, ke0, dkr); dkr = FDOT2(k1, ke1, dkr);
      }
      if (yok)
        S[xx][yy] = la_qk * dqk + la_qr * dqr + la_kr * dkr + lbsum;
    }
  }
  __syncthreads();

  // ---- softmax over y; lanes on x, 8 slices of ~32 y ----
  int xx = lane & 31;
  int sl = wvid * 2 + (lane >> 5);
  int ylo = sl * 32;
  int yhi = min(ylo + 32, WPOS);
  {
    float m = -1e30f;
    for (int y2 = ylo; y2 < yhi; ++y2) m = fmaxf(m, S[xx][y2]);
    sred[sl * 32 + xx] = m;
  }
  __syncthreads();
  float rowm = sred[0 * 32 + xx];
#pragma unroll
  for (int s = 1; s < 8; ++s) rowm = fmaxf(rowm, sred[s * 32 + xx]);
  __syncthreads();
  {
    float sacc = 0.f;
    for (int y2 = ylo; y2 < yhi; ++y2) {
      float e = __expf(S[xx][y2] - rowm);
      S[xx][y2] = e;
      sacc += e;
    }
    sred[sl * 32 + xx] = sacc;
  }
  __syncthreads();
  float denom = 0.f;
#pragma unroll
  for (int s = 0; s < 8; ++s) denom += sred[s * 32 + xx];

  // ---- attention: group sl = 4 d-channels, lanes on x ----
  int d0 = sl * 4;
  const float* Srow = &S[xx][0];
  float4 acc = {0.f, 0.f, 0.f, 0.f};
  {
    const float* vb = vt + (size_t)bbh * WPOS * 32 + d0;
    int y2 = 0;
    for (; y2 + 7 < WPOS; y2 += 8) {
      float w[8];
      float4 v[8];
#pragma unroll
      for (int u = 0; u < 8; ++u) v[u] = *(const float4*)(vb + (size_t)(y2 + u) * 32);
#pragma unroll
      for (int u = 0; u < 8; ++u) w[u] = Srow[y2 + u];
#pragma unroll
      for (int u = 0; u < 8; ++u) {
        acc.x += w[u] * v[u].x; acc.y += w[u] * v[u].y;
        acc.z += w[u] * v[u].z; acc.w += w[u] * v[u].w;
      }
    }
    for (; y2 < WPOS; ++y2) {
      float w0 = Srow[y2];
      float4 v0 = *(const float4*)(vb + (size_t)y2 * 32);
      acc.x += w0 * v0.x; acc.y += w0 * v0.y;
      acc.z += w0 * v0.z; acc.w += w0 * v0.w;
    }
  }
  {
    int xg = x0 + xx;
    int pmin = max(0, 250 - (x0 + nr - 1));
    int pmax = 500 - x0;
    int pi0 = max(pmin, 250 - x0);       // all-lane y2 >= 0
    int pi1 = min(pmax, 466 - x0);       // all-lane y2+3 <= 250
    const float* veb = vet + d0;
    int p = pmin;
    for (; p < pi0; ++p) {
      int y2 = xg + p - 250;
      float w0 = ((unsigned)y2 < (unsigned)WPOS) ? Srow[y2] : 0.f;
      float4 v0 = *(const float4*)(veb + (size_t)p * 32);
      acc.x += w0 * v0.x; acc.y += w0 * v0.y;
      acc.z += w0 * v0.z; acc.w += w0 * v0.w;
    }
    for (; p + 3 <= pi1; p += 4) {
      int y2 = xg + p - 250;
      float w0 = Srow[y2], w1 = Srow[y2 + 1], w2 = Srow[y2 + 2], w3 = Srow[y2 + 3];
      float4 v0 = *(const float4*)(veb + (size_t)(p + 0) * 32);
      float4 v1 = *(const float4*)(veb + (size_t)(p + 1) * 32);
      float4 v2 = *(const float4*)(veb + (size_t)(p + 2) * 32);
      float4 v3 = *(const float4*)(veb + (size_t)(p + 3) * 32);
      acc.x += w0 * v0.x + w1 * v1.x + w2 * v2.x + w3 * v3.x;
      acc.y += w0 * v0.y + w1 * v1.y + w2 * v2.y + w3 * v3.y;
      acc.z += w0 * v0.z + w1 * v1.z + w2 * v2.z + w3 * v3.z;
      acc.w += w0 * v0.w + w1 * v1.w + w2 * v2.w + w3 * v3.w;
    }
    for (; p <= pmax; ++p) {
      int y2 = xg + p - 250;
      float w0 = ((unsigned)y2 < (unsigned)WPOS) ? Srow[y2] : 0.f;
      float4 v0 = *(const float4*)(veb + (size_t)p * 32);
      acc.x += w0 * v0.x; acc.y += w0 * v0.y;
      acc.z += w0 * v0.z; acc.w += w0 * v0.w;
    }
  }
  if (xx < nr) {
    float rinv = 1.0f / denom;
    int xg = x0 + xx;
    float av[4] = {acc.x, acc.y, acc.z, acc.w};
#pragma unroll
    for (int dd = 0; dd < 4; ++dd) {
      int d = d0 + dd;
      out[(((size_t)b * 256 + h * 32 + d) * 15 + hi) * WPOS + xg] = av[dd] * rinv;
    }
  }
}

// ---------------- launch ----------------
extern "C" void kernel_launch(void* const* d_in, const int* in_sizes, int n_in,
                              void* d_out, int out_size, void* d_ws, size_t ws_size,
                              hipStream_t stream) {
  const float* x    = (const float*)d_in[0];
  const float* y    = (const float*)d_in[1];
  const float* wk   = (const float*)d_in[2];
  const float* wq   = (const float*)d_in[3];
  const float* wv   = (const float*)d_in[4];
  const float* gk   = (const float*)d_in[5];
  const float* bk   = (const float*)d_in[6];
  const float* gq   = (const float*)d_in[7];
  const float* bq   = (const float*)d_in[8];
  const float* gkq  = (const float*)d_in[9];
  const float* bkq  = (const float*)d_in[10];
  const float* glog = (const float*)d_in[11];
  const float* blog = (const float*)d_in[12];
  const float* rel  = (const float*)d_in[13];
  float* out = (float*)d_out;
  float* ws  = (float*)d_ws;

  float* z      = ws + OFF_Z;
  float* vt     = ws + OFF_VT;
  unsigned* retc= (unsigned*)(ws + OFF_RETC);
  float* vet    = ws + OFF_VET;
  float* p1q    = ws + OFF_P1Q;
  float* p1k    = ws + OFF_P1K;
  float* p2q    = ws + OFF_P2Q;
  float* p2k    = ws + OFF_P2K;
  float* ca     = ws + OFF_CA;
  float* cb     = ws + OFF_CB;
  float* lp     = ws + OFF_LP;
  float* lab    = ws + OFF_LAB;

  dim3 g1(4, 8, NBB);
  k_gemm<<<g1, 256, 0, stream>>>(x, y, wk, wq, wv, z);
  k_chan_stats<<<512, 256, 0, stream>>>(z, gk, bk, gq, bq, gkq, bkq, ca, cb);
  k_norm_v<<<960, 256, 0, stream>>>(z, ca, cb, vt);
  k_rel_prep<<<(RELP * 48 + 255) / 256, 256, 0, stream>>>(rel, retc, vet);
  k_prefix<<<544, 256, 0, stream>>>(rel, p1q, p1k, p2q, p2k);
  k_logit_stats<<<240, 256, 0, stream>>>(z, ca, cb, p1q, p1k, p2q, p2k, lp);
  k_logit_final<<<1, 32, 0, stream>>>(lp, glog, blog, lab);
  k_attn<<<240 * 8, 256, 0, stream>>>(z, ca, cb, vt, retc, vet, lab, out);
}

// Round 6
// 247.608 us; speedup vs baseline: 2.8603x; 1.1493x over previous
//
#include <hip/hip_runtime.h>
#include <hip/hip_bf16.h>
#include <cstdint>

#define WPOS 251
#define NBB  30
#define NCH  512
#define RELP 501
#define NEPS 1e-5f

typedef _Float16 half2_t __attribute__((ext_vector_type(2)));

#if defined(__has_builtin)
#if __has_builtin(__builtin_amdgcn_fdot2)
#define FDOT2(a, b, c) __builtin_amdgcn_fdot2((a), (b), (c), false)
#endif
#endif
#ifndef FDOT2
#define FDOT2(a, b, c) ((float)(a)[0] * (float)(b)[0] + (float)(a)[1] * (float)(b)[1] + (c))
#endif

// ---------------- workspace layout (in float slots) ----------------
static constexpr size_t SZ_Z     = (size_t)NBB * NCH * WPOS;
static constexpr size_t OFF_Z    = 0;
static constexpr size_t OFF_VH   = OFF_Z + SZ_Z;                   // uint[bbh][126][32] half2 v pairs
static constexpr size_t SZ_VH    = (size_t)NBB * 8 * 126 * 32;
static constexpr size_t OFF_RETC = OFF_VH + SZ_VH;                 // uint[501][16]: qe|keR fp16 pairs
static constexpr size_t OFF_VET  = OFF_RETC + (size_t)RELP * 16;   // f32 [501][32]
static constexpr size_t OFF_P1Q  = OFF_VET + (size_t)RELP * 32;    // [16][502]
static constexpr size_t OFF_P1K  = OFF_P1Q + (size_t)16 * 502;
static constexpr size_t OFF_P2Q  = OFF_P1K + (size_t)16 * 502;     // [256][502]
static constexpr size_t OFF_P2K  = OFF_P2Q + (size_t)256 * 502;
static constexpr size_t OFF_CA   = OFF_P2K + (size_t)256 * 502;    // [512]
static constexpr size_t OFF_CB   = OFF_CA + 512;
static constexpr size_t OFF_LP   = OFF_CB + 512;                   // [240][6]
static constexpr size_t OFF_LAB  = OFF_LP + (size_t)240 * 6;       // [24][2]

static __device__ __forceinline__ unsigned packh2(float a, float b) {
  half2_t t;
  t[0] = (_Float16)a;
  t[1] = (_Float16)b;
  return __builtin_bit_cast(unsigned, t);
}
static __device__ __forceinline__ half2_t ash2(unsigned u) {
  return __builtin_bit_cast(half2_t, u);
}

// ---------------- K1: kqv GEMM: Z[bb][o][l] (raw, pre-BN) ----------------
__global__ __launch_bounds__(256) void k_gemm(
    const float* __restrict__ x, const float* __restrict__ y,
    const float* __restrict__ wk, const float* __restrict__ wq,
    const float* __restrict__ wv, float* __restrict__ z) {
  int l0 = blockIdx.x * 64;
  int o0 = blockIdx.y * 64;
  int bb = blockIdx.z;
  int b = bb / 15, hi = bb % 15;
  const float* src;
  const float* wmat;
  int orow0;
  if (o0 < 128)      { wmat = wk; orow0 = o0;       src = x; }
  else if (o0 < 256) { wmat = wq; orow0 = o0 - 128; src = y; }
  else               { wmat = wv; orow0 = o0 - 256; src = x; }

  __shared__ float Ws[32][65];
  __shared__ float Xs[32][65];
  int tid = threadIdx.x;
  int tx = tid & 15, ty = tid >> 4;
  float acc[4][4] = {};

  for (int c0 = 0; c0 < 256; c0 += 32) {
#pragma unroll
    for (int r = 0; r < 8; ++r) {
      int idx = tid + r * 256;
      int oo = idx >> 5, cc = idx & 31;
      Ws[cc][oo] = wmat[(size_t)(orow0 + oo) * 256 + c0 + cc];
    }
#pragma unroll
    for (int r = 0; r < 8; ++r) {
      int idx = tid + r * 256;
      int cc = idx >> 6, ll = idx & 63;
      int l = l0 + ll;
      float v = 0.f;
      if (l < WPOS)
        v = src[(((size_t)b * 256 + c0 + cc) * 15 + hi) * WPOS + l];
      Xs[cc][ll] = v;
    }
    __syncthreads();
#pragma unroll
    for (int cc = 0; cc < 32; ++cc) {
      float rw[4], rx[4];
#pragma unroll
      for (int i = 0; i < 4; ++i) rw[i] = Ws[cc][ty * 4 + i];
#pragma unroll
      for (int j = 0; j < 4; ++j) rx[j] = Xs[cc][tx * 4 + j];
#pragma unroll
      for (int i = 0; i < 4; ++i)
#pragma unroll
        for (int j = 0; j < 4; ++j) acc[i][j] += rw[i] * rx[j];
    }
    __syncthreads();
  }
#pragma unroll
  for (int i = 0; i < 4; ++i) {
    int o = o0 + ty * 4 + i;
#pragma unroll
    for (int j = 0; j < 4; ++j) {
      int l = l0 + tx * 4 + j;
      if (l < WPOS) z[((size_t)bb * NCH + o) * WPOS + l] = acc[i][j];
    }
  }
}

// ---------------- K2: per-channel BN stats -> affine a,b ----------------
__global__ __launch_bounds__(256) void k_chan_stats(
    const float* __restrict__ z,
    const float* __restrict__ gk, const float* __restrict__ bk,
    const float* __restrict__ gq, const float* __restrict__ bq,
    const float* __restrict__ gkq, const float* __restrict__ bkq,
    float* __restrict__ ca, float* __restrict__ cb) {
  int o = blockIdx.x;
  int tid = threadIdx.x;
  float s = 0.f, s2 = 0.f;
  for (int idx = tid; idx < NBB * WPOS; idx += 256) {
    int bb = idx / WPOS, l = idx - bb * WPOS;
    float v = z[((size_t)bb * NCH + o) * WPOS + l];
    s += v; s2 += v * v;
  }
  __shared__ float r1[256], r2[256];
  r1[tid] = s; r2[tid] = s2; __syncthreads();
  for (int st = 128; st > 0; st >>= 1) {
    if (tid < st) { r1[tid] += r1[tid + st]; r2[tid] += r2[tid + st]; }
    __syncthreads();
  }
  if (tid == 0) {
    float n = (float)(NBB * WPOS);
    float mean = r1[0] / n;
    float var = r2[0] / n - mean * mean;
    float g, bi;
    if (o < 128)      { g = gk[o];        bi = bk[o]; }
    else if (o < 256) { g = gq[o - 128];  bi = bq[o - 128]; }
    else              { g = gkq[o - 256]; bi = bkq[o - 256]; }
    float a = g / sqrtf(var + NEPS);
    ca[o] = a;
    cb[o] = bi - mean * a;
  }
}

// ---------------- K3: normalized v -> VH[bbh][pair][32] half2 pairs ----------------
__global__ __launch_bounds__(256) void k_norm_vh(
    const float* __restrict__ z, const float* __restrict__ ca, const float* __restrict__ cb,
    unsigned* __restrict__ vh) {
  int blk = blockIdx.x;            // 960 = 4 ltile * 240 bbh, bbh fastest (XCD locality)
  int bbh = blk % 240, lt = blk / 240;
  int bb = bbh >> 3, h = bbh & 7;
  int l0 = lt * 64;
  __shared__ float T[32][65];
  int tid = threadIdx.x;
  const float* zv = z + ((size_t)bb * NCH + h * 64 + 32) * WPOS;
  for (int i = tid; i < 32 * 64; i += 256) {
    int ch = i >> 6, l = i & 63;
    int gl = l0 + l;
    int cch = h * 64 + 32 + ch;
    T[ch][l] = (gl < WPOS) ? (ca[cch] * zv[(size_t)ch * WPOS + gl] + cb[cch]) : 0.f;
  }
  __syncthreads();
  int p0 = l0 >> 1;
  for (int i = tid; i < 32 * 32; i += 256) {
    int pl = i >> 5, ch = i & 31;
    int gp = p0 + pl;
    if (gp < 126)
      vh[((size_t)bbh * 126 + gp) * 32 + ch] = packh2(T[ch][2 * pl], T[ch][2 * pl + 1]);
  }
}

// ---------------- K4: rel prep: combined fp16 qe|keR table + vet ----------------
__global__ void k_rel_prep(const float* __restrict__ rel, unsigned* __restrict__ retc,
                           float* __restrict__ vet) {
  int idx = blockIdx.x * 256 + threadIdx.x;
  if (idx >= RELP * 48) return;
  int p = idx / 48, j = idx - p * 48;
  if (j < 16) {
    float lo, hi;
    if (j < 8) {                       // qe pairs: d = 2j, 2j+1 at position p
      lo = rel[(size_t)(2 * j) * RELP + p];
      hi = rel[(size_t)(2 * j + 1) * RELP + p];
    } else {                           // keR pairs: d = 2(j-8), at position 500-p
      int jj = j - 8;
      lo = rel[(size_t)(16 + 2 * jj) * RELP + (500 - p)];
      hi = rel[(size_t)(17 + 2 * jj) * RELP + (500 - p)];
    }
    retc[(size_t)p * 16 + j] = packh2(lo, hi);
  } else {
    int dd = j - 16;
    vet[(size_t)p * 32 + dd] = rel[(size_t)(32 + dd) * RELP + p];
  }
}

// ---------------- K5: prefix sums (parallel pair + Hillis-Steele scan) ----------------
__global__ __launch_bounds__(256) void k_prefix(const float* __restrict__ rel,
                                                float* __restrict__ p1q, float* __restrict__ p1k,
                                                float* __restrict__ p2q, float* __restrict__ p2k) {
  int task = blockIdx.x;   // 0..543
  const float* ra;
  const float* rb = nullptr;
  float* outp;
  if (task < 16)        { ra = rel + (size_t)task * RELP; outp = p1q + (size_t)task * 502; }
  else if (task < 32)   { ra = rel + (size_t)task * RELP; outp = p1k + (size_t)(task - 16) * 502; }
  else if (task < 288)  { int pr = task - 32;
                          ra = rel + (size_t)(pr >> 4) * RELP;
                          rb = rel + (size_t)(pr & 15) * RELP;
                          outp = p2q + (size_t)pr * 502; }
  else                  { int pr = task - 288;
                          ra = rel + (size_t)(16 + (pr >> 4)) * RELP;
                          rb = rel + (size_t)(16 + (pr & 15)) * RELP;
                          outp = p2k + (size_t)pr * 502; }
  __shared__ float buf[256];
  int t = threadIdx.x;
  int i0 = 2 * t, i1 = 2 * t + 1;
  float a0 = (i0 < RELP) ? (rb ? ra[i0] * rb[i0] : ra[i0]) : 0.f;
  float a1 = (i1 < RELP) ? (rb ? ra[i1] * rb[i1] : ra[i1]) : 0.f;
  buf[t] = a0 + a1;
  __syncthreads();
#pragma unroll
  for (int off = 1; off < 256; off <<= 1) {
    float v = buf[t];
    float add = (t >= off) ? buf[t - off] : 0.f;
    __syncthreads();
    buf[t] = v + add;
    __syncthreads();
  }
  float ex = buf[t] - (a0 + a1);          // exclusive scan over pairs
  if (i0 <= RELP) outp[i0] = ex;
  if (i1 <= RELP) outp[i1] = ex + a0;
}

// ---------------- block reduce helper ----------------
__device__ __forceinline__ float block_reduce(float v, float* red, int tid) {
  red[tid] = v; __syncthreads();
  for (int s = 128; s > 0; s >>= 1) {
    if (tid < s) red[tid] += red[tid + s];
    __syncthreads();
  }
  float r = red[0]; __syncthreads();
  return r;
}

// ---------------- K6: logit BN stats per (bb,h) (affine at staging) ----------------
__global__ __launch_bounds__(256) void k_logit_stats(
    const float* __restrict__ z, const float* __restrict__ ca, const float* __restrict__ cb,
    const float* __restrict__ p1q, const float* __restrict__ p1k,
    const float* __restrict__ p2q, const float* __restrict__ p2k,
    float* __restrict__ lp) {
  int bbh = blockIdx.x;
  int bb = bbh >> 3, h = bbh & 7;
  int tid = threadIdx.x;
  __shared__ float qs[16][257], ks[16][257];
  __shared__ float Qg[256], Kg[256];
  __shared__ float red[256];
  __shared__ float qsum[16], ksum[16];

  const float* zb = z + ((size_t)bb * NCH + h * 64) * WPOS;
  for (int idx = tid; idx < 16 * WPOS; idx += 256) {
    int d = idx / WPOS, xx = idx - d * WPOS;
    int chk = h * 64 + d, chq = h * 64 + 16 + d;
    ks[d][xx] = ca[chk] * zb[(size_t)d * WPOS + xx] + cb[chk];
    qs[d][xx] = ca[chq] * zb[(size_t)(16 + d) * WPOS + xx] + cb[chq];
  }
  __syncthreads();
  if (tid < 16) {
    float s = 0.f;
    for (int xx = 0; xx < WPOS; ++xx) s += qs[tid][xx];
    qsum[tid] = s;
  } else if (tid < 32) {
    float s = 0.f;
    for (int xx = 0; xx < WPOS; ++xx) s += ks[tid - 16][xx];
    ksum[tid - 16] = s;
  }
  {
    int d = tid >> 4, d2 = tid & 15;
    float g1 = 0.f, g2 = 0.f;
    for (int xx = 0; xx < WPOS; ++xx) {
      g1 += qs[d][xx] * qs[d2][xx];
      g2 += ks[d][xx] * ks[d2][xx];
    }
    Qg[tid] = g1; Kg[tid] = g2;
  }
  __syncthreads();

  float v_sqqk = Qg[tid] * Kg[tid];
  float v_sumqr = 0.f, v_sqqr = 0.f, v_sumkr = 0.f, v_sqkr = 0.f;
  for (int idx = tid; idx < 16 * WPOS; idx += 256) {
    int d = idx / WPOS, xx = idx - d * WPOS;
    int ihi = 501 - xx, ilo = 250 - xx;
    float qv = qs[d][xx];
    v_sumqr += qv * (p1q[d * 502 + ihi] - p1q[d * 502 + ilo]);
    float t = 0.f;
    for (int d2 = 0; d2 < 16; ++d2) {
      const float* pp = p2q + (size_t)(d * 16 + d2) * 502;
      t += qs[d2][xx] * (pp[ihi] - pp[ilo]);
    }
    v_sqqr += qv * t;
    float kv = ks[d][xx];
    v_sumkr += kv * (p1k[d * 502 + ihi] - p1k[d * 502 + ilo]);
    float t2 = 0.f;
    for (int d2 = 0; d2 < 16; ++d2) {
      const float* pp = p2k + (size_t)(d * 16 + d2) * 502;
      t2 += ks[d2][xx] * (pp[ihi] - pp[ilo]);
    }
    v_sqkr += kv * t2;
  }
  float r_sqqk  = block_reduce(v_sqqk, red, tid);
  float r_sumqr = block_reduce(v_sumqr, red, tid);
  float r_sqqr  = block_reduce(v_sqqr, red, tid);
  float r_sumkr = block_reduce(v_sumkr, red, tid);
  float r_sqkr  = block_reduce(v_sqkr, red, tid);
  if (tid == 0) {
    float sum_qk = 0.f;
    for (int d = 0; d < 16; ++d) sum_qk += qsum[d] * ksum[d];
    float* o = lp + (size_t)bbh * 6;
    o[0] = sum_qk; o[1] = r_sqqk;
    o[2] = r_sumqr; o[3] = r_sqqr;
    o[4] = r_sumkr; o[5] = r_sqkr;
  }
}

// ---------------- K7: finalize logit BN affine ----------------
__global__ void k_logit_final(const float* __restrict__ lp,
                              const float* __restrict__ glog, const float* __restrict__ blog,
                              float* __restrict__ lab) {
  int c = threadIdx.x;
  if (c >= 24) return;
  int grp = c >> 3, h = c & 7;
  float s = 0.f, s2 = 0.f;
  for (int bb = 0; bb < NBB; ++bb) {
    const float* o = lp + (size_t)(bb * 8 + h) * 6 + grp * 2;
    s += o[0]; s2 += o[1];
  }
  float n = (float)NBB * (float)WPOS * (float)WPOS;
  float mean = s / n;
  float var = s2 / n - mean * mean;
  float la = glog[c] / sqrtf(var + NEPS);
  lab[c * 2] = la;
  lab[c * 2 + 1] = blog[c] - mean * la;
}

// ---------------- K8: fused logits + softmax + attention ----------------
// 1920 blocks = 8 tiles x 240 bbh, bbh fastest -> blk%8 == bbh%8 (XCD locality).
// S stored fp16, stride 260 halfs (520B rows: 8B aligned, 2-way banks = free).
__global__ __launch_bounds__(256) void k_attn(
    const float* __restrict__ z, const float* __restrict__ ca, const float* __restrict__ cb,
    const unsigned* __restrict__ vh,
    const unsigned* __restrict__ retc, const float* __restrict__ vet,
    const float* __restrict__ lab, float* __restrict__ out) {
  int blk = blockIdx.x;
  int bbh = blk % 240, tile = blk / 240;
  int bb = bbh >> 3, h = bbh & 7;
  int b = bb / 15, hi = bb % 15;
  int x0 = tile * 32;
  int nr = min(32, WPOS - x0);
  int tid = threadIdx.x;
  int lane = tid & 63, wvid = tid >> 6;

  float la_qk = lab[h * 2],        lb0 = lab[h * 2 + 1];
  float la_qr = lab[(8 + h) * 2],  lb1 = lab[(8 + h) * 2 + 1];
  float la_kr = lab[(16 + h) * 2], lb2 = lab[(16 + h) * 2 + 1];
  float lbsum = lb0 + lb1 + lb2;

  __shared__ __align__(16) unsigned Su[32 * 130];     // 16,640 B  fp16 S, 260 halfs/row
  __shared__ __align__(16) unsigned winU[282 * 18];   // 20,304 B  fp16-pair rel rows
  __shared__ __align__(16) unsigned uSh[256];         // 1,024 B   qsP early, sred later
  _Float16* S = (_Float16*)Su;

  unsigned* qsP = uSh;
  float* sred = (float*)uSh;

  int pwin0 = 251 - x0 - nr;
  int nwin = 250 + nr;

  const float* zb = z + ((size_t)bb * NCH + h * 64) * WPOS;

  // ---- stage rel window into LDS ----
  for (int i = tid; i < nwin * 16; i += 256) {
    int r = i >> 4, j = i & 15;
    winU[r * 18 + j] = retc[(size_t)(pwin0 + r) * 16 + j];
  }

  // ---- stage q tile (affine from raw z, fp16-packed) ----
  {
    int xx = tid & 31, j = tid >> 5;
    int xcl = min(x0 + xx, WPOS - 1);
    int ch0 = h * 64 + 16 + 2 * j;
    float q0 = ca[ch0]     * zb[(size_t)(16 + 2 * j) * WPOS + xcl] + cb[ch0];
    float q1 = ca[ch0 + 1] * zb[(size_t)(17 + 2 * j) * WPOS + xcl] + cb[ch0 + 1];
    qsP[xx * 8 + j] = packh2(q0, q1);
  }

  // ---- k row per lane (affine from raw z), fp16-packed ----
  int yy = wvid * 64 + lane;
  int yc = min(yy, WPOS - 1);
  bool yok = (yy < WPOS);
  half2_t kh[8];
#pragma unroll
  for (int d = 0; d < 8; ++d) {
    int ch = h * 64 + 2 * d;
    float k0 = ca[ch]     * zb[(size_t)(2 * d) * WPOS + yc] + cb[ch];
    float k1 = ca[ch + 1] * zb[(size_t)(2 * d + 1) * WPOS + yc] + cb[ch + 1];
    kh[d] = __builtin_bit_cast(half2_t, packh2(k0, k1));
  }
  __syncthreads();

  // ---- fused S: qk + qr + kr via v_dot2_f32_f16; lanes on y, loop over x ----
  {
    int rowbase = yc + nr - 1;
    for (int xx = 0; xx < nr; ++xx) {
      const unsigned* wr = &winU[(size_t)(rowbase - xx) * 18];
      const unsigned* qp = &qsP[xx * 8];
      float dqk = 0.f, dqr = 0.f, dkr = 0.f;
#pragma unroll
      for (int j2 = 0; j2 < 4; ++j2) {
        uint2 ue = *(const uint2*)(wr + 2 * j2);
        uint2 uk = *(const uint2*)(wr + 8 + 2 * j2);
        uint2 uq = *(const uint2*)(qp + 2 * j2);
        half2_t qe0 = ash2(ue.x), qe1 = ash2(ue.y);
        half2_t ke0 = ash2(uk.x), ke1 = ash2(uk.y);
        half2_t q0  = ash2(uq.x), q1  = ash2(uq.y);
        half2_t k0 = kh[2 * j2], k1 = kh[2 * j2 + 1];
        dqk = FDOT2(q0, k0, dqk);  dqk = FDOT2(q1, k1, dqk);
        dqr = FDOT2(q0, qe0, dqr); dqr = FDOT2(q1, qe1, dqr);
        dkr = FDOT2(k0, ke0, dkr); dkr = FDOT2(k1, ke1, dkr);
      }
      float sval = la_qk * dqk + la_qr * dqr + la_kr * dkr + lbsum;
      if (yy < 260) S[xx * 260 + yy] = yok ? (_Float16)sval : (_Float16)0.f;
    }
  }
  __syncthreads();

  // ---- softmax over y; lanes on x, 8 slices; pair-wise fp16 reads ----
  int xx = lane & 31;
  int sl = wvid * 2 + (lane >> 5);
  int ylo = sl * 32;
  const unsigned* Srp = Su + xx * 130;
  {
    float m = -1e30f;
    if (sl < 7) {
#pragma unroll
      for (int pp = 0; pp < 16; ++pp) {
        half2_t hp = ash2(Srp[(ylo >> 1) + pp]);
        m = fmaxf(m, fmaxf((float)hp[0], (float)hp[1]));
      }
    } else {
#pragma unroll
      for (int pp = 0; pp < 13; ++pp) {
        half2_t hp = ash2(Srp[112 + pp]);
        m = fmaxf(m, fmaxf((float)hp[0], (float)hp[1]));
      }
      m = fmaxf(m, (float)S[xx * 260 + 250]);
    }
    sred[sl * 32 + xx] = m;
  }
  __syncthreads();
  float rowm = sred[0 * 32 + xx];
#pragma unroll
  for (int s = 1; s < 8; ++s) rowm = fmaxf(rowm, sred[s * 32 + xx]);
  __syncthreads();
  {
    float sacc = 0.f;
    unsigned* Swp = Su + xx * 130;
    if (sl < 7) {
#pragma unroll
      for (int pp = 0; pp < 16; ++pp) {
        half2_t hp = ash2(Swp[(ylo >> 1) + pp]);
        float e0 = __expf((float)hp[0] - rowm);
        float e1 = __expf((float)hp[1] - rowm);
        Swp[(ylo >> 1) + pp] = packh2(e0, e1);
        sacc += e0 + e1;
      }
    } else {
#pragma unroll
      for (int pp = 0; pp < 13; ++pp) {
        half2_t hp = ash2(Swp[112 + pp]);
        float e0 = __expf((float)hp[0] - rowm);
        float e1 = __expf((float)hp[1] - rowm);
        Swp[112 + pp] = packh2(e0, e1);
        sacc += e0 + e1;
      }
      float e = __expf((float)S[xx * 260 + 250] - rowm);
      S[xx * 260 + 250] = (_Float16)e;       // half 251 stays 0 -> safe pad weight
      sacc += e;
    }
    sred[sl * 32 + xx] = sacc;
  }
  __syncthreads();
  float denom = 0.f;
#pragma unroll
  for (int s = 0; s < 8; ++s) denom += sred[s * 32 + xx];

  // ---- attention: group sl = 4 d-channels, lanes on x ----
  int d0 = sl * 4;
  float4 acc = {0.f, 0.f, 0.f, 0.f};
  {
    const unsigned* vb = vh + ((size_t)bbh * 126) * 32 + d0;
    const unsigned* Sw = Su + xx * 130;
#pragma unroll 4
    for (int p2 = 0; p2 < 63; ++p2) {
      uint2 w2 = *(const uint2*)(Sw + 2 * p2);         // 4 weights (halfs 4p2..4p2+3)
      half2_t wa = ash2(w2.x), wb = ash2(w2.y);
      uint4 va = *(const uint4*)(vb + (size_t)(2 * p2) * 32);
      uint4 vb4 = *(const uint4*)(vb + (size_t)(2 * p2 + 1) * 32);
      acc.x = FDOT2(wa, ash2(va.x), acc.x); acc.x = FDOT2(wb, ash2(vb4.x), acc.x);
      acc.y = FDOT2(wa, ash2(va.y), acc.y); acc.y = FDOT2(wb, ash2(vb4.y), acc.y);
      acc.z = FDOT2(wa, ash2(va.z), acc.z); acc.z = FDOT2(wb, ash2(vb4.z), acc.z);
      acc.w = FDOT2(wa, ash2(va.w), acc.w); acc.w = FDOT2(wb, ash2(vb4.w), acc.w);
    }
  }
  {
    int xg = x0 + xx;
    int pmin = max(0, 250 - (x0 + nr - 1));
    int pmax = 500 - x0;
    int pi0 = max(pmin, 250 - x0);       // all-lane y2 >= 0
    int pi1 = min(pmax, 466 - x0);       // all-lane y2+3 <= 250
    const float* veb = vet + d0;
    const _Float16* Sh = S + xx * 260;
    int p = pmin;
    for (; p < pi0; ++p) {
      int y2 = xg + p - 250;
      float w0 = ((unsigned)y2 < (unsigned)WPOS) ? (float)Sh[y2] : 0.f;
      float4 v0 = *(const float4*)(veb + (size_t)p * 32);
      acc.x += w0 * v0.x; acc.y += w0 * v0.y;
      acc.z += w0 * v0.z; acc.w += w0 * v0.w;
    }
    for (; p + 3 <= pi1; p += 4) {
      int y2 = xg + p - 250;
      float w0 = (float)Sh[y2], w1 = (float)Sh[y2 + 1];
      float w2 = (float)Sh[y2 + 2], w3 = (float)Sh[y2 + 3];
      float4 v0 = *(const float4*)(veb + (size_t)(p + 0) * 32);
      float4 v1 = *(const float4*)(veb + (size_t)(p + 1) * 32);
      float4 v2 = *(const float4*)(veb + (size_t)(p + 2) * 32);
      float4 v3 = *(const float4*)(veb + (size_t)(p + 3) * 32);
      acc.x += w0 * v0.x + w1 * v1.x + w2 * v2.x + w3 * v3.x;
      acc.y += w0 * v0.y + w1 * v1.y + w2 * v2.y + w3 * v3.y;
      acc.z += w0 * v0.z + w1 * v1.z + w2 * v2.z + w3 * v3.z;
      acc.w += w0 * v0.w + w1 * v1.w + w2 * v2.w + w3 * v3.w;
    }
    for (; p <= pmax; ++p) {
      int y2 = xg + p - 250;
      float w0 = ((unsigned)y2 < (unsigned)WPOS) ? (float)Sh[y2] : 0.f;
      float4 v0 = *(const float4*)(veb + (size_t)p * 32);
      acc.x += w0 * v0.x; acc.y += w0 * v0.y;
      acc.z += w0 * v0.z; acc.w += w0 * v0.w;
    }
  }
  if (xx < nr) {
    float rinv = 1.0f / denom;
    int xg = x0 + xx;
    float av[4] = {acc.x, acc.y, acc.z, acc.w};
#pragma unroll
    for (int dd = 0; dd < 4; ++dd) {
      int d = d0 + dd;
      out[(((size_t)b * 256 + h * 32 + d) * 15 + hi) * WPOS + xg] = av[dd] * rinv;
    }
  }
}

// ---------------- launch ----------------
extern "C" void kernel_launch(void* const* d_in, const int* in_sizes, int n_in,
                              void* d_out, int out_size, void* d_ws, size_t ws_size,
                              hipStream_t stream) {
  const float* x    = (const float*)d_in[0];
  const float* y    = (const float*)d_in[1];
  const float* wk   = (const float*)d_in[2];
  const float* wq   = (const float*)d_in[3];
  const float* wv   = (const float*)d_in[4];
  const float* gk   = (const float*)d_in[5];
  const float* bk   = (const float*)d_in[6];
  const float* gq   = (const float*)d_in[7];
  const float* bq   = (const float*)d_in[8];
  const float* gkq  = (const float*)d_in[9];
  const float* bkq  = (const float*)d_in[10];
  const float* glog = (const float*)d_in[11];
  const float* blog = (const float*)d_in[12];
  const float* rel  = (const float*)d_in[13];
  float* out = (float*)d_out;
  float* ws  = (float*)d_ws;

  float* z      = ws + OFF_Z;
  unsigned* vh  = (unsigned*)(ws + OFF_VH);
  unsigned* retc= (unsigned*)(ws + OFF_RETC);
  float* vet    = ws + OFF_VET;
  float* p1q    = ws + OFF_P1Q;
  float* p1k    = ws + OFF_P1K;
  float* p2q    = ws + OFF_P2Q;
  float* p2k    = ws + OFF_P2K;
  float* ca     = ws + OFF_CA;
  float* cb     = ws + OFF_CB;
  float* lp     = ws + OFF_LP;
  float* lab    = ws + OFF_LAB;

  dim3 g1(4, 8, NBB);
  k_gemm<<<g1, 256, 0, stream>>>(x, y, wk, wq, wv, z);
  k_chan_stats<<<512, 256, 0, stream>>>(z, gk, bk, gq, bq, gkq, bkq, ca, cb);
  k_norm_vh<<<960, 256, 0, stream>>>(z, ca, cb, vh);
  k_rel_prep<<<(RELP * 48 + 255) / 256, 256, 0, stream>>>(rel, retc, vet);
  k_prefix<<<544, 256, 0, stream>>>(rel, p1q, p1k, p2q, p2k);
  k_logit_stats<<<240, 256, 0, stream>>>(z, ca, cb, p1q, p1k, p2q, p2k, lp);
  k_logit_final<<<1, 32, 0, stream>>>(lp, glog, blog, lab);
  k_attn<<<240 * 8, 256, 0, stream>>>(z, ca, cb, vh, retc, vet, lab, out);
}

// Round 7
// 194.253 us; speedup vs baseline: 3.6459x; 1.2747x over previous
//
#include <hip/hip_runtime.h>
#include <hip/hip_bf16.h>
#include <cstdint>

#define WPOS 251
#define NBB  30
#define NCH  512
#define RELP 501
#define NEPS 1e-5f

typedef _Float16 half2_t __attribute__((ext_vector_type(2)));
typedef _Float16 half8_t __attribute__((ext_vector_type(8)));
typedef float f32x16_t __attribute__((ext_vector_type(16)));

#if defined(__has_builtin)
#if __has_builtin(__builtin_amdgcn_fdot2)
#define FDOT2(a, b, c) __builtin_amdgcn_fdot2((a), (b), (c), false)
#endif
#endif
#ifndef FDOT2
#define FDOT2(a, b, c) ((float)(a)[0] * (float)(b)[0] + (float)(a)[1] * (float)(b)[1] + (c))
#endif

// ---------------- workspace layout (in float slots) ----------------
static constexpr size_t SZ_Z     = (size_t)NBB * NCH * WPOS;
static constexpr size_t OFF_Z    = 0;
static constexpr size_t OFF_VH   = OFF_Z + SZ_Z;                   // uint[bbh][126][32] half2 v pairs
static constexpr size_t SZ_VH    = (size_t)NBB * 8 * 126 * 32;
static constexpr size_t OFF_RETC = OFF_VH + SZ_VH;                 // uint[501][16]: qe|keR fp16 pairs
static constexpr size_t OFF_VET  = OFF_RETC + (size_t)RELP * 16;   // f32 [501][32]
static constexpr size_t OFF_P1Q  = OFF_VET + (size_t)RELP * 32;    // [16][502]
static constexpr size_t OFF_P1K  = OFF_P1Q + (size_t)16 * 502;
static constexpr size_t OFF_P2Q  = OFF_P1K + (size_t)16 * 502;     // [256][502]
static constexpr size_t OFF_P2K  = OFF_P2Q + (size_t)256 * 502;
static constexpr size_t OFF_CA   = OFF_P2K + (size_t)256 * 502;    // [512]
static constexpr size_t OFF_CB   = OFF_CA + 512;
static constexpr size_t OFF_LP   = OFF_CB + 512;                   // [240][6]
static constexpr size_t OFF_LAB  = OFF_LP + (size_t)240 * 6;       // [24][2]
static constexpr size_t OFF_LPP  = OFF_LAB + 48;                   // [960][548] partials

static __device__ __forceinline__ unsigned packh2(float a, float b) {
  half2_t t;
  t[0] = (_Float16)a;
  t[1] = (_Float16)b;
  return __builtin_bit_cast(unsigned, t);
}
static __device__ __forceinline__ half2_t ash2(unsigned u) {
  return __builtin_bit_cast(half2_t, u);
}

// ---------------- K1: kqv GEMM via fp16 MFMA: Z[bb][o][l] (raw, pre-BN) ----------------
// 64o x 64l tile per block; 4 waves = 4 quadrants of 32x32; K staged 64 at a time.
__global__ __launch_bounds__(256) void k_gemm(
    const float* __restrict__ x, const float* __restrict__ y,
    const float* __restrict__ wk, const float* __restrict__ wq,
    const float* __restrict__ wv, float* __restrict__ z) {
  int l0 = blockIdx.x * 64;
  int o0 = blockIdx.y * 64;
  int bb = blockIdx.z;
  int b = bb / 15, hi = bb % 15;
  const float* src;
  const float* wmat;
  int orow0;
  if (o0 < 128)      { wmat = wk; orow0 = o0;       src = x; }
  else if (o0 < 256) { wmat = wq; orow0 = o0 - 128; src = y; }
  else               { wmat = wv; orow0 = o0 - 256; src = x; }

  __shared__ _Float16 Ah[64][68];   // [o][k]  k-contiguous, pad->2-way banks
  __shared__ _Float16 Bh[64][68];   // [k][l]

  int tid = threadIdx.x;
  int lane = tid & 63, wv4 = tid >> 6;
  int wo = wv4 >> 1, wl = wv4 & 1;
  int m = lane & 31, kh = lane >> 5;

  f32x16_t acc = {};

  // staging coords (scalar, fully coalesced over lanes)
  int cA = tid & 63, ogA = tid >> 6;           // A: 16 o-rows per thread at col cA
  int lB = tid & 63, kgB = tid >> 6;           // B: 16 k-rows per thread at col lB
  int lglob = l0 + lB;
  bool lok = (lglob < WPOS);
  const float* xcol = src + (size_t)(((size_t)b * 256) * 15 + hi) * WPOS + lglob;

  for (int c0 = 0; c0 < 256; c0 += 64) {
#pragma unroll
    for (int i = 0; i < 16; ++i) {
      int o = ogA * 16 + i;
      Ah[o][cA] = (_Float16)wmat[(size_t)(orow0 + o) * 256 + c0 + cA];
    }
#pragma unroll
    for (int i = 0; i < 16; ++i) {
      int k = kgB * 16 + i;
      float v = lok ? xcol[(size_t)(c0 + k) * 15 * WPOS] : 0.f;
      Bh[k][lB] = (_Float16)v;
    }
    __syncthreads();
#pragma unroll
    for (int ks = 0; ks < 4; ++ks) {
      // A-frag: row wo*32+m, k = ks*16 + kh*8 + e
      const _Float16* ap = &Ah[wo * 32 + m][ks * 16 + kh * 8];
      uint2 aLo = *(const uint2*)(ap);
      uint2 aHi = *(const uint2*)(ap + 4);
      uint4 au = {aLo.x, aLo.y, aHi.x, aHi.y};
      half8_t af = __builtin_bit_cast(half8_t, au);
      // B-frag: col wl*32+m, k rows ks*16+kh*8+e
      half8_t bf;
      int kb = ks * 16 + kh * 8;
      int bcol = wl * 32 + m;
#pragma unroll
      for (int e = 0; e < 8; ++e) bf[e] = Bh[kb + e][bcol];
      acc = __builtin_amdgcn_mfma_f32_32x32x16_f16(af, bf, acc, 0, 0, 0);
    }
    __syncthreads();
  }

  // store: D col=lane&31, row=(r&3)+8*(r>>2)+4*(lane>>5)
  int n = lane & 31;
  int lout = l0 + wl * 32 + n;
  if (lout < WPOS) {
#pragma unroll
    for (int r = 0; r < 16; ++r) {
      int mrow = (r & 3) + 8 * (r >> 2) + 4 * kh;
      int o = o0 + wo * 32 + mrow;
      z[((size_t)bb * NCH + o) * WPOS + lout] = acc[r];
    }
  }
}

// ---------------- K2: per-channel BN stats -> affine a,b ----------------
__global__ __launch_bounds__(256) void k_chan_stats(
    const float* __restrict__ z,
    const float* __restrict__ gk, const float* __restrict__ bk,
    const float* __restrict__ gq, const float* __restrict__ bq,
    const float* __restrict__ gkq, const float* __restrict__ bkq,
    float* __restrict__ ca, float* __restrict__ cb) {
  int o = blockIdx.x;
  int tid = threadIdx.x;
  float s = 0.f, s2 = 0.f;
  for (int idx = tid; idx < NBB * WPOS; idx += 256) {
    int bb = idx / WPOS, l = idx - bb * WPOS;
    float v = z[((size_t)bb * NCH + o) * WPOS + l];
    s += v; s2 += v * v;
  }
  __shared__ float r1[256], r2[256];
  r1[tid] = s; r2[tid] = s2; __syncthreads();
  for (int st = 128; st > 0; st >>= 1) {
    if (tid < st) { r1[tid] += r1[tid + st]; r2[tid] += r2[tid + st]; }
    __syncthreads();
  }
  if (tid == 0) {
    float n = (float)(NBB * WPOS);
    float mean = r1[0] / n;
    float var = r2[0] / n - mean * mean;
    float g, bi;
    if (o < 128)      { g = gk[o];        bi = bk[o]; }
    else if (o < 256) { g = gq[o - 128];  bi = bq[o - 128]; }
    else              { g = gkq[o - 256]; bi = bkq[o - 256]; }
    float a = g / sqrtf(var + NEPS);
    ca[o] = a;
    cb[o] = bi - mean * a;
  }
}

// ---------------- K3: normalized v -> VH[bbh][pair][32] half2 pairs ----------------
__global__ __launch_bounds__(256) void k_norm_vh(
    const float* __restrict__ z, const float* __restrict__ ca, const float* __restrict__ cb,
    unsigned* __restrict__ vh) {
  int blk = blockIdx.x;            // 960 = 4 ltile * 240 bbh, bbh fastest (XCD locality)
  int bbh = blk % 240, lt = blk / 240;
  int bb = bbh >> 3, h = bbh & 7;
  int l0 = lt * 64;
  __shared__ float T[32][65];
  int tid = threadIdx.x;
  const float* zv = z + ((size_t)bb * NCH + h * 64 + 32) * WPOS;
  for (int i = tid; i < 32 * 64; i += 256) {
    int ch = i >> 6, l = i & 63;
    int gl = l0 + l;
    int cch = h * 64 + 32 + ch;
    T[ch][l] = (gl < WPOS) ? (ca[cch] * zv[(size_t)ch * WPOS + gl] + cb[cch]) : 0.f;
  }
  __syncthreads();
  int p0 = l0 >> 1;
  for (int i = tid; i < 32 * 32; i += 256) {
    int pl = i >> 5, ch = i & 31;
    int gp = p0 + pl;
    if (gp < 126)
      vh[((size_t)bbh * 126 + gp) * 32 + ch] = packh2(T[ch][2 * pl], T[ch][2 * pl + 1]);
  }
}

// ---------------- K4: rel prep: combined fp16 qe|keR table + vet ----------------
__global__ void k_rel_prep(const float* __restrict__ rel, unsigned* __restrict__ retc,
                           float* __restrict__ vet) {
  int idx = blockIdx.x * 256 + threadIdx.x;
  if (idx >= RELP * 48) return;
  int p = idx / 48, j = idx - p * 48;
  if (j < 16) {
    float lo, hi;
    if (j < 8) {
      lo = rel[(size_t)(2 * j) * RELP + p];
      hi = rel[(size_t)(2 * j + 1) * RELP + p];
    } else {
      int jj = j - 8;
      lo = rel[(size_t)(16 + 2 * jj) * RELP + (500 - p)];
      hi = rel[(size_t)(17 + 2 * jj) * RELP + (500 - p)];
    }
    retc[(size_t)p * 16 + j] = packh2(lo, hi);
  } else {
    int dd = j - 16;
    vet[(size_t)p * 32 + dd] = rel[(size_t)(32 + dd) * RELP + p];
  }
}

// ---------------- K5: prefix sums (parallel pair + Hillis-Steele scan) ----------------
__global__ __launch_bounds__(256) void k_prefix(const float* __restrict__ rel,
                                                float* __restrict__ p1q, float* __restrict__ p1k,
                                                float* __restrict__ p2q, float* __restrict__ p2k) {
  int task = blockIdx.x;   // 0..543
  const float* ra;
  const float* rb = nullptr;
  float* outp;
  if (task < 16)        { ra = rel + (size_t)task * RELP; outp = p1q + (size_t)task * 502; }
  else if (task < 32)   { ra = rel + (size_t)task * RELP; outp = p1k + (size_t)(task - 16) * 502; }
  else if (task < 288)  { int pr = task - 32;
                          ra = rel + (size_t)(pr >> 4) * RELP;
                          rb = rel + (size_t)(pr & 15) * RELP;
                          outp = p2q + (size_t)pr * 502; }
  else                  { int pr = task - 288;
                          ra = rel + (size_t)(16 + (pr >> 4)) * RELP;
                          rb = rel + (size_t)(16 + (pr & 15)) * RELP;
                          outp = p2k + (size_t)pr * 502; }
  __shared__ float buf[256];
  int t = threadIdx.x;
  int i0 = 2 * t, i1 = 2 * t + 1;
  float a0 = (i0 < RELP) ? (rb ? ra[i0] * rb[i0] : ra[i0]) : 0.f;
  float a1 = (i1 < RELP) ? (rb ? ra[i1] * rb[i1] : ra[i1]) : 0.f;
  buf[t] = a0 + a1;
  __syncthreads();
#pragma unroll
  for (int off = 1; off < 256; off <<= 1) {
    float v = buf[t];
    float add = (t >= off) ? buf[t - off] : 0.f;
    __syncthreads();
    buf[t] = v + add;
    __syncthreads();
  }
  float ex = buf[t] - (a0 + a1);          // exclusive scan over pairs
  if (i0 <= RELP) outp[i0] = ex;
  if (i1 <= RELP) outp[i1] = ex + a0;
}

// ---------------- block reduce helper ----------------
__device__ __forceinline__ float block_reduce(float v, float* red, int tid) {
  red[tid] = v; __syncthreads();
  for (int s = 128; s > 0; s >>= 1) {
    if (tid < s) red[tid] += red[tid + s];
    __syncthreads();
  }
  float r = red[0]; __syncthreads();
  return r;
}

// ---------------- K6a: logit BN partials per (bbh, x-chunk) ----------------
__global__ __launch_bounds__(256) void k_lstats1(
    const float* __restrict__ z, const float* __restrict__ ca, const float* __restrict__ cb,
    const float* __restrict__ p1q, const float* __restrict__ p1k,
    const float* __restrict__ p2q, const float* __restrict__ p2k,
    float* __restrict__ lpp) {
  int blk = blockIdx.x;            // 960 = 4 xc * 240 bbh, bbh fastest
  int bbh = blk % 240, xc = blk / 240;
  int bb = bbh >> 3, h = bbh & 7;
  int x0 = xc * 64;
  int tid = threadIdx.x;
  __shared__ float qs[16][68], ks[16][68];
  __shared__ float red[256];
  const float* zb = z + ((size_t)bb * NCH + h * 64) * WPOS;
  for (int idx = tid; idx < 16 * 64; idx += 256) {
    int d = idx >> 6, xl = idx & 63;
    int xg = x0 + xl;
    float kv = 0.f, qv = 0.f;
    if (xg < WPOS) {
      int chk = h * 64 + d, chq = h * 64 + 16 + d;
      kv = ca[chk] * zb[(size_t)d * WPOS + xg] + cb[chk];
      qv = ca[chq] * zb[(size_t)(16 + d) * WPOS + xg] + cb[chq];
    }
    ks[d][xl] = kv; qs[d][xl] = qv;
  }
  __syncthreads();
  float* outp = lpp + ((size_t)bbh * 4 + xc) * 548;
  if (tid < 16) {
    float s = 0.f;
    for (int xl = 0; xl < 64; ++xl) s += qs[tid][xl];
    outp[516 + tid] = s;
  } else if (tid < 32) {
    float s = 0.f;
    for (int xl = 0; xl < 64; ++xl) s += ks[tid - 16][xl];
    outp[532 + (tid - 16)] = s;
  }
  {
    int d = tid >> 4, d2 = tid & 15;
    float g1 = 0.f, g2 = 0.f;
    for (int xl = 0; xl < 64; ++xl) {
      g1 += qs[d][xl] * qs[d2][xl];
      g2 += ks[d][xl] * ks[d2][xl];
    }
    outp[tid] = g1;
    outp[256 + tid] = g2;
  }
  float v_sumqr = 0.f, v_sqqr = 0.f, v_sumkr = 0.f, v_sqkr = 0.f;
  for (int idx = tid; idx < 16 * 64; idx += 256) {
    int d = idx >> 6, xl = idx & 63;
    int xg = x0 + xl;
    if (xg < WPOS) {
      int ihi = 501 - xg, ilo = 250 - xg;
      float qv = qs[d][xl];
      v_sumqr += qv * (p1q[d * 502 + ihi] - p1q[d * 502 + ilo]);
      float t = 0.f;
      for (int d2 = 0; d2 < 16; ++d2) {
        const float* pp = p2q + (size_t)(d * 16 + d2) * 502;
        t += qs[d2][xl] * (pp[ihi] - pp[ilo]);
      }
      v_sqqr += qv * t;
      float kv = ks[d][xl];
      v_sumkr += kv * (p1k[d * 502 + ihi] - p1k[d * 502 + ilo]);
      float t2 = 0.f;
      for (int d2 = 0; d2 < 16; ++d2) {
        const float* pp = p2k + (size_t)(d * 16 + d2) * 502;
        t2 += ks[d2][xl] * (pp[ihi] - pp[ilo]);
      }
      v_sqkr += kv * t2;
    }
  }
  float r1 = block_reduce(v_sumqr, red, tid);
  float r2 = block_reduce(v_sqqr, red, tid);
  float r3 = block_reduce(v_sumkr, red, tid);
  float r4 = block_reduce(v_sqkr, red, tid);
  if (tid == 0) { outp[512] = r1; outp[513] = r2; outp[514] = r3; outp[515] = r4; }
}

// ---------------- K6b: combine partials -> lp[bbh][6] ----------------
__global__ __launch_bounds__(256) void k_lstats2(const float* __restrict__ lpp,
                                                 float* __restrict__ lp) {
  int bbh = blockIdx.x;
  int tid = threadIdx.x;
  __shared__ float red[256];
  __shared__ float qsums[16], ksums[16];
  const float* b0 = lpp + (size_t)bbh * 4 * 548;
  float qg = b0[tid] + b0[548 + tid] + b0[1096 + tid] + b0[1644 + tid];
  float kg = b0[256 + tid] + b0[804 + tid] + b0[1352 + tid] + b0[1900 + tid];
  if (tid < 16) {
    qsums[tid] = b0[516 + tid] + b0[1064 + tid] + b0[1612 + tid] + b0[2160 + tid];
    ksums[tid] = b0[532 + tid] + b0[1080 + tid] + b0[1628 + tid] + b0[2176 + tid];
  }
  float sqqk = block_reduce(qg * kg, red, tid);
  if (tid == 0) {
    float sum_qk = 0.f;
    for (int d = 0; d < 16; ++d) sum_qk += qsums[d] * ksums[d];
    float s1 = 0.f, s2 = 0.f, s3 = 0.f, s4 = 0.f;
    for (int c = 0; c < 4; ++c) {
      const float* bc = b0 + (size_t)c * 548;
      s1 += bc[512]; s2 += bc[513]; s3 += bc[514]; s4 += bc[515];
    }
    float* o = lp + (size_t)bbh * 6;
    o[0] = sum_qk; o[1] = sqqk;
    o[2] = s1; o[3] = s2; o[4] = s3; o[5] = s4;
  }
}

// ---------------- K7: finalize logit BN affine ----------------
__global__ void k_logit_final(const float* __restrict__ lp,
                              const float* __restrict__ glog, const float* __restrict__ blog,
                              float* __restrict__ lab) {
  int c = threadIdx.x;
  if (c >= 24) return;
  int grp = c >> 3, h = c & 7;
  float s = 0.f, s2 = 0.f;
  for (int bb = 0; bb < NBB; ++bb) {
    const float* o = lp + (size_t)(bb * 8 + h) * 6 + grp * 2;
    s += o[0]; s2 += o[1];
  }
  float n = (float)NBB * (float)WPOS * (float)WPOS;
  float mean = s / n;
  float var = s2 / n - mean * mean;
  float la = glog[c] / sqrtf(var + NEPS);
  lab[c * 2] = la;
  lab[c * 2 + 1] = blog[c] - mean * la;
}

// ---------------- K8: fused logits + softmax + attention ----------------
// 1920 blocks = 8 tiles x 240 bbh, bbh fastest -> blk%8 == bbh%8 (XCD locality).
__global__ __launch_bounds__(256) void k_attn(
    const float* __restrict__ z, const float* __restrict__ ca, const float* __restrict__ cb,
    const unsigned* __restrict__ vh,
    const unsigned* __restrict__ retc, const float* __restrict__ vet,
    const float* __restrict__ lab, float* __restrict__ out) {
  int blk = blockIdx.x;
  int bbh = blk % 240, tile = blk / 240;
  int bb = bbh >> 3, h = bbh & 7;
  int b = bb / 15, hi = bb % 15;
  int x0 = tile * 32;
  int nr = min(32, WPOS - x0);
  int tid = threadIdx.x;
  int lane = tid & 63, wvid = tid >> 6;

  float la_qk = lab[h * 2],        lb0 = lab[h * 2 + 1];
  float la_qr = lab[(8 + h) * 2],  lb1 = lab[(8 + h) * 2 + 1];
  float la_kr = lab[(16 + h) * 2], lb2 = lab[(16 + h) * 2 + 1];
  float lbsum = lb0 + lb1 + lb2;

  __shared__ __align__(16) unsigned Su[32 * 130];     // fp16 S, 260 halfs/row
  __shared__ __align__(16) unsigned winU[282 * 18];   // fp16-pair rel rows
  __shared__ __align__(16) unsigned uSh[256];
  _Float16* S = (_Float16*)Su;

  unsigned* qsP = uSh;
  float* sred = (float*)uSh;

  int pwin0 = 251 - x0 - nr;
  int nwin = 250 + nr;

  const float* zb = z + ((size_t)bb * NCH + h * 64) * WPOS;

  for (int i = tid; i < nwin * 16; i += 256) {
    int r = i >> 4, j = i & 15;
    winU[r * 18 + j] = retc[(size_t)(pwin0 + r) * 16 + j];
  }

  {
    int xx = tid & 31, j = tid >> 5;
    int xcl = min(x0 + xx, WPOS - 1);
    int ch0 = h * 64 + 16 + 2 * j;
    float q0 = ca[ch0]     * zb[(size_t)(16 + 2 * j) * WPOS + xcl] + cb[ch0];
    float q1 = ca[ch0 + 1] * zb[(size_t)(17 + 2 * j) * WPOS + xcl] + cb[ch0 + 1];
    qsP[xx * 8 + j] = packh2(q0, q1);
  }

  int yy = wvid * 64 + lane;
  int yc = min(yy, WPOS - 1);
  bool yok = (yy < WPOS);
  half2_t kh[8];
#pragma unroll
  for (int d = 0; d < 8; ++d) {
    int ch = h * 64 + 2 * d;
    float k0 = ca[ch]     * zb[(size_t)(2 * d) * WPOS + yc] + cb[ch];
    float k1 = ca[ch + 1] * zb[(size_t)(2 * d + 1) * WPOS + yc] + cb[ch + 1];
    kh[d] = __builtin_bit_cast(half2_t, packh2(k0, k1));
  }
  __syncthreads();

  {
    int rowbase = yc + nr - 1;
    for (int xx = 0; xx < nr; ++xx) {
      const unsigned* wr = &winU[(size_t)(rowbase - xx) * 18];
      const unsigned* qp = &qsP[xx * 8];
      float dqk = 0.f, dqr = 0.f, dkr = 0.f;
#pragma unroll
      for (int j2 = 0; j2 < 4; ++j2) {
        uint2 ue = *(const uint2*)(wr + 2 * j2);
        uint2 uk = *(const uint2*)(wr + 8 + 2 * j2);
        uint2 uq = *(const uint2*)(qp + 2 * j2);
        half2_t qe0 = ash2(ue.x), qe1 = ash2(ue.y);
        half2_t ke0 = ash2(uk.x), ke1 = ash2(uk.y);
        half2_t q0  = ash2(uq.x), q1  = ash2(uq.y);
        half2_t k0 = kh[2 * j2], k1 = kh[2 * j2 + 1];
        dqk = FDOT2(q0, k0, dqk);  dqk = FDOT2(q1, k1, dqk);
        dqr = FDOT2(q0, qe0, dqr); dqr = FDOT2(q1, qe1, dqr);
        dkr = FDOT2(k0, ke0, dkr); dkr = FDOT2(k1, ke1, dkr);
      }
      float sval = la_qk * dqk + la_qr * dqr + la_kr * dkr + lbsum;
      if (yy < 260) S[xx * 260 + yy] = yok ? (_Float16)sval : (_Float16)0.f;
    }
  }
  __syncthreads();

  int xx = lane & 31;
  int sl = wvid * 2 + (lane >> 5);
  int ylo = sl * 32;
  const unsigned* Srp = Su + xx * 130;
  {
    float m = -1e30f;
    if (sl < 7) {
#pragma unroll
      for (int pp = 0; pp < 16; ++pp) {
        half2_t hp = ash2(Srp[(ylo >> 1) + pp]);
        m = fmaxf(m, fmaxf((float)hp[0], (float)hp[1]));
      }
    } else {
#pragma unroll
      for (int pp = 0; pp < 13; ++pp) {
        half2_t hp = ash2(Srp[112 + pp]);
        m = fmaxf(m, fmaxf((float)hp[0], (float)hp[1]));
      }
      m = fmaxf(m, (float)S[xx * 260 + 250]);
    }
    sred[sl * 32 + xx] = m;
  }
  __syncthreads();
  float rowm = sred[0 * 32 + xx];
#pragma unroll
  for (int s = 1; s < 8; ++s) rowm = fmaxf(rowm, sred[s * 32 + xx]);
  __syncthreads();
  {
    float sacc = 0.f;
    unsigned* Swp = Su + xx * 130;
    if (sl < 7) {
#pragma unroll
      for (int pp = 0; pp < 16; ++pp) {
        half2_t hp = ash2(Swp[(ylo >> 1) + pp]);
        float e0 = __expf((float)hp[0] - rowm);
        float e1 = __expf((float)hp[1] - rowm);
        Swp[(ylo >> 1) + pp] = packh2(e0, e1);
        sacc += e0 + e1;
      }
    } else {
#pragma unroll
      for (int pp = 0; pp < 13; ++pp) {
        half2_t hp = ash2(Swp[112 + pp]);
        float e0 = __expf((float)hp[0] - rowm);
        float e1 = __expf((float)hp[1] - rowm);
        Swp[112 + pp] = packh2(e0, e1);
        sacc += e0 + e1;
      }
      float e = __expf((float)S[xx * 260 + 250] - rowm);
      S[xx * 260 + 250] = (_Float16)e;
      sacc += e;
    }
    sred[sl * 32 + xx] = sacc;
  }
  __syncthreads();
  float denom = 0.f;
#pragma unroll
  for (int s = 0; s < 8; ++s) denom += sred[s * 32 + xx];

  int d0 = sl * 4;
  float4 acc = {0.f, 0.f, 0.f, 0.f};
  {
    const unsigned* vb = vh + ((size_t)bbh * 126) * 32 + d0;
    const unsigned* Sw = Su + xx * 130;
#pragma unroll 4
    for (int p2 = 0; p2 < 63; ++p2) {
      uint2 w2 = *(const uint2*)(Sw + 2 * p2);
      half2_t wa = ash2(w2.x), wb = ash2(w2.y);
      uint4 va = *(const uint4*)(vb + (size_t)(2 * p2) * 32);
      uint4 vb4 = *(const uint4*)(vb + (size_t)(2 * p2 + 1) * 32);
      acc.x = FDOT2(wa, ash2(va.x), acc.x); acc.x = FDOT2(wb, ash2(vb4.x), acc.x);
      acc.y = FDOT2(wa, ash2(va.y), acc.y); acc.y = FDOT2(wb, ash2(vb4.y), acc.y);
      acc.z = FDOT2(wa, ash2(va.z), acc.z); acc.z = FDOT2(wb, ash2(vb4.z), acc.z);
      acc.w = FDOT2(wa, ash2(va.w), acc.w); acc.w = FDOT2(wb, ash2(vb4.w), acc.w);
    }
  }
  {
    int xg = x0 + xx;
    int pmin = max(0, 250 - (x0 + nr - 1));
    int pmax = 500 - x0;
    int pi0 = max(pmin, 250 - x0);
    int pi1 = min(pmax, 466 - x0);
    const float* veb = vet + d0;
    const _Float16* Sh = S + xx * 260;
    int p = pmin;
    for (; p < pi0; ++p) {
      int y2 = xg + p - 250;
      float w0 = ((unsigned)y2 < (unsigned)WPOS) ? (float)Sh[y2] : 0.f;
      float4 v0 = *(const float4*)(veb + (size_t)p * 32);
      acc.x += w0 * v0.x; acc.y += w0 * v0.y;
      acc.z += w0 * v0.z; acc.w += w0 * v0.w;
    }
    for (; p + 3 <= pi1; p += 4) {
      int y2 = xg + p - 250;
      float w0 = (float)Sh[y2], w1 = (float)Sh[y2 + 1];
      float w2 = (float)Sh[y2 + 2], w3 = (float)Sh[y2 + 3];
      float4 v0 = *(const float4*)(veb + (size_t)(p + 0) * 32);
      float4 v1 = *(const float4*)(veb + (size_t)(p + 1) * 32);
      float4 v2 = *(const float4*)(veb + (size_t)(p + 2) * 32);
      float4 v3 = *(const float4*)(veb + (size_t)(p + 3) * 32);
      acc.x += w0 * v0.x + w1 * v1.x + w2 * v2.x + w3 * v3.x;
      acc.y += w0 * v0.y + w1 * v1.y + w2 * v2.y + w3 * v3.y;
      acc.z += w0 * v0.z + w1 * v1.z + w2 * v2.z + w3 * v3.z;
      acc.w += w0 * v0.w + w1 * v1.w + w2 * v2.w + w3 * v3.w;
    }
    for (; p <= pmax; ++p) {
      int y2 = xg + p - 250;
      float w0 = ((unsigned)y2 < (unsigned)WPOS) ? (float)Sh[y2] : 0.f;
      float4 v0 = *(const float4*)(veb + (size_t)p * 32);
      acc.x += w0 * v0.x; acc.y += w0 * v0.y;
      acc.z += w0 * v0.z; acc.w += w0 * v0.w;
    }
  }
  if (xx < nr) {
    float rinv = 1.0f / denom;
    int xg = x0 + xx;
    float av[4] = {acc.x, acc.y, acc.z, acc.w};
#pragma unroll
    for (int dd = 0; dd < 4; ++dd) {
      int d = d0 + dd;
      out[(((size_t)b * 256 + h * 32 + d) * 15 + hi) * WPOS + xg] = av[dd] * rinv;
    }
  }
}

// ---------------- launch ----------------
extern "C" void kernel_launch(void* const* d_in, const int* in_sizes, int n_in,
                              void* d_out, int out_size, void* d_ws, size_t ws_size,
                              hipStream_t stream) {
  const float* x    = (const float*)d_in[0];
  const float* y    = (const float*)d_in[1];
  const float* wk   = (const float*)d_in[2];
  const float* wq   = (const float*)d_in[3];
  const float* wv   = (const float*)d_in[4];
  const float* gk   = (const float*)d_in[5];
  const float* bk   = (const float*)d_in[6];
  const float* gq   = (const float*)d_in[7];
  const float* bq   = (const float*)d_in[8];
  const float* gkq  = (const float*)d_in[9];
  const float* bkq  = (const float*)d_in[10];
  const float* glog = (const float*)d_in[11];
  const float* blog = (const float*)d_in[12];
  const float* rel  = (const float*)d_in[13];
  float* out = (float*)d_out;
  float* ws  = (float*)d_ws;

  float* z      = ws + OFF_Z;
  unsigned* vh  = (unsigned*)(ws + OFF_VH);
  unsigned* retc= (unsigned*)(ws + OFF_RETC);
  float* vet    = ws + OFF_VET;
  float* p1q    = ws + OFF_P1Q;
  float* p1k    = ws + OFF_P1K;
  float* p2q    = ws + OFF_P2Q;
  float* p2k    = ws + OFF_P2K;
  float* ca     = ws + OFF_CA;
  float* cb     = ws + OFF_CB;
  float* lp     = ws + OFF_LP;
  float* lab    = ws + OFF_LAB;
  float* lpp    = ws + OFF_LPP;

  dim3 g1(4, 8, NBB);
  k_gemm<<<g1, 256, 0, stream>>>(x, y, wk, wq, wv, z);
  k_chan_stats<<<512, 256, 0, stream>>>(z, gk, bk, gq, bq, gkq, bkq, ca, cb);
  k_norm_vh<<<960, 256, 0, stream>>>(z, ca, cb, vh);
  k_rel_prep<<<(RELP * 48 + 255) / 256, 256, 0, stream>>>(rel, retc, vet);
  k_prefix<<<544, 256, 0, stream>>>(rel, p1q, p1k, p2q, p2k);
  k_lstats1<<<960, 256, 0, stream>>>(z, ca, cb, p1q, p1k, p2q, p2k, lpp);
  k_lstats2<<<240, 256, 0, stream>>>(lpp, lp);
  k_logit_final<<<1, 32, 0, stream>>>(lp, glog, blog, lab);
  k_attn<<<240 * 8, 256, 0, stream>>>(z, ca, cb, vh, retc, vet, lab, out);
}

// Round 8
// 190.342 us; speedup vs baseline: 3.7208x; 1.0205x over previous
//
#include <hip/hip_runtime.h>
#include <hip/hip_bf16.h>
#include <cstdint>

#define WPOS 251
#define NBB  30
#define NCH  512
#define RELP 501
#define NEPS 1e-5f

typedef _Float16 half2_t __attribute__((ext_vector_type(2)));
typedef _Float16 half8_t __attribute__((ext_vector_type(8)));
typedef float f32x16_t __attribute__((ext_vector_type(16)));

#if defined(__has_builtin)
#if __has_builtin(__builtin_amdgcn_fdot2)
#define FDOT2(a, b, c) __builtin_amdgcn_fdot2((a), (b), (c), false)
#endif
#endif
#ifndef FDOT2
#define FDOT2(a, b, c) ((float)(a)[0] * (float)(b)[0] + (float)(a)[1] * (float)(b)[1] + (c))
#endif

// ---------------- workspace layout (in float slots) ----------------
static constexpr size_t SZ_Z     = (size_t)NBB * NCH * WPOS;
static constexpr size_t OFF_Z    = 0;
static constexpr size_t OFF_VH   = OFF_Z + SZ_Z;                   // uint[bbh][126][32] half2 v pairs
static constexpr size_t SZ_VH    = (size_t)NBB * 8 * 126 * 32;
static constexpr size_t OFF_RETC = OFF_VH + SZ_VH;                 // uint[501][16]: qe|keR fp16 pairs
static constexpr size_t OFF_VET  = OFF_RETC + (size_t)RELP * 16;   // f32 [501][32]
static constexpr size_t OFF_VETP = OFF_VET + (size_t)RELP * 32;    // uint[251][32] half2 p-pairs
static constexpr size_t OFF_P1Q  = OFF_VETP + (size_t)251 * 32;    // [16][502]
static constexpr size_t OFF_P1K  = OFF_P1Q + (size_t)16 * 502;
static constexpr size_t OFF_P2Q  = OFF_P1K + (size_t)16 * 502;     // [256][502]
static constexpr size_t OFF_P2K  = OFF_P2Q + (size_t)256 * 502;
static constexpr size_t OFF_CA   = OFF_P2K + (size_t)256 * 502;    // [512]
static constexpr size_t OFF_CB   = OFF_CA + 512;
static constexpr size_t OFF_LP   = OFF_CB + 512;                   // [240][6]
static constexpr size_t OFF_LAB  = OFF_LP + (size_t)240 * 6;       // [24][2]
static constexpr size_t OFF_LPP  = OFF_LAB + 48;                   // [960][548] partials

static __device__ __forceinline__ unsigned packh2(float a, float b) {
  half2_t t;
  t[0] = (_Float16)a;
  t[1] = (_Float16)b;
  return __builtin_bit_cast(unsigned, t);
}
static __device__ __forceinline__ half2_t ash2(unsigned u) {
  return __builtin_bit_cast(half2_t, u);
}

// ---------------- K1: kqv GEMM via fp16 MFMA: Z[bb][o][l] (raw, pre-BN) ----------------
__global__ __launch_bounds__(256) void k_gemm(
    const float* __restrict__ x, const float* __restrict__ y,
    const float* __restrict__ wk, const float* __restrict__ wq,
    const float* __restrict__ wv, float* __restrict__ z) {
  int l0 = blockIdx.x * 64;
  int o0 = blockIdx.y * 64;
  int bb = blockIdx.z;
  int b = bb / 15, hi = bb % 15;
  const float* src;
  const float* wmat;
  int orow0;
  if (o0 < 128)      { wmat = wk; orow0 = o0;       src = x; }
  else if (o0 < 256) { wmat = wq; orow0 = o0 - 128; src = y; }
  else               { wmat = wv; orow0 = o0 - 256; src = x; }

  __shared__ _Float16 Ah[64][68];   // [o][k]
  __shared__ _Float16 Bh[64][68];   // [k][l]

  int tid = threadIdx.x;
  int lane = tid & 63, wv4 = tid >> 6;
  int wo = wv4 >> 1, wl = wv4 & 1;
  int m = lane & 31, kh = lane >> 5;

  f32x16_t acc = {};

  int cA = tid & 63, ogA = tid >> 6;
  int lB = tid & 63, kgB = tid >> 6;
  int lglob = l0 + lB;
  bool lok = (lglob < WPOS);
  const float* xcol = src + (size_t)(((size_t)b * 256) * 15 + hi) * WPOS + lglob;

  for (int c0 = 0; c0 < 256; c0 += 64) {
#pragma unroll
    for (int i = 0; i < 16; ++i) {
      int o = ogA * 16 + i;
      Ah[o][cA] = (_Float16)wmat[(size_t)(orow0 + o) * 256 + c0 + cA];
    }
#pragma unroll
    for (int i = 0; i < 16; ++i) {
      int k = kgB * 16 + i;
      float v = lok ? xcol[(size_t)(c0 + k) * 15 * WPOS] : 0.f;
      Bh[k][lB] = (_Float16)v;
    }
    __syncthreads();
#pragma unroll
    for (int ks = 0; ks < 4; ++ks) {
      const _Float16* ap = &Ah[wo * 32 + m][ks * 16 + kh * 8];
      uint2 aLo = *(const uint2*)(ap);
      uint2 aHi = *(const uint2*)(ap + 4);
      uint4 au = {aLo.x, aLo.y, aHi.x, aHi.y};
      half8_t af = __builtin_bit_cast(half8_t, au);
      half8_t bf;
      int kb = ks * 16 + kh * 8;
      int bcol = wl * 32 + m;
#pragma unroll
      for (int e = 0; e < 8; ++e) bf[e] = Bh[kb + e][bcol];
      acc = __builtin_amdgcn_mfma_f32_32x32x16_f16(af, bf, acc, 0, 0, 0);
    }
    __syncthreads();
  }

  int n = lane & 31;
  int lout = l0 + wl * 32 + n;
  if (lout < WPOS) {
#pragma unroll
    for (int r = 0; r < 16; ++r) {
      int mrow = (r & 3) + 8 * (r >> 2) + 4 * kh;
      int o = o0 + wo * 32 + mrow;
      z[((size_t)bb * NCH + o) * WPOS + lout] = acc[r];
    }
  }
}

// ---------------- K2: per-channel BN stats -> affine a,b ----------------
__global__ __launch_bounds__(256) void k_chan_stats(
    const float* __restrict__ z,
    const float* __restrict__ gk, const float* __restrict__ bk,
    const float* __restrict__ gq, const float* __restrict__ bq,
    const float* __restrict__ gkq, const float* __restrict__ bkq,
    float* __restrict__ ca, float* __restrict__ cb) {
  int o = blockIdx.x;
  int tid = threadIdx.x;
  float s = 0.f, s2 = 0.f;
  for (int idx = tid; idx < NBB * WPOS; idx += 256) {
    int bb = idx / WPOS, l = idx - bb * WPOS;
    float v = z[((size_t)bb * NCH + o) * WPOS + l];
    s += v; s2 += v * v;
  }
  __shared__ float r1[256], r2[256];
  r1[tid] = s; r2[tid] = s2; __syncthreads();
  for (int st = 128; st > 0; st >>= 1) {
    if (tid < st) { r1[tid] += r1[tid + st]; r2[tid] += r2[tid + st]; }
    __syncthreads();
  }
  if (tid == 0) {
    float n = (float)(NBB * WPOS);
    float mean = r1[0] / n;
    float var = r2[0] / n - mean * mean;
    float g, bi;
    if (o < 128)      { g = gk[o];        bi = bk[o]; }
    else if (o < 256) { g = gq[o - 128];  bi = bq[o - 128]; }
    else              { g = gkq[o - 256]; bi = bkq[o - 256]; }
    float a = g / sqrtf(var + NEPS);
    ca[o] = a;
    cb[o] = bi - mean * a;
  }
}

// ---------------- K3: normalized v -> VH[bbh][pair][32] half2 pairs ----------------
__global__ __launch_bounds__(256) void k_norm_vh(
    const float* __restrict__ z, const float* __restrict__ ca, const float* __restrict__ cb,
    unsigned* __restrict__ vh) {
  int blk = blockIdx.x;
  int bbh = blk % 240, lt = blk / 240;
  int bb = bbh >> 3, h = bbh & 7;
  int l0 = lt * 64;
  __shared__ float T[32][65];
  int tid = threadIdx.x;
  const float* zv = z + ((size_t)bb * NCH + h * 64 + 32) * WPOS;
  for (int i = tid; i < 32 * 64; i += 256) {
    int ch = i >> 6, l = i & 63;
    int gl = l0 + l;
    int cch = h * 64 + 32 + ch;
    T[ch][l] = (gl < WPOS) ? (ca[cch] * zv[(size_t)ch * WPOS + gl] + cb[cch]) : 0.f;
  }
  __syncthreads();
  int p0 = l0 >> 1;
  for (int i = tid; i < 32 * 32; i += 256) {
    int pl = i >> 5, ch = i & 31;
    int gp = p0 + pl;
    if (gp < 126)
      vh[((size_t)bbh * 126 + gp) * 32 + ch] = packh2(T[ch][2 * pl], T[ch][2 * pl + 1]);
  }
}

// ---------------- K4: rel prep: fp16 qe|keR table + vet + vetp pairs ----------------
__global__ void k_rel_prep(const float* __restrict__ rel, unsigned* __restrict__ retc,
                           float* __restrict__ vet, unsigned* __restrict__ vetp) {
  int idx = blockIdx.x * 256 + threadIdx.x;
  if (idx < RELP * 48) {
    int p = idx / 48, j = idx - p * 48;
    if (j < 16) {
      float lo, hi;
      if (j < 8) {
        lo = rel[(size_t)(2 * j) * RELP + p];
        hi = rel[(size_t)(2 * j + 1) * RELP + p];
      } else {
        int jj = j - 8;
        lo = rel[(size_t)(16 + 2 * jj) * RELP + (500 - p)];
        hi = rel[(size_t)(17 + 2 * jj) * RELP + (500 - p)];
      }
      retc[(size_t)p * 16 + j] = packh2(lo, hi);
    } else {
      int dd = j - 16;
      vet[(size_t)p * 32 + dd] = rel[(size_t)(32 + dd) * RELP + p];
    }
  } else {
    int i2 = idx - RELP * 48;
    if (i2 >= 251 * 32) return;
    int t = i2 >> 5, ch = i2 & 31;
    float lo = rel[(size_t)(32 + ch) * RELP + 2 * t];
    float hi = (2 * t + 1 <= 500) ? rel[(size_t)(32 + ch) * RELP + 2 * t + 1] : 0.f;
    vetp[(size_t)t * 32 + ch] = packh2(lo, hi);
  }
}

// ---------------- K5: prefix sums (parallel pair + Hillis-Steele scan) ----------------
__global__ __launch_bounds__(256) void k_prefix(const float* __restrict__ rel,
                                                float* __restrict__ p1q, float* __restrict__ p1k,
                                                float* __restrict__ p2q, float* __restrict__ p2k) {
  int task = blockIdx.x;   // 0..543
  const float* ra;
  const float* rb = nullptr;
  float* outp;
  if (task < 16)        { ra = rel + (size_t)task * RELP; outp = p1q + (size_t)task * 502; }
  else if (task < 32)   { ra = rel + (size_t)task * RELP; outp = p1k + (size_t)(task - 16) * 502; }
  else if (task < 288)  { int pr = task - 32;
                          ra = rel + (size_t)(pr >> 4) * RELP;
                          rb = rel + (size_t)(pr & 15) * RELP;
                          outp = p2q + (size_t)pr * 502; }
  else                  { int pr = task - 288;
                          ra = rel + (size_t)(16 + (pr >> 4)) * RELP;
                          rb = rel + (size_t)(16 + (pr & 15)) * RELP;
                          outp = p2k + (size_t)pr * 502; }
  __shared__ float buf[256];
  int t = threadIdx.x;
  int i0 = 2 * t, i1 = 2 * t + 1;
  float a0 = (i0 < RELP) ? (rb ? ra[i0] * rb[i0] : ra[i0]) : 0.f;
  float a1 = (i1 < RELP) ? (rb ? ra[i1] * rb[i1] : ra[i1]) : 0.f;
  buf[t] = a0 + a1;
  __syncthreads();
#pragma unroll
  for (int off = 1; off < 256; off <<= 1) {
    float v = buf[t];
    float add = (t >= off) ? buf[t - off] : 0.f;
    __syncthreads();
    buf[t] = v + add;
    __syncthreads();
  }
  float ex = buf[t] - (a0 + a1);
  if (i0 <= RELP) outp[i0] = ex;
  if (i1 <= RELP) outp[i1] = ex + a0;
}

// ---------------- block reduce helper ----------------
__device__ __forceinline__ float block_reduce(float v, float* red, int tid) {
  red[tid] = v; __syncthreads();
  for (int s = 128; s > 0; s >>= 1) {
    if (tid < s) red[tid] += red[tid + s];
    __syncthreads();
  }
  float r = red[0]; __syncthreads();
  return r;
}

// ---------------- K6a: logit BN partials per (bbh, x-chunk) ----------------
__global__ __launch_bounds__(256) void k_lstats1(
    const float* __restrict__ z, const float* __restrict__ ca, const float* __restrict__ cb,
    const float* __restrict__ p1q, const float* __restrict__ p1k,
    const float* __restrict__ p2q, const float* __restrict__ p2k,
    float* __restrict__ lpp) {
  int blk = blockIdx.x;
  int bbh = blk % 240, xc = blk / 240;
  int bb = bbh >> 3, h = bbh & 7;
  int x0 = xc * 64;
  int tid = threadIdx.x;
  __shared__ float qs[16][68], ks[16][68];
  __shared__ float red[256];
  const float* zb = z + ((size_t)bb * NCH + h * 64) * WPOS;
  for (int idx = tid; idx < 16 * 64; idx += 256) {
    int d = idx >> 6, xl = idx & 63;
    int xg = x0 + xl;
    float kv = 0.f, qv = 0.f;
    if (xg < WPOS) {
      int chk = h * 64 + d, chq = h * 64 + 16 + d;
      kv = ca[chk] * zb[(size_t)d * WPOS + xg] + cb[chk];
      qv = ca[chq] * zb[(size_t)(16 + d) * WPOS + xg] + cb[chq];
    }
    ks[d][xl] = kv; qs[d][xl] = qv;
  }
  __syncthreads();
  float* outp = lpp + ((size_t)bbh * 4 + xc) * 548;
  if (tid < 16) {
    float s = 0.f;
    for (int xl = 0; xl < 64; ++xl) s += qs[tid][xl];
    outp[516 + tid] = s;
  } else if (tid < 32) {
    float s = 0.f;
    for (int xl = 0; xl < 64; ++xl) s += ks[tid - 16][xl];
    outp[532 + (tid - 16)] = s;
  }
  {
    int d = tid >> 4, d2 = tid & 15;
    float g1 = 0.f, g2 = 0.f;
    for (int xl = 0; xl < 64; ++xl) {
      g1 += qs[d][xl] * qs[d2][xl];
      g2 += ks[d][xl] * ks[d2][xl];
    }
    outp[tid] = g1;
    outp[256 + tid] = g2;
  }
  float v_sumqr = 0.f, v_sqqr = 0.f, v_sumkr = 0.f, v_sqkr = 0.f;
  for (int idx = tid; idx < 16 * 64; idx += 256) {
    int d = idx >> 6, xl = idx & 63;
    int xg = x0 + xl;
    if (xg < WPOS) {
      int ihi = 501 - xg, ilo = 250 - xg;
      float qv = qs[d][xl];
      v_sumqr += qv * (p1q[d * 502 + ihi] - p1q[d * 502 + ilo]);
      float t = 0.f;
      for (int d2 = 0; d2 < 16; ++d2) {
        const float* pp = p2q + (size_t)(d * 16 + d2) * 502;
        t += qs[d2][xl] * (pp[ihi] - pp[ilo]);
      }
      v_sqqr += qv * t;
      float kv = ks[d][xl];
      v_sumkr += kv * (p1k[d * 502 + ihi] - p1k[d * 502 + ilo]);
      float t2 = 0.f;
      for (int d2 = 0; d2 < 16; ++d2) {
        const float* pp = p2k + (size_t)(d * 16 + d2) * 502;
        t2 += ks[d2][xl] * (pp[ihi] - pp[ilo]);
      }
      v_sqkr += kv * t2;
    }
  }
  float r1 = block_reduce(v_sumqr, red, tid);
  float r2 = block_reduce(v_sqqr, red, tid);
  float r3 = block_reduce(v_sumkr, red, tid);
  float r4 = block_reduce(v_sqkr, red, tid);
  if (tid == 0) { outp[512] = r1; outp[513] = r2; outp[514] = r3; outp[515] = r4; }
}

// ---------------- K6b: combine partials -> lp[bbh][6] ----------------
__global__ __launch_bounds__(256) void k_lstats2(const float* __restrict__ lpp,
                                                 float* __restrict__ lp) {
  int bbh = blockIdx.x;
  int tid = threadIdx.x;
  __shared__ float red[256];
  __shared__ float qsums[16], ksums[16];
  const float* b0 = lpp + (size_t)bbh * 4 * 548;
  float qg = b0[tid] + b0[548 + tid] + b0[1096 + tid] + b0[1644 + tid];
  float kg = b0[256 + tid] + b0[804 + tid] + b0[1352 + tid] + b0[1900 + tid];
  if (tid < 16) {
    qsums[tid] = b0[516 + tid] + b0[1064 + tid] + b0[1612 + tid] + b0[2160 + tid];
    ksums[tid] = b0[532 + tid] + b0[1080 + tid] + b0[1628 + tid] + b0[2176 + tid];
  }
  float sqqk = block_reduce(qg * kg, red, tid);
  if (tid == 0) {
    float sum_qk = 0.f;
    for (int d = 0; d < 16; ++d) sum_qk += qsums[d] * ksums[d];
    float s1 = 0.f, s2 = 0.f, s3 = 0.f, s4 = 0.f;
    for (int c = 0; c < 4; ++c) {
      const float* bc = b0 + (size_t)c * 548;
      s1 += bc[512]; s2 += bc[513]; s3 += bc[514]; s4 += bc[515];
    }
    float* o = lp + (size_t)bbh * 6;
    o[0] = sum_qk; o[1] = sqqk;
    o[2] = s1; o[3] = s2; o[4] = s3; o[5] = s4;
  }
}

// ---------------- K7: finalize logit BN affine ----------------
__global__ void k_logit_final(const float* __restrict__ lp,
                              const float* __restrict__ glog, const float* __restrict__ blog,
                              float* __restrict__ lab) {
  int c = threadIdx.x;
  if (c >= 24) return;
  int grp = c >> 3, h = c & 7;
  float s = 0.f, s2 = 0.f;
  for (int bb = 0; bb < NBB; ++bb) {
    const float* o = lp + (size_t)(bb * 8 + h) * 6 + grp * 2;
    s += o[0]; s2 += o[1];
  }
  float n = (float)NBB * (float)WPOS * (float)WPOS;
  float mean = s / n;
  float var = s2 / n - mean * mean;
  float la = glog[c] / sqrtf(var + NEPS);
  lab[c * 2] = la;
  lab[c * 2 + 1] = blog[c] - mean * la;
}

// ---------------- K8: fused logits + softmax + attention ----------------
// 1920 blocks = 8 tiles x 240 bbh, bbh fastest (XCD locality).
// S in log2 domain (la scales pre-multiplied by log2e; constant bias dropped —
// it cancels exactly in softmax). exp2f in the softmax pass.
__global__ __launch_bounds__(256) void k_attn(
    const float* __restrict__ z, const float* __restrict__ ca, const float* __restrict__ cb,
    const unsigned* __restrict__ vh,
    const unsigned* __restrict__ retc, const float* __restrict__ vet,
    const unsigned* __restrict__ vetp,
    const float* __restrict__ lab, float* __restrict__ out) {
  int blk = blockIdx.x;
  int bbh = blk % 240, tile = blk / 240;
  int bb = bbh >> 3, h = bbh & 7;
  int b = bb / 15, hi = bb % 15;
  int x0 = tile * 32;
  int nr = min(32, WPOS - x0);
  int tid = threadIdx.x;
  int lane = tid & 63, wvid = tid >> 6;

  const float LOG2E = 1.4426950408889634f;
  float la_qk = lab[h * 2] * LOG2E;
  float la_qr = lab[(8 + h) * 2] * LOG2E;
  float la_kr = lab[(16 + h) * 2] * LOG2E;

  __shared__ __align__(16) unsigned Su[32 * 130];     // fp16 S, 260 halfs/row
  __shared__ __align__(16) unsigned winU[282 * 18];   // fp16-pair rel rows
  __shared__ __align__(16) unsigned uSh[256];
  _Float16* S = (_Float16*)Su;

  unsigned* qsP = uSh;
  float* sred = (float*)uSh;

  int pwin0 = 251 - x0 - nr;
  int nwin = 250 + nr;

  const float* zb = z + ((size_t)bb * NCH + h * 64) * WPOS;

  for (int i = tid; i < nwin * 16; i += 256) {
    int r = i >> 4, j = i & 15;
    winU[r * 18 + j] = retc[(size_t)(pwin0 + r) * 16 + j];
  }

  {
    int xx = tid & 31, j = tid >> 5;
    int xcl = min(x0 + xx, WPOS - 1);
    int ch0 = h * 64 + 16 + 2 * j;
    float q0 = ca[ch0]     * zb[(size_t)(16 + 2 * j) * WPOS + xcl] + cb[ch0];
    float q1 = ca[ch0 + 1] * zb[(size_t)(17 + 2 * j) * WPOS + xcl] + cb[ch0 + 1];
    qsP[xx * 8 + j] = packh2(q0, q1);
  }

  int yy = wvid * 64 + lane;
  int yc = min(yy, WPOS - 1);
  bool yok = (yy < WPOS);
  half2_t kh[8];
#pragma unroll
  for (int d = 0; d < 8; ++d) {
    int ch = h * 64 + 2 * d;
    float k0 = ca[ch]     * zb[(size_t)(2 * d) * WPOS + yc] + cb[ch];
    float k1 = ca[ch + 1] * zb[(size_t)(2 * d + 1) * WPOS + yc] + cb[ch + 1];
    kh[d] = __builtin_bit_cast(half2_t, packh2(k0, k1));
  }
  __syncthreads();

  {
    int rowbase = yc + nr - 1;
    for (int xx = 0; xx < nr; ++xx) {
      const unsigned* wr = &winU[(size_t)(rowbase - xx) * 18];
      const unsigned* qp = &qsP[xx * 8];
      float dqk = 0.f, dqr = 0.f, dkr = 0.f;
#pragma unroll
      for (int j2 = 0; j2 < 4; ++j2) {
        uint2 ue = *(const uint2*)(wr + 2 * j2);
        uint2 uk = *(const uint2*)(wr + 8 + 2 * j2);
        uint2 uq = *(const uint2*)(qp + 2 * j2);
        half2_t qe0 = ash2(ue.x), qe1 = ash2(ue.y);
        half2_t ke0 = ash2(uk.x), ke1 = ash2(uk.y);
        half2_t q0  = ash2(uq.x), q1  = ash2(uq.y);
        half2_t k0 = kh[2 * j2], k1 = kh[2 * j2 + 1];
        dqk = FDOT2(q0, k0, dqk);  dqk = FDOT2(q1, k1, dqk);
        dqr = FDOT2(q0, qe0, dqr); dqr = FDOT2(q1, qe1, dqr);
        dkr = FDOT2(k0, ke0, dkr); dkr = FDOT2(k1, ke1, dkr);
      }
      float sval = la_qk * dqk + la_qr * dqr + la_kr * dkr;
      if (yy < 260) S[xx * 260 + yy] = yok ? (_Float16)sval : (_Float16)0.f;
    }
  }
  __syncthreads();

  int xx = lane & 31;
  int sl = wvid * 2 + (lane >> 5);
  int ylo = sl * 32;
  const unsigned* Srp = Su + xx * 130;
  {
    float m = -1e30f;
    if (sl < 7) {
#pragma unroll
      for (int pp = 0; pp < 16; ++pp) {
        half2_t hp = ash2(Srp[(ylo >> 1) + pp]);
        m = fmaxf(m, fmaxf((float)hp[0], (float)hp[1]));
      }
    } else {
#pragma unroll
      for (int pp = 0; pp < 13; ++pp) {
        half2_t hp = ash2(Srp[112 + pp]);
        m = fmaxf(m, fmaxf((float)hp[0], (float)hp[1]));
      }
      m = fmaxf(m, (float)S[xx * 260 + 250]);
    }
    sred[sl * 32 + xx] = m;
  }
  __syncthreads();
  float rowm = sred[0 * 32 + xx];
#pragma unroll
  for (int s = 1; s < 8; ++s) rowm = fmaxf(rowm, sred[s * 32 + xx]);
  __syncthreads();
  {
    float sacc = 0.f;
    unsigned* Swp = Su + xx * 130;
    if (sl < 7) {
#pragma unroll
      for (int pp = 0; pp < 16; ++pp) {
        half2_t hp = ash2(Swp[(ylo >> 1) + pp]);
        float e0 = exp2f((float)hp[0] - rowm);
        float e1 = exp2f((float)hp[1] - rowm);
        Swp[(ylo >> 1) + pp] = packh2(e0, e1);
        sacc += e0 + e1;
      }
    } else {
#pragma unroll
      for (int pp = 0; pp < 13; ++pp) {
        half2_t hp = ash2(Swp[112 + pp]);
        float e0 = exp2f((float)hp[0] - rowm);
        float e1 = exp2f((float)hp[1] - rowm);
        Swp[112 + pp] = packh2(e0, e1);
        sacc += e0 + e1;
      }
      float e = exp2f((float)S[xx * 260 + 250] - rowm);
      S[xx * 260 + 250] = (_Float16)e;
      sacc += e;
    }
    sred[sl * 32 + xx] = sacc;
  }
  __syncthreads();
  float denom = 0.f;
#pragma unroll
  for (int s = 0; s < 8; ++s) denom += sred[s * 32 + xx];

  int d0 = sl * 4;
  float4 acc = {0.f, 0.f, 0.f, 0.f};
  {
    const unsigned* vb = vh + ((size_t)bbh * 126) * 32 + d0;
    const unsigned* Sw = Su + xx * 130;
#pragma unroll 4
    for (int p2 = 0; p2 < 63; ++p2) {
      uint2 w2 = *(const uint2*)(Sw + 2 * p2);
      half2_t wa = ash2(w2.x), wb = ash2(w2.y);
      uint4 va = *(const uint4*)(vb + (size_t)(2 * p2) * 32);
      uint4 vb4 = *(const uint4*)(vb + (size_t)(2 * p2 + 1) * 32);
      acc.x = FDOT2(wa, ash2(va.x), acc.x); acc.x = FDOT2(wb, ash2(vb4.x), acc.x);
      acc.y = FDOT2(wa, ash2(va.y), acc.y); acc.y = FDOT2(wb, ash2(vb4.y), acc.y);
      acc.z = FDOT2(wa, ash2(va.z), acc.z); acc.z = FDOT2(wb, ash2(vb4.z), acc.z);
      acc.w = FDOT2(wa, ash2(va.w), acc.w); acc.w = FDOT2(wb, ash2(vb4.w), acc.w);
    }
  }
  {
    int xg = x0 + xx;
    int pmin = max(0, 250 - (x0 + nr - 1));
    int pmax = 500 - x0;
    int tlo = (251 - x0) >> 1;            // ceil((250 - x0)/2)
    int thi = (500 - x0 - nr) >> 1;       // floor; all-lane-valid pair range
    const float* veb = vet + d0;
    const _Float16* Sh = S + xx * 260;
    int phead = 2 * tlo;
    for (int p = pmin; p < phead; ++p) {
      int y2 = xg + p - 250;
      float w0 = ((unsigned)y2 < (unsigned)WPOS) ? (float)Sh[y2] : 0.f;
      float4 v0 = *(const float4*)(veb + (size_t)p * 32);
      acc.x += w0 * v0.x; acc.y += w0 * v0.y;
      acc.z += w0 * v0.z; acc.w += w0 * v0.w;
    }
    const unsigned* vpb = vetp + d0;
#pragma unroll 2
    for (int t = tlo; t <= thi; ++t) {
      int y2 = xg + 2 * t - 250;
      half2_t w;
      w[0] = Sh[y2];
      w[1] = Sh[y2 + 1];
      uint4 vv = *(const uint4*)(vpb + (size_t)t * 32);
      acc.x = FDOT2(w, ash2(vv.x), acc.x);
      acc.y = FDOT2(w, ash2(vv.y), acc.y);
      acc.z = FDOT2(w, ash2(vv.z), acc.z);
      acc.w = FDOT2(w, ash2(vv.w), acc.w);
    }
    for (int p = 2 * thi + 2; p <= pmax; ++p) {
      int y2 = xg + p - 250;
      float w0 = ((unsigned)y2 < (unsigned)WPOS) ? (float)Sh[y2] : 0.f;
      float4 v0 = *(const float4*)(veb + (size_t)p * 32);
      acc.x += w0 * v0.x; acc.y += w0 * v0.y;
      acc.z += w0 * v0.z; acc.w += w0 * v0.w;
    }
  }
  if (xx < nr) {
    float rinv = 1.0f / denom;
    int xg = x0 + xx;
    float av[4] = {acc.x, acc.y, acc.z, acc.w};
#pragma unroll
    for (int dd = 0; dd < 4; ++dd) {
      int d = d0 + dd;
      out[(((size_t)b * 256 + h * 32 + d) * 15 + hi) * WPOS + xg] = av[dd] * rinv;
    }
  }
}

// ---------------- launch ----------------
extern "C" void kernel_launch(void* const* d_in, const int* in_sizes, int n_in,
                              void* d_out, int out_size, void* d_ws, size_t ws_size,
                              hipStream_t stream) {
  const float* x    = (const float*)d_in[0];
  const float* y    = (const float*)d_in[1];
  const float* wk   = (const float*)d_in[2];
  const float* wq   = (const float*)d_in[3];
  const float* wv   = (const float*)d_in[4];
  const float* gk   = (const float*)d_in[5];
  const float* bk   = (const float*)d_in[6];
  const float* gq   = (const float*)d_in[7];
  const float* bq   = (const float*)d_in[8];
  const float* gkq  = (const float*)d_in[9];
  const float* bkq  = (const float*)d_in[10];
  const float* glog = (const float*)d_in[11];
  const float* blog = (const float*)d_in[12];
  const float* rel  = (const float*)d_in[13];
  float* out = (float*)d_out;
  float* ws  = (float*)d_ws;

  float* z      = ws + OFF_Z;
  unsigned* vh  = (unsigned*)(ws + OFF_VH);
  unsigned* retc= (unsigned*)(ws + OFF_RETC);
  float* vet    = ws + OFF_VET;
  unsigned* vetp= (unsigned*)(ws + OFF_VETP);
  float* p1q    = ws + OFF_P1Q;
  float* p1k    = ws + OFF_P1K;
  float* p2q    = ws + OFF_P2Q;
  float* p2k    = ws + OFF_P2K;
  float* ca     = ws + OFF_CA;
  float* cb     = ws + OFF_CB;
  float* lp     = ws + OFF_LP;
  float* lab    = ws + OFF_LAB;
  float* lpp    = ws + OFF_LPP;

  dim3 g1(4, 8, NBB);
  k_gemm<<<g1, 256, 0, stream>>>(x, y, wk, wq, wv, z);
  k_chan_stats<<<512, 256, 0, stream>>>(z, gk, bk, gq, bq, gkq, bkq, ca, cb);
  k_norm_vh<<<960, 256, 0, stream>>>(z, ca, cb, vh);
  k_rel_prep<<<(RELP * 48 + 251 * 32 + 255) / 256, 256, 0, stream>>>(rel, retc, vet, vetp);
  k_prefix<<<544, 256, 0, stream>>>(rel, p1q, p1k, p2q, p2k);
  k_lstats1<<<960, 256, 0, stream>>>(z, ca, cb, p1q, p1k, p2q, p2k, lpp);
  k_lstats2<<<240, 256, 0, stream>>>(lpp, lp);
  k_logit_final<<<1, 32, 0, stream>>>(lp, glog, blog, lab);
  k_attn<<<240 * 8, 256, 0, stream>>>(z, ca, cb, vh, retc, vet, vetp, lab, out);
}

// Round 9
// 113.867 us; speedup vs baseline: 6.2198x; 1.6716x over previous
//
#include <hip/hip_runtime.h>
#include <hip/hip_bf16.h>
#include <cstdint>

#define WPOS 251
#define NBB  30
#define NCH  512
#define RELP 501
#define NEPS 1e-5f

typedef _Float16 half2_t __attribute__((ext_vector_type(2)));
typedef _Float16 half8_t __attribute__((ext_vector_type(8)));
typedef float f32x16_t __attribute__((ext_vector_type(16)));

#if defined(__has_builtin)
#if __has_builtin(__builtin_amdgcn_fdot2)
#define FDOT2(a, b, c) __builtin_amdgcn_fdot2((a), (b), (c), false)
#endif
#endif
#ifndef FDOT2
#define FDOT2(a, b, c) ((float)(a)[0] * (float)(b)[0] + (float)(a)[1] * (float)(b)[1] + (c))
#endif

// ---------------- workspace layout (in float slots) ----------------
static constexpr size_t SZ_Z     = (size_t)NBB * NCH * WPOS;
static constexpr size_t OFF_Z    = 0;
static constexpr size_t OFF_VH   = OFF_Z + SZ_Z;                   // uint[bbh][128][32] half2 v pairs (zero-padded)
static constexpr size_t SZ_VH    = (size_t)NBB * 8 * 128 * 32;
static constexpr size_t OFF_RETC = OFF_VH + SZ_VH;                 // uint[501][16]: qe|keR fp16 pairs
static constexpr size_t OFF_VETP = OFF_RETC + (size_t)RELP * 16;   // uint[256][32] half2 p-pairs (zero-padded)
static constexpr size_t OFF_P1Q  = OFF_VETP + (size_t)256 * 32;    // [16][502]
static constexpr size_t OFF_P1K  = OFF_P1Q + (size_t)16 * 502;
static constexpr size_t OFF_P2Q  = OFF_P1K + (size_t)16 * 502;     // [256][502]
static constexpr size_t OFF_P2K  = OFF_P2Q + (size_t)256 * 502;
static constexpr size_t OFF_CA   = OFF_P2K + (size_t)256 * 502;    // [512]
static constexpr size_t OFF_CB   = OFF_CA + 512;
static constexpr size_t OFF_LP   = OFF_CB + 512;                   // [240][6]
static constexpr size_t OFF_LAB  = OFF_LP + (size_t)240 * 6;       // [24][2]
static constexpr size_t OFF_LPP  = OFF_LAB + 48;                   // [960][548] partials

static __device__ __forceinline__ unsigned packh2(float a, float b) {
  half2_t t;
  t[0] = (_Float16)a;
  t[1] = (_Float16)b;
  return __builtin_bit_cast(unsigned, t);
}
static __device__ __forceinline__ half2_t ash2(unsigned u) {
  return __builtin_bit_cast(half2_t, u);
}

// ---------------- K1: kqv GEMM via fp16 MFMA: Z[bb][o][l] (raw, pre-BN) ----------------
__global__ __launch_bounds__(256) void k_gemm(
    const float* __restrict__ x, const float* __restrict__ y,
    const float* __restrict__ wk, const float* __restrict__ wq,
    const float* __restrict__ wv, float* __restrict__ z) {
  int l0 = blockIdx.x * 64;
  int o0 = blockIdx.y * 64;
  int bb = blockIdx.z;
  int b = bb / 15, hi = bb % 15;
  const float* src;
  const float* wmat;
  int orow0;
  if (o0 < 128)      { wmat = wk; orow0 = o0;       src = x; }
  else if (o0 < 256) { wmat = wq; orow0 = o0 - 128; src = y; }
  else               { wmat = wv; orow0 = o0 - 256; src = x; }

  __shared__ _Float16 Ah[64][68];   // [o][k]
  __shared__ _Float16 Bh[64][68];   // [k][l]

  int tid = threadIdx.x;
  int lane = tid & 63, wv4 = tid >> 6;
  int wo = wv4 >> 1, wl = wv4 & 1;
  int m = lane & 31, kh = lane >> 5;

  f32x16_t acc = {};

  int cA = tid & 63, ogA = tid >> 6;
  int lB = tid & 63, kgB = tid >> 6;
  int lglob = l0 + lB;
  bool lok = (lglob < WPOS);
  const float* xcol = src + (size_t)(((size_t)b * 256) * 15 + hi) * WPOS + lglob;

  for (int c0 = 0; c0 < 256; c0 += 64) {
#pragma unroll
    for (int i = 0; i < 16; ++i) {
      int o = ogA * 16 + i;
      Ah[o][cA] = (_Float16)wmat[(size_t)(orow0 + o) * 256 + c0 + cA];
    }
#pragma unroll
    for (int i = 0; i < 16; ++i) {
      int k = kgB * 16 + i;
      float v = lok ? xcol[(size_t)(c0 + k) * 15 * WPOS] : 0.f;
      Bh[k][lB] = (_Float16)v;
    }
    __syncthreads();
#pragma unroll
    for (int ks = 0; ks < 4; ++ks) {
      const _Float16* ap = &Ah[wo * 32 + m][ks * 16 + kh * 8];
      uint2 aLo = *(const uint2*)(ap);
      uint2 aHi = *(const uint2*)(ap + 4);
      uint4 au = {aLo.x, aLo.y, aHi.x, aHi.y};
      half8_t af = __builtin_bit_cast(half8_t, au);
      half8_t bf;
      int kb = ks * 16 + kh * 8;
      int bcol = wl * 32 + m;
#pragma unroll
      for (int e = 0; e < 8; ++e) bf[e] = Bh[kb + e][bcol];
      acc = __builtin_amdgcn_mfma_f32_32x32x16_f16(af, bf, acc, 0, 0, 0);
    }
    __syncthreads();
  }

  int n = lane & 31;
  int lout = l0 + wl * 32 + n;
  if (lout < WPOS) {
#pragma unroll
    for (int r = 0; r < 16; ++r) {
      int mrow = (r & 3) + 8 * (r >> 2) + 4 * kh;
      int o = o0 + wo * 32 + mrow;
      z[((size_t)bb * NCH + o) * WPOS + lout] = acc[r];
    }
  }
}

// ---------------- K2: per-channel BN stats -> affine a,b ----------------
__global__ __launch_bounds__(256) void k_chan_stats(
    const float* __restrict__ z,
    const float* __restrict__ gk, const float* __restrict__ bk,
    const float* __restrict__ gq, const float* __restrict__ bq,
    const float* __restrict__ gkq, const float* __restrict__ bkq,
    float* __restrict__ ca, float* __restrict__ cb) {
  int o = blockIdx.x;
  int tid = threadIdx.x;
  float s = 0.f, s2 = 0.f;
  for (int idx = tid; idx < NBB * WPOS; idx += 256) {
    int bb = idx / WPOS, l = idx - bb * WPOS;
    float v = z[((size_t)bb * NCH + o) * WPOS + l];
    s += v; s2 += v * v;
  }
  __shared__ float r1[256], r2[256];
  r1[tid] = s; r2[tid] = s2; __syncthreads();
  for (int st = 128; st > 0; st >>= 1) {
    if (tid < st) { r1[tid] += r1[tid + st]; r2[tid] += r2[tid + st]; }
    __syncthreads();
  }
  if (tid == 0) {
    float n = (float)(NBB * WPOS);
    float mean = r1[0] / n;
    float var = r2[0] / n - mean * mean;
    float g, bi;
    if (o < 128)      { g = gk[o];        bi = bk[o]; }
    else if (o < 256) { g = gq[o - 128];  bi = bq[o - 128]; }
    else              { g = gkq[o - 256]; bi = bkq[o - 256]; }
    float a = g / sqrtf(var + NEPS);
    ca[o] = a;
    cb[o] = bi - mean * a;
  }
}

// ---------------- K3: normalized v -> VH[bbh][pair][32] half2 pairs ----------------
__global__ __launch_bounds__(256) void k_norm_vh(
    const float* __restrict__ z, const float* __restrict__ ca, const float* __restrict__ cb,
    unsigned* __restrict__ vh) {
  int blk = blockIdx.x;
  int bbh = blk % 240, lt = blk / 240;
  int bb = bbh >> 3, h = bbh & 7;
  int l0 = lt * 64;
  __shared__ float T[32][65];
  int tid = threadIdx.x;
  const float* zv = z + ((size_t)bb * NCH + h * 64 + 32) * WPOS;
  for (int i = tid; i < 32 * 64; i += 256) {
    int ch = i >> 6, l = i & 63;
    int gl = l0 + l;
    int cch = h * 64 + 32 + ch;
    T[ch][l] = (gl < WPOS) ? (ca[cch] * zv[(size_t)ch * WPOS + gl] + cb[cch]) : 0.f;
  }
  __syncthreads();
  int p0 = l0 >> 1;
  for (int i = tid; i < 32 * 32; i += 256) {
    int pl = i >> 5, ch = i & 31;
    int gp = p0 + pl;
    if (gp < 128)
      vh[((size_t)bbh * 128 + gp) * 32 + ch] = packh2(T[ch][2 * pl], T[ch][2 * pl + 1]);
  }
}

// ---------------- K4: rel prep: fp16 qe|keR table + vetp pairs (zero-padded) ----------------
__global__ void k_rel_prep(const float* __restrict__ rel, unsigned* __restrict__ retc,
                           unsigned* __restrict__ vetp) {
  int idx = blockIdx.x * 256 + threadIdx.x;
  if (idx < RELP * 16) {
    int p = idx >> 4, j = idx & 15;
    float lo, hi;
    if (j < 8) {
      lo = rel[(size_t)(2 * j) * RELP + p];
      hi = rel[(size_t)(2 * j + 1) * RELP + p];
    } else {
      int jj = j - 8;
      lo = rel[(size_t)(16 + 2 * jj) * RELP + (500 - p)];
      hi = rel[(size_t)(17 + 2 * jj) * RELP + (500 - p)];
    }
    retc[(size_t)p * 16 + j] = packh2(lo, hi);
  } else {
    int i2 = idx - RELP * 16;
    if (i2 >= 256 * 32) return;
    int t = i2 >> 5, ch = i2 & 31;
    float lo = (2 * t <= 500) ? rel[(size_t)(32 + ch) * RELP + 2 * t] : 0.f;
    float hi = (2 * t + 1 <= 500) ? rel[(size_t)(32 + ch) * RELP + 2 * t + 1] : 0.f;
    vetp[(size_t)t * 32 + ch] = packh2(lo, hi);
  }
}

// ---------------- K5: prefix sums (parallel pair + Hillis-Steele scan) ----------------
__global__ __launch_bounds__(256) void k_prefix(const float* __restrict__ rel,
                                                float* __restrict__ p1q, float* __restrict__ p1k,
                                                float* __restrict__ p2q, float* __restrict__ p2k) {
  int task = blockIdx.x;   // 0..543
  const float* ra;
  const float* rb = nullptr;
  float* outp;
  if (task < 16)        { ra = rel + (size_t)task * RELP; outp = p1q + (size_t)task * 502; }
  else if (task < 32)   { ra = rel + (size_t)task * RELP; outp = p1k + (size_t)(task - 16) * 502; }
  else if (task < 288)  { int pr = task - 32;
                          ra = rel + (size_t)(pr >> 4) * RELP;
                          rb = rel + (size_t)(pr & 15) * RELP;
                          outp = p2q + (size_t)pr * 502; }
  else                  { int pr = task - 288;
                          ra = rel + (size_t)(16 + (pr >> 4)) * RELP;
                          rb = rel + (size_t)(16 + (pr & 15)) * RELP;
                          outp = p2k + (size_t)pr * 502; }
  __shared__ float buf[256];
  int t = threadIdx.x;
  int i0 = 2 * t, i1 = 2 * t + 1;
  float a0 = (i0 < RELP) ? (rb ? ra[i0] * rb[i0] : ra[i0]) : 0.f;
  float a1 = (i1 < RELP) ? (rb ? ra[i1] * rb[i1] : ra[i1]) : 0.f;
  buf[t] = a0 + a1;
  __syncthreads();
#pragma unroll
  for (int off = 1; off < 256; off <<= 1) {
    float v = buf[t];
    float add = (t >= off) ? buf[t - off] : 0.f;
    __syncthreads();
    buf[t] = v + add;
    __syncthreads();
  }
  float ex = buf[t] - (a0 + a1);
  if (i0 <= RELP) outp[i0] = ex;
  if (i1 <= RELP) outp[i1] = ex + a0;
}

// ---------------- block reduce helper ----------------
__device__ __forceinline__ float block_reduce(float v, float* red, int tid) {
  red[tid] = v; __syncthreads();
  for (int s = 128; s > 0; s >>= 1) {
    if (tid < s) red[tid] += red[tid + s];
    __syncthreads();
  }
  float r = red[0]; __syncthreads();
  return r;
}

// ---------------- K6a: logit BN partials per (bbh, x-chunk) ----------------
__global__ __launch_bounds__(256) void k_lstats1(
    const float* __restrict__ z, const float* __restrict__ ca, const float* __restrict__ cb,
    const float* __restrict__ p1q, const float* __restrict__ p1k,
    const float* __restrict__ p2q, const float* __restrict__ p2k,
    float* __restrict__ lpp) {
  int blk = blockIdx.x;
  int bbh = blk % 240, xc = blk / 240;
  int bb = bbh >> 3, h = bbh & 7;
  int x0 = xc * 64;
  int tid = threadIdx.x;
  __shared__ float qs[16][68], ks[16][68];
  __shared__ float red[256];
  const float* zb = z + ((size_t)bb * NCH + h * 64) * WPOS;
  for (int idx = tid; idx < 16 * 64; idx += 256) {
    int d = idx >> 6, xl = idx & 63;
    int xg = x0 + xl;
    float kv = 0.f, qv = 0.f;
    if (xg < WPOS) {
      int chk = h * 64 + d, chq = h * 64 + 16 + d;
      kv = ca[chk] * zb[(size_t)d * WPOS + xg] + cb[chk];
      qv = ca[chq] * zb[(size_t)(16 + d) * WPOS + xg] + cb[chq];
    }
    ks[d][xl] = kv; qs[d][xl] = qv;
  }
  __syncthreads();
  float* outp = lpp + ((size_t)bbh * 4 + xc) * 548;
  if (tid < 16) {
    float s = 0.f;
    for (int xl = 0; xl < 64; ++xl) s += qs[tid][xl];
    outp[516 + tid] = s;
  } else if (tid < 32) {
    float s = 0.f;
    for (int xl = 0; xl < 64; ++xl) s += ks[tid - 16][xl];
    outp[532 + (tid - 16)] = s;
  }
  {
    int d = tid >> 4, d2 = tid & 15;
    float g1 = 0.f, g2 = 0.f;
    for (int xl = 0; xl < 64; ++xl) {
      g1 += qs[d][xl] * qs[d2][xl];
      g2 += ks[d][xl] * ks[d2][xl];
    }
    outp[tid] = g1;
    outp[256 + tid] = g2;
  }
  float v_sumqr = 0.f, v_sqqr = 0.f, v_sumkr = 0.f, v_sqkr = 0.f;
  for (int idx = tid; idx < 16 * 64; idx += 256) {
    int d = idx >> 6, xl = idx & 63;
    int xg = x0 + xl;
    if (xg < WPOS) {
      int ihi = 501 - xg, ilo = 250 - xg;
      float qv = qs[d][xl];
      v_sumqr += qv * (p1q[d * 502 + ihi] - p1q[d * 502 + ilo]);
      float t = 0.f;
      for (int d2 = 0; d2 < 16; ++d2) {
        const float* pp = p2q + (size_t)(d * 16 + d2) * 502;
        t += qs[d2][xl] * (pp[ihi] - pp[ilo]);
      }
      v_sqqr += qv * t;
      float kv = ks[d][xl];
      v_sumkr += kv * (p1k[d * 502 + ihi] - p1k[d * 502 + ilo]);
      float t2 = 0.f;
      for (int d2 = 0; d2 < 16; ++d2) {
        const float* pp = p2k + (size_t)(d * 16 + d2) * 502;
        t2 += ks[d2][xl] * (pp[ihi] - pp[ilo]);
      }
      v_sqkr += kv * t2;
    }
  }
  float r1 = block_reduce(v_sumqr, red, tid);
  float r2 = block_reduce(v_sqqr, red, tid);
  float r3 = block_reduce(v_sumkr, red, tid);
  float r4 = block_reduce(v_sqkr, red, tid);
  if (tid == 0) { outp[512] = r1; outp[513] = r2; outp[514] = r3; outp[515] = r4; }
}

// ---------------- K6b: combine partials -> lp[bbh][6] ----------------
__global__ __launch_bounds__(256) void k_lstats2(const float* __restrict__ lpp,
                                                 float* __restrict__ lp) {
  int bbh = blockIdx.x;
  int tid = threadIdx.x;
  __shared__ float red[256];
  __shared__ float qsums[16], ksums[16];
  const float* b0 = lpp + (size_t)bbh * 4 * 548;
  float qg = b0[tid] + b0[548 + tid] + b0[1096 + tid] + b0[1644 + tid];
  float kg = b0[256 + tid] + b0[804 + tid] + b0[1352 + tid] + b0[1900 + tid];
  if (tid < 16) {
    qsums[tid] = b0[516 + tid] + b0[1064 + tid] + b0[1612 + tid] + b0[2160 + tid];
    ksums[tid] = b0[532 + tid] + b0[1080 + tid] + b0[1628 + tid] + b0[2176 + tid];
  }
  float sqqk = block_reduce(qg * kg, red, tid);
  if (tid == 0) {
    float sum_qk = 0.f;
    for (int d = 0; d < 16; ++d) sum_qk += qsums[d] * ksums[d];
    float s1 = 0.f, s2 = 0.f, s3 = 0.f, s4 = 0.f;
    for (int c = 0; c < 4; ++c) {
      const float* bc = b0 + (size_t)c * 548;
      s1 += bc[512]; s2 += bc[513]; s3 += bc[514]; s4 += bc[515];
    }
    float* o = lp + (size_t)bbh * 6;
    o[0] = sum_qk; o[1] = sqqk;
    o[2] = s1; o[3] = s2; o[4] = s3; o[5] = s4;
  }
}

// ---------------- K7: finalize logit BN affine ----------------
__global__ void k_logit_final(const float* __restrict__ lp,
                              const float* __restrict__ glog, const float* __restrict__ blog,
                              float* __restrict__ lab) {
  int c = threadIdx.x;
  if (c >= 24) return;
  int grp = c >> 3, h = c & 7;
  float s = 0.f, s2 = 0.f;
  for (int bb = 0; bb < NBB; ++bb) {
    const float* o = lp + (size_t)(bb * 8 + h) * 6 + grp * 2;
    s += o[0]; s2 += o[1];
  }
  float n = (float)NBB * (float)WPOS * (float)WPOS;
  float mean = s / n;
  float var = s2 / n - mean * mean;
  float la = glog[c] / sqrtf(var + NEPS);
  lab[c * 2] = la;
  lab[c * 2 + 1] = blog[c] - mean * la;
}

// ---------------- K8: fused logits + softmax + MFMA attention ----------------
// 1920 blocks = 8 tiles x 240 bbh, bbh fastest (XCD locality).
// S fp16, stride 264 halfs (528B = 33*16B: every row 16B-aligned).
// PV-main: C[32d][32x] = V^T(K=256) * W^T  — 4 MFMA/wave (K-split by wave).
// Band:    C += VE^T(K=512) * W'          — 8 MFMA/wave, W' = Toeplitz read of S.
__global__ __launch_bounds__(256) void k_attn(
    const float* __restrict__ z, const float* __restrict__ ca, const float* __restrict__ cb,
    const unsigned* __restrict__ vh,
    const unsigned* __restrict__ retc, const unsigned* __restrict__ vetp,
    const float* __restrict__ lab, float* __restrict__ out) {
  int blk = blockIdx.x;
  int bbh = blk % 240, tile = blk / 240;
  int bb = bbh >> 3, h = bbh & 7;
  int b = bb / 15, hi = bb % 15;
  int x0 = tile * 32;
  int nr = min(32, WPOS - x0);
  int tid = threadIdx.x;
  int lane = tid & 63, wvid = tid >> 6;

  const float LOG2E = 1.4426950408889634f;
  float la_qk = lab[h * 2] * LOG2E;
  float la_qr = lab[(8 + h) * 2] * LOG2E;
  float la_kr = lab[(16 + h) * 2] * LOG2E;

  __shared__ __align__(16) unsigned Su[32 * 132];     // 16,896 B  fp16 S, 264 halfs/row
  __shared__ __align__(16) unsigned winU[282 * 18];   // 20,304 B  rel rows; later Cred[3][64][17] f32
  __shared__ __align__(16) unsigned uSh[256];         // 1,024 B   qsP early, sred later
  _Float16* S = (_Float16*)Su;
  unsigned* qsP = uSh;
  float* sred = (float*)uSh;
  float* Cred = (float*)winU;

  int pwin0 = 251 - x0 - nr;
  int nwin = 250 + nr;

  const float* zb = z + ((size_t)bb * NCH + h * 64) * WPOS;

  // ---- stage rel window into LDS ----
  for (int i = tid; i < nwin * 16; i += 256) {
    int r = i >> 4, j = i & 15;
    winU[r * 18 + j] = retc[(size_t)(pwin0 + r) * 16 + j];
  }

  // ---- stage q tile (affine from raw z, fp16-packed) ----
  {
    int xx = tid & 31, j = tid >> 5;
    int xcl = min(x0 + xx, WPOS - 1);
    int ch0 = h * 64 + 16 + 2 * j;
    float q0 = ca[ch0]     * zb[(size_t)(16 + 2 * j) * WPOS + xcl] + cb[ch0];
    float q1 = ca[ch0 + 1] * zb[(size_t)(17 + 2 * j) * WPOS + xcl] + cb[ch0 + 1];
    qsP[xx * 8 + j] = packh2(q0, q1);
  }

  // ---- k row per lane (affine from raw z), fp16-packed ----
  int yy = wvid * 64 + lane;
  int yc = min(yy, WPOS - 1);
  bool yok = (yy < WPOS);
  half2_t khv[8];
#pragma unroll
  for (int d = 0; d < 8; ++d) {
    int ch = h * 64 + 2 * d;
    float k0 = ca[ch]     * zb[(size_t)(2 * d) * WPOS + yc] + cb[ch];
    float k1 = ca[ch + 1] * zb[(size_t)(2 * d + 1) * WPOS + yc] + cb[ch + 1];
    khv[d] = __builtin_bit_cast(half2_t, packh2(k0, k1));
  }
  __syncthreads();

  // ---- fused S: qk + qr + kr, log2 domain; lanes on y, loop over x ----
  {
    int rowbase = yc + nr - 1;
    for (int xx = 0; xx < nr; ++xx) {
      const unsigned* wr = &winU[(size_t)(rowbase - xx) * 18];
      const unsigned* qp = &qsP[xx * 8];
      float dqk = 0.f, dqr = 0.f, dkr = 0.f;
#pragma unroll
      for (int j2 = 0; j2 < 4; ++j2) {
        uint2 ue = *(const uint2*)(wr + 2 * j2);
        uint2 uk = *(const uint2*)(wr + 8 + 2 * j2);
        uint2 uq = *(const uint2*)(qp + 2 * j2);
        half2_t qe0 = ash2(ue.x), qe1 = ash2(ue.y);
        half2_t ke0 = ash2(uk.x), ke1 = ash2(uk.y);
        half2_t q0  = ash2(uq.x), q1  = ash2(uq.y);
        half2_t k0 = khv[2 * j2], k1 = khv[2 * j2 + 1];
        dqk = FDOT2(q0, k0, dqk);  dqk = FDOT2(q1, k1, dqk);
        dqr = FDOT2(q0, qe0, dqr); dqr = FDOT2(q1, qe1, dqr);
        dkr = FDOT2(k0, ke0, dkr); dkr = FDOT2(k1, ke1, dkr);
      }
      float sval = la_qk * dqk + la_qr * dqr + la_kr * dkr;
      S[xx * 264 + yy] = yok ? (_Float16)sval : (_Float16)0.f;
    }
  }
  // ---- zero pad: cols 256..263 all rows; full rows nr..31 (tile 7) ----
  for (int i = tid; i < 32 * 8; i += 256)
    S[(i >> 3) * 264 + 256 + (i & 7)] = (_Float16)0.f;
  if (nr < 32) {
    int ntail = (32 - nr) * 264;
    for (int i = tid; i < ntail; i += 256) S[nr * 264 + i] = (_Float16)0.f;
  }
  __syncthreads();

  // ---- softmax over y; lanes on x, 8 slices; pair-wise fp16 ----
  int xx = lane & 31;
  int sl = wvid * 2 + (lane >> 5);
  int ylo = sl * 32;
  const unsigned* Srp = Su + xx * 132;
  {
    float m = -1e30f;
    if (sl < 7) {
#pragma unroll
      for (int pp = 0; pp < 16; ++pp) {
        half2_t hp = ash2(Srp[(ylo >> 1) + pp]);
        m = fmaxf(m, fmaxf((float)hp[0], (float)hp[1]));
      }
    } else {
#pragma unroll
      for (int pp = 0; pp < 13; ++pp) {
        half2_t hp = ash2(Srp[112 + pp]);
        m = fmaxf(m, fmaxf((float)hp[0], (float)hp[1]));
      }
      m = fmaxf(m, (float)S[xx * 264 + 250]);
    }
    sred[sl * 32 + xx] = m;
  }
  __syncthreads();
  float rowm = sred[0 * 32 + xx];
#pragma unroll
  for (int s = 1; s < 8; ++s) rowm = fmaxf(rowm, sred[s * 32 + xx]);
  __syncthreads();
  {
    float sacc = 0.f;
    unsigned* Swp = Su + xx * 132;
    if (sl < 7) {
#pragma unroll
      for (int pp = 0; pp < 16; ++pp) {
        half2_t hp = ash2(Swp[(ylo >> 1) + pp]);
        float e0 = exp2f((float)hp[0] - rowm);
        float e1 = exp2f((float)hp[1] - rowm);
        Swp[(ylo >> 1) + pp] = packh2(e0, e1);
        sacc += e0 + e1;
      }
    } else {
#pragma unroll
      for (int pp = 0; pp < 13; ++pp) {
        half2_t hp = ash2(Swp[112 + pp]);
        float e0 = exp2f((float)hp[0] - rowm);
        float e1 = exp2f((float)hp[1] - rowm);
        Swp[112 + pp] = packh2(e0, e1);
        sacc += e0 + e1;
      }
      float e = exp2f((float)S[xx * 264 + 250] - rowm);
      S[xx * 264 + 250] = (_Float16)e;   // half 251 stays 0
      sacc += e;
    }
    sred[sl * 32 + xx] = sacc;
  }
  __syncthreads();
  float denom = 0.f;
#pragma unroll
  for (int s = 0; s < 8; ++s) denom += sred[s * 32 + xx];

  // ---- MFMA PV: C[d][x] ; K-split across 4 waves ----
  f32x16_t acc = {};
  int xcol = lane & 31;
  int khh = lane >> 5;
  const _Float16* Srow = S + xcol * 264;
  {
    // PV-main: A[d][y] = v[y][d] (vh pairs), B[y][x] = W[x][y] (b128 from S row)
    const unsigned* vhb = vh + (size_t)bbh * 128 * 32 + xcol;
#pragma unroll
    for (int ks = 0; ks < 4; ++ks) {
      int y0 = 64 * wvid + 16 * ks + 8 * khh;
      int t0 = y0 >> 1;
      uint4 au = {vhb[(size_t)(t0 + 0) * 32], vhb[(size_t)(t0 + 1) * 32],
                  vhb[(size_t)(t0 + 2) * 32], vhb[(size_t)(t0 + 3) * 32]};
      half8_t af = __builtin_bit_cast(half8_t, au);
      half8_t bf = *(const half8_t*)(Srow + y0);    // 16B-aligned: 528*x + 16k
      acc = __builtin_amdgcn_mfma_f32_32x32x16_f16(af, bf, acc, 0, 0, 0);
    }
    // Band: A[d][p] = vet[p][d] (vetp pairs), B[p][x] = W'[x][p] = S[x][x+x0+p-250]
    const unsigned* vpb = vetp + xcol;
    int ybase = xcol + x0 - 250;
#pragma unroll
    for (int ks = 0; ks < 8; ++ks) {
      int p0 = 128 * wvid + 16 * ks + 8 * khh;
      int t0 = p0 >> 1;
      uint4 au = {vpb[(size_t)(t0 + 0) * 32], vpb[(size_t)(t0 + 1) * 32],
                  vpb[(size_t)(t0 + 2) * 32], vpb[(size_t)(t0 + 3) * 32]};
      half8_t af = __builtin_bit_cast(half8_t, au);
      half8_t bf;
#pragma unroll
      for (int e = 0; e < 8; ++e) {
        int yv = ybase + p0 + e;
        bf[e] = ((unsigned)yv < 264u) ? Srow[yv] : (_Float16)0.f;
      }
      acc = __builtin_amdgcn_mfma_f32_32x32x16_f16(af, bf, acc, 0, 0, 0);
    }
  }

  // ---- cross-wave C reduction via Cred (winU space), wave 0 stores ----
  if (wvid > 0) {
    float* cp = Cred + ((size_t)(wvid - 1) * 64 + lane) * 17;
#pragma unroll
    for (int r = 0; r < 16; ++r) cp[r] = acc[r];
  }
  __syncthreads();
  if (wvid == 0) {
#pragma unroll
    for (int w2 = 0; w2 < 3; ++w2) {
      const float* cp = Cred + ((size_t)w2 * 64 + lane) * 17;
#pragma unroll
      for (int r = 0; r < 16; ++r) acc[r] += cp[r];
    }
    if (xcol < nr) {
      float rinv = 1.0f / denom;
      int xg = x0 + xcol;
#pragma unroll
      for (int r = 0; r < 16; ++r) {
        int d = (r & 3) + 8 * (r >> 2) + 4 * khh;
        out[(((size_t)b * 256 + h * 32 + d) * 15 + hi) * WPOS + xg] = acc[r] * rinv;
      }
    }
  }
}

// ---------------- launch ----------------
extern "C" void kernel_launch(void* const* d_in, const int* in_sizes, int n_in,
                              void* d_out, int out_size, void* d_ws, size_t ws_size,
                              hipStream_t stream) {
  const float* x    = (const float*)d_in[0];
  const float* y    = (const float*)d_in[1];
  const float* wk   = (const float*)d_in[2];
  const float* wq   = (const float*)d_in[3];
  const float* wv   = (const float*)d_in[4];
  const float* gk   = (const float*)d_in[5];
  const float* bk   = (const float*)d_in[6];
  const float* gq   = (const float*)d_in[7];
  const float* bq   = (const float*)d_in[8];
  const float* gkq  = (const float*)d_in[9];
  const float* bkq  = (const float*)d_in[10];
  const float* glog = (const float*)d_in[11];
  const float* blog = (const float*)d_in[12];
  const float* rel  = (const float*)d_in[13];
  float* out = (float*)d_out;
  float* ws  = (float*)d_ws;

  float* z      = ws + OFF_Z;
  unsigned* vh  = (unsigned*)(ws + OFF_VH);
  unsigned* retc= (unsigned*)(ws + OFF_RETC);
  unsigned* vetp= (unsigned*)(ws + OFF_VETP);
  float* p1q    = ws + OFF_P1Q;
  float* p1k    = ws + OFF_P1K;
  float* p2q    = ws + OFF_P2Q;
  float* p2k    = ws + OFF_P2K;
  float* ca     = ws + OFF_CA;
  float* cb     = ws + OFF_CB;
  float* lp     = ws + OFF_LP;
  float* lab    = ws + OFF_LAB;
  float* lpp    = ws + OFF_LPP;

  dim3 g1(4, 8, NBB);
  k_gemm<<<g1, 256, 0, stream>>>(x, y, wk, wq, wv, z);
  k_chan_stats<<<512, 256, 0, stream>>>(z, gk, bk, gq, bq, gkq, bkq, ca, cb);
  k_norm_vh<<<960, 256, 0, stream>>>(z, ca, cb, vh);
  k_rel_prep<<<(RELP * 16 + 256 * 32 + 255) / 256, 256, 0, stream>>>(rel, retc, vetp);
  k_prefix<<<544, 256, 0, stream>>>(rel, p1q, p1k, p2q, p2k);
  k_lstats1<<<960, 256, 0, stream>>>(z, ca, cb, p1q, p1k, p2q, p2k, lpp);
  k_lstats2<<<240, 256, 0, stream>>>(lpp, lp);
  k_logit_final<<<1, 32, 0, stream>>>(lp, glog, blog, lab);
  k_attn<<<240 * 8, 256, 0, stream>>>(z, ca, cb, vh, retc, vetp, lab, out);
}